// Round 15
// baseline (552.066 us; speedup 1.0000x reference)
//
#include <hip/hip_runtime.h>
#include <stdint.h>

#define D 2048
#define LSEQ 2048
#define BATCH 4
#define BL (BATCH * LSEQ)   // 8192 rows
#define NSLOT 16
#define NHEAD 32
#define HDIM 64
#define EPSV 1e-6f

typedef __attribute__((ext_vector_type(8))) short bf16x8;
typedef __attribute__((ext_vector_type(4))) float f32x4;

static __device__ __forceinline__ ushort f2bf(float f) {
    uint32_t u = __float_as_uint(f);
    u += 0x7fffu + ((u >> 16) & 1u);   // RNE
    return (ushort)(u >> 16);
}

static __device__ __forceinline__ float wave_sum(float v) {
#pragma unroll
    for (int off = 32; off > 0; off >>= 1) v += __shfl_xor(v, off, 64);
    return v;
}

static __device__ __forceinline__ void gl_lds16(const void* g, void* l) {
    __builtin_amdgcn_global_load_lds(
        (__attribute__((address_space(1))) uint32_t*)(uintptr_t)g,
        (__attribute__((address_space(3))) uint32_t*)(uint32_t)(uintptr_t)l,
        16, 0, 0);
}

// ---------------- weight convert f32 -> bf16 ----------------
__global__ __launch_bounds__(256) void conv_bf16_kernel(const float4* __restrict__ src,
                                                        ushort* __restrict__ dst, int n4) {
    int i = blockIdx.x * 256 + threadIdx.x;
    int stride = gridDim.x * 256;
    for (; i < n4; i += stride) {
        float4 v = src[i];
        uint2 o;
        o.x = (uint)f2bf(v.x) | ((uint)f2bf(v.y) << 16);
        o.y = (uint)f2bf(v.z) | ((uint)f2bf(v.w) << 16);
        *(uint2*)(dst + (size_t)i * 4) = o;
    }
}

// ---------------- 2048x2048 bf16 transpose (once, for Wq^T) ----------------
__global__ __launch_bounds__(256) void transpose_bf16_kernel(const ushort* __restrict__ src,
                                                             ushort* __restrict__ dst) {
    __shared__ ushort t[64][72];
    int bx = blockIdx.x & 31, by = blockIdx.x >> 5;
    int r0 = by * 64, c0 = bx * 64;
    int tid = threadIdx.x;
    int lr = tid >> 3;
    int lc = (tid & 7) * 8;
#pragma unroll
    for (int p = 0; p < 2; ++p) {
        int rr = p * 32 + lr;
        bf16x8 v = *(const bf16x8*)(src + (size_t)(r0 + rr) * 2048 + c0 + lc);
#pragma unroll
        for (int j = 0; j < 8; ++j) t[lc + j][rr] = (ushort)v[j];
    }
    __syncthreads();
#pragma unroll
    for (int p = 0; p < 2; ++p) {
        int rr = p * 32 + lr;
        *(bf16x8*)(dst + (size_t)(c0 + rr) * 2048 + r0 + lc) = *(const bf16x8*)&t[rr][lc];
    }
}

// ---------------- logits v5: 8 rows/block, per-slot streamed reduction -----------
// BIT-EXACT per row to the passing R4/R6 kernels: same xw products, same 8-term
// dot expression, same 6-level wave_sum butterfly, same cross-wave add order
// (red[0]+red[1]+red[2]+red[3]), same rsq/fma. Rows-per-block is a free schedule
// parameter (passed with 1 and 4 rows). Streaming the per-slot wave_sum keeps
// VGPRs flat while doubling rows (halves compete_w re-reads, 2x ILP in trees).
// DO NOT change any arithmetic: logits bits feed top-k (order-statistic
// discontinuity); R5 failed from a 1e-7-level summation-order change.
__global__ __launch_bounds__(256) void logits_kernel(
    const float* __restrict__ x, const float* __restrict__ cw,
    const float* __restrict__ cb, const float* __restrict__ wpre,
    float* __restrict__ logits_t) {
    int blk = blockIdx.x;              // 1024 blocks, 8 rows each
    int b = blk >> 8;                  // 256 blocks per batch
    int l0 = (blk & 255) << 3;
    int tid = threadIdx.x;
    int i0 = tid * 8;
    float4 w0 = *(const float4*)(wpre + i0);
    float4 w1 = *(const float4*)(wpre + i0 + 4);
    float wv[8] = {w0.x, w0.y, w0.z, w0.w, w1.x, w1.y, w1.z, w1.w};
    float xw[8][8];
    float ss[8];
#pragma unroll
    for (int r = 0; r < 8; ++r) {
        const float* xr = x + ((size_t)(b * LSEQ + l0 + r)) * D;
        float4 a0 = *(const float4*)(xr + i0);
        float4 a1 = *(const float4*)(xr + i0 + 4);
        float xv[8] = {a0.x, a0.y, a0.z, a0.w, a1.x, a1.y, a1.z, a1.w};
        float s0 = 0.f;
#pragma unroll
        for (int j = 0; j < 8; ++j) { s0 += xv[j] * xv[j]; xw[r][j] = xv[j] * wv[j]; }
        ss[r] = s0;
    }
#pragma unroll
    for (int r = 0; r < 8; ++r) ss[r] = wave_sum(ss[r]);
    __shared__ float red[4][NSLOT][8];
    __shared__ float redss[4][8];
    int lane = tid & 63, w = tid >> 6;
    if (lane == 0) {
#pragma unroll
        for (int r = 0; r < 8; ++r) redss[w][r] = ss[r];
    }
#pragma unroll 2
    for (int s = 0; s < NSLOT; ++s) {
        const float* cwr = cw + (size_t)s * D + i0;
        float4 c0 = *(const float4*)(cwr);
        float4 c1 = *(const float4*)(cwr + 4);
        float acc[8];
#pragma unroll
        for (int r = 0; r < 8; ++r)
            acc[r] = xw[r][0] * c0.x + xw[r][1] * c0.y + xw[r][2] * c0.z + xw[r][3] * c0.w +
                     xw[r][4] * c1.x + xw[r][5] * c1.y + xw[r][6] * c1.z + xw[r][7] * c1.w;
#pragma unroll
        for (int r = 0; r < 8; ++r) acc[r] = wave_sum(acc[r]);
        if (lane == 0) {
#pragma unroll
            for (int r = 0; r < 8; ++r) red[w][s][r] = acc[r];
        }
    }
    __syncthreads();
    if (tid < 128) {
        int s = tid >> 3, r = tid & 7;
        float tot = red[0][s][r] + red[1][s][r] + red[2][s][r] + red[3][s][r];
        float s2 = redss[0][r] + redss[1][r] + redss[2][r] + redss[3][r];
        float rsq = 1.0f / sqrtf(s2 * (1.0f / (float)D) + EPSV);
        logits_t[((size_t)(b * NSLOT + s)) * LSEQ + l0 + r] = tot * rsq + cb[s];
    }
}

// ---------------- top-4 + softmax + weighted row gather (xbar, bf16) ----------------
__global__ __launch_bounds__(256) void topk_xbar_kernel(
    const float* __restrict__ logits_t, const float* __restrict__ x,
    ushort* __restrict__ xbar_b) {
    int bs = blockIdx.x;
    int b = bs >> 4;
    const float* lr = logits_t + (size_t)bs * LSEQ;
    int tid = threadIdx.x, lane = tid & 63, w = tid >> 6;
    __shared__ float rv[4];
    __shared__ int ri[4];
    __shared__ float selv[4];
    __shared__ int seli[4];
    int i0 = tid * 8;
    float myv[8];
#pragma unroll
    for (int j = 0; j < 8; ++j) myv[j] = lr[i0 + j];
    int chosen[4];
    for (int p = 0; p < 4; ++p) {
        float bv = -3.4e38f;
        int bi = 0x7fffffff;
#pragma unroll
        for (int j = 0; j < 8; ++j) {
            int i = i0 + j;
            bool skip = false;
            for (int q = 0; q < p; ++q) skip = skip || (i == chosen[q]);
            float v = myv[j];
            if (!skip && (v > bv || (v == bv && i < bi))) { bv = v; bi = i; }
        }
#pragma unroll
        for (int off = 1; off < 64; off <<= 1) {
            float ov = __shfl_xor(bv, off, 64);
            int oi = __shfl_xor(bi, off, 64);
            if (ov > bv || (ov == bv && oi < bi)) { bv = ov; bi = oi; }
        }
        if (lane == 0) { rv[w] = bv; ri[w] = bi; }
        __syncthreads();
        if (tid == 0) {
            float fv = rv[0];
            int fi = ri[0];
            for (int q = 1; q < 4; ++q)
                if (rv[q] > fv || (rv[q] == fv && ri[q] < fi)) { fv = rv[q]; fi = ri[q]; }
            selv[p] = fv;
            seli[p] = fi;
        }
        __syncthreads();
        chosen[p] = seli[p];
    }
    float vals[4];
#pragma unroll
    for (int p = 0; p < 4; ++p) vals[p] = selv[p];
    float mx = vals[0];   // first pick is the max
    float e[4], den = 0.f;
#pragma unroll
    for (int p = 0; p < 4; ++p) { e[p] = expf(vals[p] - mx); den += e[p]; }
    float inv = 1.0f / den;
    const float* xr0 = x + ((size_t)b * LSEQ + chosen[0]) * D;
    const float* xr1 = x + ((size_t)b * LSEQ + chosen[1]) * D;
    const float* xr2 = x + ((size_t)b * LSEQ + chosen[2]) * D;
    const float* xr3 = x + ((size_t)b * LSEQ + chosen[3]) * D;
    float s[8];
#pragma unroll
    for (int j = 0; j < 8; ++j) {
        int i = i0 + j;
        s[j] = (e[0] * xr0[i] + e[1] * xr1[i] + e[2] * xr2[i] + e[3] * xr3[i]) * inv;
    }
    uint4 o;
    o.x = (uint)f2bf(s[0]) | ((uint)f2bf(s[1]) << 16);
    o.y = (uint)f2bf(s[2]) | ((uint)f2bf(s[3]) << 16);
    o.z = (uint)f2bf(s[4]) | ((uint)f2bf(s[5]) << 16);
    o.w = (uint)f2bf(s[6]) | ((uint)f2bf(s[7]) << 16);
    *(uint4*)(xbar_b + (size_t)bs * D + i0) = o;
}

// ---------------- ws = rms(ws_prev + written) (+bf16 copy) ----------------
__global__ __launch_bounds__(256) void ws_update_kernel(
    const float* __restrict__ written, const float* __restrict__ ws_prev,
    const float* __restrict__ workspace0, int first,
    const float* __restrict__ wpost, float* __restrict__ ws_out,
    ushort* __restrict__ ws_b) {
    int bs = blockIdx.x;
    int s = bs & (NSLOT - 1);
    int tid = threadIdx.x;
    int i0 = tid * 8;
    const float* prev = first ? (workspace0 + (size_t)s * D) : (ws_prev + (size_t)bs * D);
    const float* wr = written + (size_t)bs * D;
    float4 p0 = *(const float4*)(prev + i0);
    float4 p1 = *(const float4*)(prev + i0 + 4);
    float4 q0 = *(const float4*)(wr + i0);
    float4 q1 = *(const float4*)(wr + i0 + 4);
    float t[8] = {p0.x + q0.x, p0.y + q0.y, p0.z + q0.z, p0.w + q0.w,
                  p1.x + q1.x, p1.y + q1.y, p1.z + q1.z, p1.w + q1.w};
    float ss = 0.f;
#pragma unroll
    for (int j = 0; j < 8; ++j) ss += t[j] * t[j];
    ss = wave_sum(ss);
    __shared__ float sb[4];
    if ((tid & 63) == 0) sb[tid >> 6] = ss;
    __syncthreads();
    ss = sb[0] + sb[1] + sb[2] + sb[3];
    float rsq = 1.0f / sqrtf(ss * (1.0f / (float)D) + EPSV);
    float4 w0 = *(const float4*)(wpost + i0);
    float4 w1 = *(const float4*)(wpost + i0 + 4);
    float wv[8] = {w0.x, w0.y, w0.z, w0.w, w1.x, w1.y, w1.z, w1.w};
    float o[8];
#pragma unroll
    for (int j = 0; j < 8; ++j) o[j] = t[j] * rsq * wv[j];
    float4 r0 = {o[0], o[1], o[2], o[3]};
    float4 r1 = {o[4], o[5], o[6], o[7]};
    *(float4*)(ws_out + (size_t)bs * D + i0) = r0;
    *(float4*)(ws_out + (size_t)bs * D + i0 + 4) = r1;
    uint4 ob;
    ob.x = (uint)f2bf(o[0]) | ((uint)f2bf(o[1]) << 16);
    ob.y = (uint)f2bf(o[2]) | ((uint)f2bf(o[3]) << 16);
    ob.z = (uint)f2bf(o[4]) | ((uint)f2bf(o[5]) << 16);
    ob.w = (uint)f2bf(o[6]) | ((uint)f2bf(o[7]) << 16);
    *(uint4*)(ws_b + (size_t)bs * D + i0) = ob;
}

// ---------------- x = rms(x + attn_out) (+bf16 copy) ----------------
__global__ __launch_bounds__(256) void resid_rms_kernel(
    const float* __restrict__ x_src, const float* __restrict__ ao,
    const float* __restrict__ wpost, float* __restrict__ x_dst,
    ushort* __restrict__ xb) {
    int row = blockIdx.x;
    int tid = threadIdx.x;
    int i0 = tid * 8;
    const float* xr = x_src + (size_t)row * D;
    const float* ar = ao + (size_t)row * D;
    float4 p0 = *(const float4*)(xr + i0);
    float4 p1 = *(const float4*)(xr + i0 + 4);
    float4 q0 = *(const float4*)(ar + i0);
    float4 q1 = *(const float4*)(ar + i0 + 4);
    float t[8] = {p0.x + q0.x, p0.y + q0.y, p0.z + q0.z, p0.w + q0.w,
                  p1.x + q1.x, p1.y + q1.y, p1.z + q1.z, p1.w + q1.w};
    float ss = 0.f;
#pragma unroll
    for (int j = 0; j < 8; ++j) ss += t[j] * t[j];
    ss = wave_sum(ss);
    __shared__ float sb[4];
    if ((tid & 63) == 0) sb[tid >> 6] = ss;
    __syncthreads();
    ss = sb[0] + sb[1] + sb[2] + sb[3];
    float rsq = 1.0f / sqrtf(ss * (1.0f / (float)D) + EPSV);
    float4 w0 = *(const float4*)(wpost + i0);
    float4 w1 = *(const float4*)(wpost + i0 + 4);
    float wv[8] = {w0.x, w0.y, w0.z, w0.w, w1.x, w1.y, w1.z, w1.w};
    float o[8];
#pragma unroll
    for (int j = 0; j < 8; ++j) o[j] = t[j] * rsq * wv[j];
    float4 r0 = {o[0], o[1], o[2], o[3]};
    float4 r1 = {o[4], o[5], o[6], o[7]};
    *(float4*)(x_dst + (size_t)row * D + i0) = r0;
    *(float4*)(x_dst + (size_t)row * D + i0 + 4) = r1;
    uint4 ob;
    ob.x = (uint)f2bf(o[0]) | ((uint)f2bf(o[1]) << 16);
    ob.y = (uint)f2bf(o[2]) | ((uint)f2bf(o[3]) << 16);
    ob.z = (uint)f2bf(o[4]) | ((uint)f2bf(o[5]) << 16);
    ob.w = (uint)f2bf(o[6]) | ((uint)f2bf(o[7]) << 16);
    *(uint4*)(xb + (size_t)row * D + i0) = ob;
}

// ---------------- cbias[b*512+hs] = sum_d K[b,h,s,d]*bq[h*64+d] ----------------
__global__ __launch_bounds__(256) void cbias_kernel(const ushort* __restrict__ kb16,
                                                    const float* __restrict__ bq,
                                                    float* __restrict__ cb) {
    int i = blockIdx.x * 256 + threadIdx.x;   // 0..2047
    int hs = i & 511;
    int h = hs >> 4;
    const ushort* kr = kb16 + (size_t)i * 64;
    const float* bb = bq + h * 64;
    float acc = 0.f;
#pragma unroll
    for (int d = 0; d < 64; ++d)
        acc += __uint_as_float(((uint)kr[d]) << 16) * bb[d];
    cb[i] = acc;
}

// ---------------- grouped 16x64 GEMM: per (b,h): C[16x2048] = A[16x64] @ Bslice^T --
template <int TRANS>
__global__ __launch_bounds__(256) void grouped16_kernel(
    const ushort* __restrict__ Abase, const ushort* __restrict__ Bmat,
    ushort* __restrict__ Cout) {
    int blk = blockIdx.x;           // g*8 + nt   (1024 blocks)
    int g = blk >> 3;               // 0..127 = b*32+h
    int nt = blk & 7;
    int h = g & 31;
    int hoff = h * 64;
    int tid = threadIdx.x, lane = tid & 63, wv = tid >> 6;
    int j0 = nt * 256 + wv * 64;
    int rr = lane & 15, ko = lane >> 4;
    const ushort* A = Abase + (size_t)g * 16 * 64;
    bf16x8 af0 = *(const bf16x8*)(A + rr * 64 + ko * 8);
    bf16x8 af1 = *(const bf16x8*)(A + rr * 64 + 32 + ko * 8);
    f32x4 acc[4];
    f32x4 zero = {0.f, 0.f, 0.f, 0.f};
#pragma unroll
    for (int nf = 0; nf < 4; ++nf) acc[nf] = zero;
#pragma unroll
    for (int nf = 0; nf < 4; ++nf) {
        int j = j0 + nf * 16 + rr;
        bf16x8 b0 = *(const bf16x8*)(Bmat + (size_t)j * 2048 + hoff + ko * 8);
        bf16x8 b1 = *(const bf16x8*)(Bmat + (size_t)j * 2048 + hoff + 32 + ko * 8);
        acc[nf] = __builtin_amdgcn_mfma_f32_16x16x32_bf16(af0, b0, acc[nf], 0, 0, 0);
        acc[nf] = __builtin_amdgcn_mfma_f32_16x16x32_bf16(af1, b1, acc[nf], 0, 0, 0);
    }
#pragma unroll
    for (int nf = 0; nf < 4; ++nf)
#pragma unroll
        for (int r = 0; r < 4; ++r) {
            int s = ko * 4 + r;
            int j = j0 + nf * 16 + rr;
            ushort v = f2bf(acc[nf][r]);
            if (TRANS) Cout[(size_t)j * 2048 + g * 16 + s] = v;
            else       Cout[(size_t)(g * 16 + s) * 2048 + j] = v;
        }
}

// ---------------- attn softmax: A_att = softmax_s((qlog0+qlog1+cbias)*0.125) ------
__global__ __launch_bounds__(256) void attn_sm_kernel(
    const float* __restrict__ qlog, const float* __restrict__ cb,
    ushort* __restrict__ aatt) {
    int blk = blockIdx.x;               // 1024 blocks x 8 rows
    int tid = threadIdx.x;
    int l = blk * 8 + (tid >> 5);
    int b = l >> 11;
    int h = tid & 31;
    const float* q0 = qlog + (size_t)l * 512 + h * 16;
    const float* q1 = q0 + (size_t)BL * 512;
    const float* c = cb + b * 512 + h * 16;
    float p[16];
#pragma unroll
    for (int i = 0; i < 16; i += 4) {
        float4 v0 = *(const float4*)(q0 + i);
        float4 v1 = *(const float4*)(q1 + i);
        float4 cc = *(const float4*)(c + i);
        p[i]     = v0.x + v1.x + cc.x;
        p[i + 1] = v0.y + v1.y + cc.y;
        p[i + 2] = v0.z + v1.z + cc.z;
        p[i + 3] = v0.w + v1.w + cc.w;
    }
    float mx = p[0];
#pragma unroll
    for (int s = 1; s < 16; ++s) mx = fmaxf(mx, p[s]);
    float den = 0.f;
#pragma unroll
    for (int s = 0; s < 16; ++s) { p[s] = __expf((p[s] - mx) * 0.125f); den += p[s]; }
    float inv = 1.0f / den;
    uint4 o[2];
    uint* ow = (uint*)o;
#pragma unroll
    for (int i = 0; i < 8; ++i)
        ow[i] = (uint)f2bf(p[2 * i] * inv) | ((uint)f2bf(p[2 * i + 1] * inv) << 16);
    ushort* dst = aatt + (size_t)l * 512 + h * 16;
    *(uint4*)dst = o[0];
    *(uint4*)(dst + 8) = o[1];
}

// ---------------- tiny-M GEMM: one wave per 16x16 output tile, no LDS/barriers ----
template <int KVMODE>
__global__ __launch_bounds__(256) void gemm_tiny(
    const ushort* __restrict__ A, const ushort* __restrict__ Bw,
    const float* __restrict__ bias, float* __restrict__ C,
    int M, int N, int K, ushort* __restrict__ kvk, ushort* __restrict__ kvv) {
    int gw = (blockIdx.x * 256 + threadIdx.x) >> 6;
    int lane = threadIdx.x & 63;
    int ntiles = N >> 4;
    int nt = gw % ntiles, mt = gw / ntiles;
    int rr = lane & 15, ko = lane >> 4;
    const ushort* Ar = A + (size_t)(mt * 16 + rr) * K;
    const ushort* Br = Bw + (size_t)(nt * 16 + rr) * K;
    f32x4 acc = {0.f, 0.f, 0.f, 0.f};
    int NT = K / 32;
#pragma unroll 8
    for (int t = 0; t < NT; ++t) {
        bf16x8 af = *(const bf16x8*)(Ar + t * 32 + ko * 8);
        bf16x8 bf = *(const bf16x8*)(Br + t * 32 + ko * 8);
        acc = __builtin_amdgcn_mfma_f32_16x16x32_bf16(af, bf, acc, 0, 0, 0);
    }
    int col = nt * 16 + rr;
    float bsv = bias ? bias[col] : 0.f;
#pragma unroll
    for (int r = 0; r < 4; ++r) {
        int rowi = mt * 16 + ko * 4 + r;
        float v = acc[r] + bsv;
        if (KVMODE) {
            int b = rowi >> 4, s = rowi & 15;
            int c2 = (col < 2048) ? col : col - 2048;
            int h = c2 >> 6, d = c2 & 63;
            size_t dst = (((size_t)(b * NHEAD + h)) * NSLOT + s) * HDIM + d;
            if (col < 2048) kvk[dst] = f2bf(v);
            else            kvv[dst] = f2bf(v);
        } else {
            C[(size_t)rowi * N + col] = v;
        }
    }
}

// ---------------- bf16 MFMA GEMM: C[m,n] = sum_k A[m,k]*Bw[n,k] + bias[n] ----------
template <int BM>
__global__ __launch_bounds__(256) void gemm_bt(
    const ushort* __restrict__ A, const ushort* __restrict__ Bw,
    const float* __restrict__ bias, float* __restrict__ C,
    int M, int N, int K, size_t bOff, int bStride, int aStride,
    int zA, int zB, size_t zC) {
    constexpr int BN = 128, BK = 32;
    constexpr int MF = BM / 32;
    constexpr int APASS = (BM * BK / 8) / 256;
    __shared__ short lds[2][(BM + BN) * BK];
    int tid = threadIdx.x;
    int lane = tid & 63, w = tid >> 6;
    int wr = w >> 1, wc = w & 1;
    int tn = blockIdx.x * BN;
    int tm = blockIdx.y * BM;
    int ksl = blockIdx.z;
    A += (size_t)ksl * zA;
    Bw += (size_t)ksl * zB + (size_t)(tm >> 11) * bOff;
    C += (size_t)ksl * zC;
    f32x4 acc[MF][4];
    f32x4 zero = {0.f, 0.f, 0.f, 0.f};
#pragma unroll
    for (int m = 0; m < MF; ++m)
#pragma unroll
        for (int n = 0; n < 4; ++n) acc[m][n] = zero;
    int NT = K / BK;

    auto stage = [&](int buf, int t) {
        int kt = t * BK;
#pragma unroll
        for (int p = 0; p < APASS; ++p) {
            int cb = p * 256 + w * 64;
            int c = cb + lane;
            int r = c >> 2;
            int k8 = (c & 3) * 8;
            int gr = tm + r;
            if (gr >= M) gr = M - 1;
            gl_lds16(A + (size_t)gr * aStride + kt + k8, (void*)&lds[buf][cb * 8]);
        }
#pragma unroll
        for (int p = 0; p < 2; ++p) {
            int cb = p * 256 + w * 64;
            int c = cb + lane;
            int r = c >> 2;
            int k8 = (c & 3) * 8;
            gl_lds16(Bw + (size_t)(tn + r) * bStride + kt + k8,
                     (void*)&lds[buf][BM * BK + cb * 8]);
        }
    };
    stage(0, 0);
    for (int t = 0; t < NT; ++t) {
        __syncthreads();
        if (t + 1 < NT) stage((t + 1) & 1, t + 1);
        const short* Ab = &lds[t & 1][0];
        const short* Bb = &lds[t & 1][BM * BK];
        int ko = (lane >> 4) * 8;
        int rr = lane & 15;
        bf16x8 af[MF], bfr[4];
#pragma unroll
        for (int m = 0; m < MF; ++m)
            af[m] = *(const bf16x8*)&Ab[(wr * (MF * 16) + m * 16 + rr) * BK + ko];
#pragma unroll
        for (int n = 0; n < 4; ++n)
            bfr[n] = *(const bf16x8*)&Bb[(wc * 64 + n * 16 + rr) * BK + ko];
#pragma unroll
        for (int m = 0; m < MF; ++m)
#pragma unroll
            for (int n = 0; n < 4; ++n)
                acc[m][n] = __builtin_amdgcn_mfma_f32_16x16x32_bf16(af[m], bfr[n],
                                                                    acc[m][n], 0, 0, 0);
    }
#pragma unroll
    for (int m = 0; m < MF; ++m) {
#pragma unroll
        for (int n = 0; n < 4; ++n) {
            int col = tn + wc * 64 + n * 16 + (lane & 15);
            float bsv = bias ? bias[col] : 0.f;
#pragma unroll
            for (int r = 0; r < 4; ++r) {
                int rowi = tm + wr * (MF * 16) + m * 16 + (lane >> 4) * 4 + r;
                if (rowi < M) C[(size_t)rowi * N + col] = acc[m][n][r] + bsv;
            }
        }
    }
}

extern "C" void kernel_launch(void* const* d_in, const int* in_sizes, int n_in,
                              void* d_out, int out_size, void* d_ws, size_t ws_size,
                              hipStream_t stream) {
    const float* x_in       = (const float*)d_in[0];
    const float* workspace  = (const float*)d_in[1];
    const float* compete_w  = (const float*)d_in[2];
    const float* compete_b  = (const float*)d_in[3];
    const float* write_w    = (const float*)d_in[4];
    const float* write_b    = (const float*)d_in[5];
    const float* in_proj_w  = (const float*)d_in[6];
    const float* in_proj_b  = (const float*)d_in[7];
    const float* out_proj_w = (const float*)d_in[8];
    const float* out_proj_b = (const float*)d_in[9];
    const float* norm_pre_w  = (const float*)d_in[12];
    const float* norm_post_w = (const float*)d_in[13];
    float* xout = (float*)d_out;

    char* base = (char*)d_ws;
    size_t off = 0;
    auto alloc = [&](size_t bytes) {
        void* p = base + off;
        off += (bytes + 255) & ~(size_t)255;
        return p;
    };
    ushort* xb      = (ushort*)alloc((size_t)BL * D * 2);
    float*  qbuf    = (float*) alloc((size_t)BL * D * 4);     // x_b (f32)
    float*  logits  = (float*) alloc((size_t)BATCH * NSLOT * LSEQ * 4);
    ushort* xbar    = (ushort*)alloc((size_t)BATCH * NSLOT * D * 2);
    float*  written = (float*) alloc((size_t)BATCH * NSLOT * D * 4);
    float*  wsbuf   = (float*) alloc((size_t)BATCH * NSLOT * D * 4);
    ushort* wsb     = (ushort*)alloc((size_t)BATCH * NSLOT * D * 2);
    ushort* ipb     = (ushort*)alloc((size_t)3 * D * D * 2);
    ushort* wob     = (ushort*)alloc((size_t)D * D * 2);
    ushort* wwb     = (ushort*)alloc((size_t)D * D * 2);
    ushort* wqt     = (ushort*)alloc((size_t)D * D * 2);      // Wq^T bf16
    ushort* kb16    = (ushort*)alloc((size_t)BATCH * NHEAD * NSLOT * HDIM * 2);
    ushort* vb16    = (ushort*)alloc((size_t)BATCH * NHEAD * NSLOT * HDIM * 2);
    ushort* ktil    = (ushort*)alloc((size_t)BATCH * 512 * D * 2);   // K~ rows b*512+hs
    ushort* wtilT   = (ushort*)alloc((size_t)D * BATCH * 512 * 2);   // W~^T rows j
    float*  qlog    = (float*) alloc((size_t)2 * BL * 512 * 4);      // 2 K-split planes
    ushort* aatt    = (ushort*)alloc((size_t)BL * 512 * 2);
    float*  cbias   = (float*) alloc((size_t)BATCH * 512 * 4);
    (void)ws_size; (void)in_sizes; (void)n_in; (void)out_size;

    conv_bf16_kernel<<<2048, 256, 0, stream>>>((const float4*)in_proj_w, ipb, 3 * D * D / 4);
    conv_bf16_kernel<<<2048, 256, 0, stream>>>((const float4*)out_proj_w, wob, D * D / 4);
    conv_bf16_kernel<<<2048, 256, 0, stream>>>((const float4*)write_w, wwb, D * D / 4);
    conv_bf16_kernel<<<2048, 256, 0, stream>>>((const float4*)x_in, xb, BL * D / 4);
    transpose_bf16_kernel<<<1024, 256, 0, stream>>>(ipb, wqt);   // Wq^T (q rows 0..D)

    for (int it = 0; it < 2; ++it) {
        const float* xs = it ? (const float*)xout : x_in;
        logits_kernel<<<BL / 8, 256, 0, stream>>>(xs, compete_w, compete_b, norm_pre_w,
                                                  logits);
        topk_xbar_kernel<<<BATCH * NSLOT, 256, 0, stream>>>(logits, xs, xbar);
        // written = xbar @ wwb^T + write_b   (64x2048, K=2048) — 512 waves
        gemm_tiny<0><<<128, 256, 0, stream>>>(xbar, wwb, write_b, written,
                                              BATCH * NSLOT, D, D,
                                              (ushort*)nullptr, (ushort*)nullptr);
        ws_update_kernel<<<BATCH * NSLOT, 256, 0, stream>>>(written, wsbuf, workspace,
                                                            it == 0 ? 1 : 0, norm_post_w,
                                                            wsbuf, wsb);
        // kv = wsb @ Wkv^T + bkv  (64x4096, K=2048) — 1024 waves, scatter to kb/vb
        gemm_tiny<1><<<256, 256, 0, stream>>>(wsb, ipb + (size_t)D * D, in_proj_b + D,
                                              (float*)nullptr, BATCH * NSLOT, 2 * D, D,
                                              kb16, vb16);
        cbias_kernel<<<8, 256, 0, stream>>>(kb16, in_proj_b, cbias);
        grouped16_kernel<0><<<1024, 256, 0, stream>>>(kb16, wqt, ktil);
        grouped16_kernel<1><<<1024, 256, 0, stream>>>(vb16, wob, wtilT);
        // qlog[z][l, hs] = xb[l, zK:zK+1024] . K~[b,hs, zK:zK+1024]  (split-K=2)
        gemm_bt<64><<<dim3(512 / 128, BL / 64, 2), 256, 0, stream>>>(
            xb, ktil, (const float*)nullptr, qlog, BL, 512, D / 2,
            (size_t)512 * D, D, D, D / 2, D / 2, (size_t)BL * 512);
        attn_sm_kernel<<<BL / 8, 256, 0, stream>>>(qlog, cbias, aatt);
        // x_b[l, j] = sum_hs aatt[l,hs] * W~T[j, b*512+hs] + out_proj_b[j]
        gemm_bt<64><<<dim3(D / 128, BL / 64), 256, 0, stream>>>(
            aatt, wtilT, out_proj_b, qbuf, BL, D, 512,
            (size_t)512, D, 512, 0, 0, 0);
        resid_rms_kernel<<<BL, 256, 0, stream>>>(xs, qbuf, norm_post_w, xout, xb);
    }
}

// Round 16
// 535.169 us; speedup vs baseline: 1.0316x; 1.0316x over previous
//
#include <hip/hip_runtime.h>
#include <stdint.h>

#define D 2048
#define LSEQ 2048
#define BATCH 4
#define BL (BATCH * LSEQ)   // 8192 rows
#define NSLOT 16
#define NHEAD 32
#define HDIM 64
#define EPSV 1e-6f

typedef __attribute__((ext_vector_type(8))) short bf16x8;
typedef __attribute__((ext_vector_type(4))) float f32x4;

static __device__ __forceinline__ ushort f2bf(float f) {
    uint32_t u = __float_as_uint(f);
    u += 0x7fffu + ((u >> 16) & 1u);   // RNE
    return (ushort)(u >> 16);
}

static __device__ __forceinline__ float wave_sum(float v) {
#pragma unroll
    for (int off = 32; off > 0; off >>= 1) v += __shfl_xor(v, off, 64);
    return v;
}

static __device__ __forceinline__ void gl_lds16(const void* g, void* l) {
    __builtin_amdgcn_global_load_lds(
        (__attribute__((address_space(1))) uint32_t*)(uintptr_t)g,
        (__attribute__((address_space(3))) uint32_t*)(uint32_t)(uintptr_t)l,
        16, 0, 0);
}

// ---------------- weight convert f32 -> bf16 ----------------
__global__ __launch_bounds__(256) void conv_bf16_kernel(const float4* __restrict__ src,
                                                        ushort* __restrict__ dst, int n4) {
    int i = blockIdx.x * 256 + threadIdx.x;
    int stride = gridDim.x * 256;
    for (; i < n4; i += stride) {
        float4 v = src[i];
        uint2 o;
        o.x = (uint)f2bf(v.x) | ((uint)f2bf(v.y) << 16);
        o.y = (uint)f2bf(v.z) | ((uint)f2bf(v.w) << 16);
        *(uint2*)(dst + (size_t)i * 4) = o;
    }
}

// ---------------- 2048x2048 bf16 transpose (once, for Wq^T) ----------------
__global__ __launch_bounds__(256) void transpose_bf16_kernel(const ushort* __restrict__ src,
                                                             ushort* __restrict__ dst) {
    __shared__ ushort t[64][72];
    int bx = blockIdx.x & 31, by = blockIdx.x >> 5;
    int r0 = by * 64, c0 = bx * 64;
    int tid = threadIdx.x;
    int lr = tid >> 3;
    int lc = (tid & 7) * 8;
#pragma unroll
    for (int p = 0; p < 2; ++p) {
        int rr = p * 32 + lr;
        bf16x8 v = *(const bf16x8*)(src + (size_t)(r0 + rr) * 2048 + c0 + lc);
#pragma unroll
        for (int j = 0; j < 8; ++j) t[lc + j][rr] = (ushort)v[j];
    }
    __syncthreads();
#pragma unroll
    for (int p = 0; p < 2; ++p) {
        int rr = p * 32 + lr;
        *(bf16x8*)(dst + (size_t)(c0 + rr) * 2048 + r0 + lc) = *(const bf16x8*)&t[rr][lc];
    }
}

// ---------------- logits v6: 4 rows/block streamed, grid 2048 (8192 waves) -------
// BIT-EXACT per row to the passing R4/R6/R15 kernels: same xw products, same
// 8-term dot expression, same 6-level wave_sum butterfly, same cross-wave add
// order (red[0]+red[1]+red[2]+red[3]), same rsq/fma. Rows-per-block is a free
// schedule parameter (passed with 1, 4, and 8 rows). 4 rows doubles the grid
// (v5's 4096 waves capped occupancy at ~34%); streaming keeps VGPRs low.
// DO NOT change any arithmetic: logits bits feed top-k (order-statistic
// discontinuity); R5 failed from a 1e-7-level summation-order change.
__global__ __launch_bounds__(256) void logits_kernel(
    const float* __restrict__ x, const float* __restrict__ cw,
    const float* __restrict__ cb, const float* __restrict__ wpre,
    float* __restrict__ logits_t) {
    int blk = blockIdx.x;              // 2048 blocks, 4 rows each
    int b = blk >> 9;                  // 512 blocks per batch
    int l0 = (blk & 511) << 2;
    int tid = threadIdx.x;
    int i0 = tid * 8;
    float4 w0 = *(const float4*)(wpre + i0);
    float4 w1 = *(const float4*)(wpre + i0 + 4);
    float wv[8] = {w0.x, w0.y, w0.z, w0.w, w1.x, w1.y, w1.z, w1.w};
    float xw[4][8];
    float ss[4];
#pragma unroll
    for (int r = 0; r < 4; ++r) {
        const float* xr = x + ((size_t)(b * LSEQ + l0 + r)) * D;
        float4 a0 = *(const float4*)(xr + i0);
        float4 a1 = *(const float4*)(xr + i0 + 4);
        float xv[8] = {a0.x, a0.y, a0.z, a0.w, a1.x, a1.y, a1.z, a1.w};
        float s0 = 0.f;
#pragma unroll
        for (int j = 0; j < 8; ++j) { s0 += xv[j] * xv[j]; xw[r][j] = xv[j] * wv[j]; }
        ss[r] = s0;
    }
#pragma unroll
    for (int r = 0; r < 4; ++r) ss[r] = wave_sum(ss[r]);
    __shared__ float red[4][NSLOT][4];
    __shared__ float redss[4][4];
    int lane = tid & 63, w = tid >> 6;
    if (lane == 0) {
#pragma unroll
        for (int r = 0; r < 4; ++r) redss[w][r] = ss[r];
    }
#pragma unroll 2
    for (int s = 0; s < NSLOT; ++s) {
        const float* cwr = cw + (size_t)s * D + i0;
        float4 c0 = *(const float4*)(cwr);
        float4 c1 = *(const float4*)(cwr + 4);
        float acc[4];
#pragma unroll
        for (int r = 0; r < 4; ++r)
            acc[r] = xw[r][0] * c0.x + xw[r][1] * c0.y + xw[r][2] * c0.z + xw[r][3] * c0.w +
                     xw[r][4] * c1.x + xw[r][5] * c1.y + xw[r][6] * c1.z + xw[r][7] * c1.w;
#pragma unroll
        for (int r = 0; r < 4; ++r) acc[r] = wave_sum(acc[r]);
        if (lane == 0) {
#pragma unroll
            for (int r = 0; r < 4; ++r) red[w][s][r] = acc[r];
        }
    }
    __syncthreads();
    if (tid < 64) {
        int s = tid >> 2, r = tid & 3;
        float tot = red[0][s][r] + red[1][s][r] + red[2][s][r] + red[3][s][r];
        float s2 = redss[0][r] + redss[1][r] + redss[2][r] + redss[3][r];
        float rsq = 1.0f / sqrtf(s2 * (1.0f / (float)D) + EPSV);
        logits_t[((size_t)(b * NSLOT + s)) * LSEQ + l0 + r] = tot * rsq + cb[s];
    }
}

// ---------------- top-4 + softmax + weighted row gather (xbar, bf16) ----------------
__global__ __launch_bounds__(256) void topk_xbar_kernel(
    const float* __restrict__ logits_t, const float* __restrict__ x,
    ushort* __restrict__ xbar_b) {
    int bs = blockIdx.x;
    int b = bs >> 4;
    const float* lr = logits_t + (size_t)bs * LSEQ;
    int tid = threadIdx.x, lane = tid & 63, w = tid >> 6;
    __shared__ float rv[4];
    __shared__ int ri[4];
    __shared__ float selv[4];
    __shared__ int seli[4];
    int i0 = tid * 8;
    float myv[8];
#pragma unroll
    for (int j = 0; j < 8; ++j) myv[j] = lr[i0 + j];
    int chosen[4];
    for (int p = 0; p < 4; ++p) {
        float bv = -3.4e38f;
        int bi = 0x7fffffff;
#pragma unroll
        for (int j = 0; j < 8; ++j) {
            int i = i0 + j;
            bool skip = false;
            for (int q = 0; q < p; ++q) skip = skip || (i == chosen[q]);
            float v = myv[j];
            if (!skip && (v > bv || (v == bv && i < bi))) { bv = v; bi = i; }
        }
#pragma unroll
        for (int off = 1; off < 64; off <<= 1) {
            float ov = __shfl_xor(bv, off, 64);
            int oi = __shfl_xor(bi, off, 64);
            if (ov > bv || (ov == bv && oi < bi)) { bv = ov; bi = oi; }
        }
        if (lane == 0) { rv[w] = bv; ri[w] = bi; }
        __syncthreads();
        if (tid == 0) {
            float fv = rv[0];
            int fi = ri[0];
            for (int q = 1; q < 4; ++q)
                if (rv[q] > fv || (rv[q] == fv && ri[q] < fi)) { fv = rv[q]; fi = ri[q]; }
            selv[p] = fv;
            seli[p] = fi;
        }
        __syncthreads();
        chosen[p] = seli[p];
    }
    float vals[4];
#pragma unroll
    for (int p = 0; p < 4; ++p) vals[p] = selv[p];
    float mx = vals[0];   // first pick is the max
    float e[4], den = 0.f;
#pragma unroll
    for (int p = 0; p < 4; ++p) { e[p] = expf(vals[p] - mx); den += e[p]; }
    float inv = 1.0f / den;
    const float* xr0 = x + ((size_t)b * LSEQ + chosen[0]) * D;
    const float* xr1 = x + ((size_t)b * LSEQ + chosen[1]) * D;
    const float* xr2 = x + ((size_t)b * LSEQ + chosen[2]) * D;
    const float* xr3 = x + ((size_t)b * LSEQ + chosen[3]) * D;
    float s[8];
#pragma unroll
    for (int j = 0; j < 8; ++j) {
        int i = i0 + j;
        s[j] = (e[0] * xr0[i] + e[1] * xr1[i] + e[2] * xr2[i] + e[3] * xr3[i]) * inv;
    }
    uint4 o;
    o.x = (uint)f2bf(s[0]) | ((uint)f2bf(s[1]) << 16);
    o.y = (uint)f2bf(s[2]) | ((uint)f2bf(s[3]) << 16);
    o.z = (uint)f2bf(s[4]) | ((uint)f2bf(s[5]) << 16);
    o.w = (uint)f2bf(s[6]) | ((uint)f2bf(s[7]) << 16);
    *(uint4*)(xbar_b + (size_t)bs * D + i0) = o;
}

// ---------------- ws = rms(ws_prev + written) (+bf16 copy) ----------------
__global__ __launch_bounds__(256) void ws_update_kernel(
    const float* __restrict__ written, const float* __restrict__ ws_prev,
    const float* __restrict__ workspace0, int first,
    const float* __restrict__ wpost, float* __restrict__ ws_out,
    ushort* __restrict__ ws_b) {
    int bs = blockIdx.x;
    int s = bs & (NSLOT - 1);
    int tid = threadIdx.x;
    int i0 = tid * 8;
    const float* prev = first ? (workspace0 + (size_t)s * D) : (ws_prev + (size_t)bs * D);
    const float* wr = written + (size_t)bs * D;
    float4 p0 = *(const float4*)(prev + i0);
    float4 p1 = *(const float4*)(prev + i0 + 4);
    float4 q0 = *(const float4*)(wr + i0);
    float4 q1 = *(const float4*)(wr + i0 + 4);
    float t[8] = {p0.x + q0.x, p0.y + q0.y, p0.z + q0.z, p0.w + q0.w,
                  p1.x + q1.x, p1.y + q1.y, p1.z + q1.z, p1.w + q1.w};
    float ss = 0.f;
#pragma unroll
    for (int j = 0; j < 8; ++j) ss += t[j] * t[j];
    ss = wave_sum(ss);
    __shared__ float sb[4];
    if ((tid & 63) == 0) sb[tid >> 6] = ss;
    __syncthreads();
    ss = sb[0] + sb[1] + sb[2] + sb[3];
    float rsq = 1.0f / sqrtf(ss * (1.0f / (float)D) + EPSV);
    float4 w0 = *(const float4*)(wpost + i0);
    float4 w1 = *(const float4*)(wpost + i0 + 4);
    float wv[8] = {w0.x, w0.y, w0.z, w0.w, w1.x, w1.y, w1.z, w1.w};
    float o[8];
#pragma unroll
    for (int j = 0; j < 8; ++j) o[j] = t[j] * rsq * wv[j];
    float4 r0 = {o[0], o[1], o[2], o[3]};
    float4 r1 = {o[4], o[5], o[6], o[7]};
    *(float4*)(ws_out + (size_t)bs * D + i0) = r0;
    *(float4*)(ws_out + (size_t)bs * D + i0 + 4) = r1;
    uint4 ob;
    ob.x = (uint)f2bf(o[0]) | ((uint)f2bf(o[1]) << 16);
    ob.y = (uint)f2bf(o[2]) | ((uint)f2bf(o[3]) << 16);
    ob.z = (uint)f2bf(o[4]) | ((uint)f2bf(o[5]) << 16);
    ob.w = (uint)f2bf(o[6]) | ((uint)f2bf(o[7]) << 16);
    *(uint4*)(ws_b + (size_t)bs * D + i0) = ob;
}

// ---------------- x = rms(x + attn_out[bf16]) (+bf16 copy) ----------------
// ao is bf16 (written by the final GEMM); unpacked to f32 before the residual
// add. Smooth path: the bf16 rounding of x_b adds ~0.4% relative on x_b only.
__global__ __launch_bounds__(256) void resid_rms_kernel(
    const float* __restrict__ x_src, const ushort* __restrict__ ao,
    const float* __restrict__ wpost, float* __restrict__ x_dst,
    ushort* __restrict__ xb) {
    int row = blockIdx.x;
    int tid = threadIdx.x;
    int i0 = tid * 8;
    const float* xr = x_src + (size_t)row * D;
    uint4 av = *(const uint4*)(ao + (size_t)row * D + i0);
    float af[8];
    af[0] = __uint_as_float(av.x << 16);
    af[1] = __uint_as_float(av.x & 0xffff0000u);
    af[2] = __uint_as_float(av.y << 16);
    af[3] = __uint_as_float(av.y & 0xffff0000u);
    af[4] = __uint_as_float(av.z << 16);
    af[5] = __uint_as_float(av.z & 0xffff0000u);
    af[6] = __uint_as_float(av.w << 16);
    af[7] = __uint_as_float(av.w & 0xffff0000u);
    float4 p0 = *(const float4*)(xr + i0);
    float4 p1 = *(const float4*)(xr + i0 + 4);
    float t[8] = {p0.x + af[0], p0.y + af[1], p0.z + af[2], p0.w + af[3],
                  p1.x + af[4], p1.y + af[5], p1.z + af[6], p1.w + af[7]};
    float ss = 0.f;
#pragma unroll
    for (int j = 0; j < 8; ++j) ss += t[j] * t[j];
    ss = wave_sum(ss);
    __shared__ float sb[4];
    if ((tid & 63) == 0) sb[tid >> 6] = ss;
    __syncthreads();
    ss = sb[0] + sb[1] + sb[2] + sb[3];
    float rsq = 1.0f / sqrtf(ss * (1.0f / (float)D) + EPSV);
    float4 w0 = *(const float4*)(wpost + i0);
    float4 w1 = *(const float4*)(wpost + i0 + 4);
    float wv[8] = {w0.x, w0.y, w0.z, w0.w, w1.x, w1.y, w1.z, w1.w};
    float o[8];
#pragma unroll
    for (int j = 0; j < 8; ++j) o[j] = t[j] * rsq * wv[j];
    float4 r0 = {o[0], o[1], o[2], o[3]};
    float4 r1 = {o[4], o[5], o[6], o[7]};
    *(float4*)(x_dst + (size_t)row * D + i0) = r0;
    *(float4*)(x_dst + (size_t)row * D + i0 + 4) = r1;
    uint4 ob;
    ob.x = (uint)f2bf(o[0]) | ((uint)f2bf(o[1]) << 16);
    ob.y = (uint)f2bf(o[2]) | ((uint)f2bf(o[3]) << 16);
    ob.z = (uint)f2bf(o[4]) | ((uint)f2bf(o[5]) << 16);
    ob.w = (uint)f2bf(o[6]) | ((uint)f2bf(o[7]) << 16);
    *(uint4*)(xb + (size_t)row * D + i0) = ob;
}

// ---------------- cbias[b*512+hs] = sum_d K[b,h,s,d]*bq[h*64+d] ----------------
__global__ __launch_bounds__(256) void cbias_kernel(const ushort* __restrict__ kb16,
                                                    const float* __restrict__ bq,
                                                    float* __restrict__ cb) {
    int i = blockIdx.x * 256 + threadIdx.x;   // 0..2047
    int hs = i & 511;
    int h = hs >> 4;
    const ushort* kr = kb16 + (size_t)i * 64;
    const float* bb = bq + h * 64;
    float acc = 0.f;
#pragma unroll
    for (int d = 0; d < 64; ++d)
        acc += __uint_as_float(((uint)kr[d]) << 16) * bb[d];
    cb[i] = acc;
}

// ---------------- grouped 16x64 GEMM: per (b,h): C[16x2048] = A[16x64] @ Bslice^T --
template <int TRANS>
__global__ __launch_bounds__(256) void grouped16_kernel(
    const ushort* __restrict__ Abase, const ushort* __restrict__ Bmat,
    ushort* __restrict__ Cout) {
    int blk = blockIdx.x;           // g*8 + nt   (1024 blocks)
    int g = blk >> 3;               // 0..127 = b*32+h
    int nt = blk & 7;
    int h = g & 31;
    int hoff = h * 64;
    int tid = threadIdx.x, lane = tid & 63, wv = tid >> 6;
    int j0 = nt * 256 + wv * 64;
    int rr = lane & 15, ko = lane >> 4;
    const ushort* A = Abase + (size_t)g * 16 * 64;
    bf16x8 af0 = *(const bf16x8*)(A + rr * 64 + ko * 8);
    bf16x8 af1 = *(const bf16x8*)(A + rr * 64 + 32 + ko * 8);
    f32x4 acc[4];
    f32x4 zero = {0.f, 0.f, 0.f, 0.f};
#pragma unroll
    for (int nf = 0; nf < 4; ++nf) acc[nf] = zero;
#pragma unroll
    for (int nf = 0; nf < 4; ++nf) {
        int j = j0 + nf * 16 + rr;
        bf16x8 b0 = *(const bf16x8*)(Bmat + (size_t)j * 2048 + hoff + ko * 8);
        bf16x8 b1 = *(const bf16x8*)(Bmat + (size_t)j * 2048 + hoff + 32 + ko * 8);
        acc[nf] = __builtin_amdgcn_mfma_f32_16x16x32_bf16(af0, b0, acc[nf], 0, 0, 0);
        acc[nf] = __builtin_amdgcn_mfma_f32_16x16x32_bf16(af1, b1, acc[nf], 0, 0, 0);
    }
#pragma unroll
    for (int nf = 0; nf < 4; ++nf)
#pragma unroll
        for (int r = 0; r < 4; ++r) {
            int s = ko * 4 + r;
            int j = j0 + nf * 16 + rr;
            ushort v = f2bf(acc[nf][r]);
            if (TRANS) Cout[(size_t)j * 2048 + g * 16 + s] = v;
            else       Cout[(size_t)(g * 16 + s) * 2048 + j] = v;
        }
}

// ---------------- attn softmax: A_att = softmax_s((qlog0+qlog1+cbias)*0.125) ------
__global__ __launch_bounds__(256) void attn_sm_kernel(
    const float* __restrict__ qlog, const float* __restrict__ cb,
    ushort* __restrict__ aatt) {
    int blk = blockIdx.x;               // 1024 blocks x 8 rows
    int tid = threadIdx.x;
    int l = blk * 8 + (tid >> 5);
    int b = l >> 11;
    int h = tid & 31;
    const float* q0 = qlog + (size_t)l * 512 + h * 16;
    const float* q1 = q0 + (size_t)BL * 512;
    const float* c = cb + b * 512 + h * 16;
    float p[16];
#pragma unroll
    for (int i = 0; i < 16; i += 4) {
        float4 v0 = *(const float4*)(q0 + i);
        float4 v1 = *(const float4*)(q1 + i);
        float4 cc = *(const float4*)(c + i);
        p[i]     = v0.x + v1.x + cc.x;
        p[i + 1] = v0.y + v1.y + cc.y;
        p[i + 2] = v0.z + v1.z + cc.z;
        p[i + 3] = v0.w + v1.w + cc.w;
    }
    float mx = p[0];
#pragma unroll
    for (int s = 1; s < 16; ++s) mx = fmaxf(mx, p[s]);
    float den = 0.f;
#pragma unroll
    for (int s = 0; s < 16; ++s) { p[s] = __expf((p[s] - mx) * 0.125f); den += p[s]; }
    float inv = 1.0f / den;
    uint4 o[2];
    uint* ow = (uint*)o;
#pragma unroll
    for (int i = 0; i < 8; ++i)
        ow[i] = (uint)f2bf(p[2 * i] * inv) | ((uint)f2bf(p[2 * i + 1] * inv) << 16);
    ushort* dst = aatt + (size_t)l * 512 + h * 16;
    *(uint4*)dst = o[0];
    *(uint4*)(dst + 8) = o[1];
}

// ---------------- tiny-M GEMM: one wave per 16x16 output tile, no LDS/barriers ----
template <int KVMODE>
__global__ __launch_bounds__(256) void gemm_tiny(
    const ushort* __restrict__ A, const ushort* __restrict__ Bw,
    const float* __restrict__ bias, float* __restrict__ C,
    int M, int N, int K, ushort* __restrict__ kvk, ushort* __restrict__ kvv) {
    int gw = (blockIdx.x * 256 + threadIdx.x) >> 6;
    int lane = threadIdx.x & 63;
    int ntiles = N >> 4;
    int nt = gw % ntiles, mt = gw / ntiles;
    int rr = lane & 15, ko = lane >> 4;
    const ushort* Ar = A + (size_t)(mt * 16 + rr) * K;
    const ushort* Br = Bw + (size_t)(nt * 16 + rr) * K;
    f32x4 acc = {0.f, 0.f, 0.f, 0.f};
    int NT = K / 32;
#pragma unroll 8
    for (int t = 0; t < NT; ++t) {
        bf16x8 af = *(const bf16x8*)(Ar + t * 32 + ko * 8);
        bf16x8 bf = *(const bf16x8*)(Br + t * 32 + ko * 8);
        acc = __builtin_amdgcn_mfma_f32_16x16x32_bf16(af, bf, acc, 0, 0, 0);
    }
    int col = nt * 16 + rr;
    float bsv = bias ? bias[col] : 0.f;
#pragma unroll
    for (int r = 0; r < 4; ++r) {
        int rowi = mt * 16 + ko * 4 + r;
        float v = acc[r] + bsv;
        if (KVMODE) {
            int b = rowi >> 4, s = rowi & 15;
            int c2 = (col < 2048) ? col : col - 2048;
            int h = c2 >> 6, d = c2 & 63;
            size_t dst = (((size_t)(b * NHEAD + h)) * NSLOT + s) * HDIM + d;
            if (col < 2048) kvk[dst] = f2bf(v);
            else            kvv[dst] = f2bf(v);
        } else {
            C[(size_t)rowi * N + col] = v;
        }
    }
}

// ---------------- bf16 MFMA GEMM: C[m,n] = sum_k A[m,k]*Bw[n,k] + bias[n] ----------
// OBF=1: write bf16 to ((ushort*)C). bOff: per-batch B offset; strides/z as before.
template <int BM, int OBF>
__global__ __launch_bounds__(256) void gemm_bt(
    const ushort* __restrict__ A, const ushort* __restrict__ Bw,
    const float* __restrict__ bias, float* __restrict__ C,
    int M, int N, int K, size_t bOff, int bStride, int aStride,
    int zA, int zB, size_t zC) {
    constexpr int BN = 128, BK = 32;
    constexpr int MF = BM / 32;
    constexpr int APASS = (BM * BK / 8) / 256;
    __shared__ short lds[2][(BM + BN) * BK];
    int tid = threadIdx.x;
    int lane = tid & 63, w = tid >> 6;
    int wr = w >> 1, wc = w & 1;
    int tn = blockIdx.x * BN;
    int tm = blockIdx.y * BM;
    int ksl = blockIdx.z;
    A += (size_t)ksl * zA;
    Bw += (size_t)ksl * zB + (size_t)(tm >> 11) * bOff;
    C += (size_t)ksl * zC;
    f32x4 acc[MF][4];
    f32x4 zero = {0.f, 0.f, 0.f, 0.f};
#pragma unroll
    for (int m = 0; m < MF; ++m)
#pragma unroll
        for (int n = 0; n < 4; ++n) acc[m][n] = zero;
    int NT = K / BK;

    auto stage = [&](int buf, int t) {
        int kt = t * BK;
#pragma unroll
        for (int p = 0; p < APASS; ++p) {
            int cb = p * 256 + w * 64;
            int c = cb + lane;
            int r = c >> 2;
            int k8 = (c & 3) * 8;
            int gr = tm + r;
            if (gr >= M) gr = M - 1;
            gl_lds16(A + (size_t)gr * aStride + kt + k8, (void*)&lds[buf][cb * 8]);
        }
#pragma unroll
        for (int p = 0; p < 2; ++p) {
            int cb = p * 256 + w * 64;
            int c = cb + lane;
            int r = c >> 2;
            int k8 = (c & 3) * 8;
            gl_lds16(Bw + (size_t)(tn + r) * bStride + kt + k8,
                     (void*)&lds[buf][BM * BK + cb * 8]);
        }
    };
    stage(0, 0);
    for (int t = 0; t < NT; ++t) {
        __syncthreads();
        if (t + 1 < NT) stage((t + 1) & 1, t + 1);
        const short* Ab = &lds[t & 1][0];
        const short* Bb = &lds[t & 1][BM * BK];
        int ko = (lane >> 4) * 8;
        int rr = lane & 15;
        bf16x8 af[MF], bfr[4];
#pragma unroll
        for (int m = 0; m < MF; ++m)
            af[m] = *(const bf16x8*)&Ab[(wr * (MF * 16) + m * 16 + rr) * BK + ko];
#pragma unroll
        for (int n = 0; n < 4; ++n)
            bfr[n] = *(const bf16x8*)&Bb[(wc * 64 + n * 16 + rr) * BK + ko];
#pragma unroll
        for (int m = 0; m < MF; ++m)
#pragma unroll
            for (int n = 0; n < 4; ++n)
                acc[m][n] = __builtin_amdgcn_mfma_f32_16x16x32_bf16(af[m], bfr[n],
                                                                    acc[m][n], 0, 0, 0);
    }
#pragma unroll
    for (int m = 0; m < MF; ++m) {
#pragma unroll
        for (int n = 0; n < 4; ++n) {
            int col = tn + wc * 64 + n * 16 + (lane & 15);
            float bsv = bias ? bias[col] : 0.f;
#pragma unroll
            for (int r = 0; r < 4; ++r) {
                int rowi = tm + wr * (MF * 16) + m * 16 + (lane >> 4) * 4 + r;
                if (rowi >= M) continue;
                float v = acc[m][n][r] + bsv;
                if (OBF) ((ushort*)C)[(size_t)rowi * N + col] = f2bf(v);
                else     C[(size_t)rowi * N + col] = v;
            }
        }
    }
}

extern "C" void kernel_launch(void* const* d_in, const int* in_sizes, int n_in,
                              void* d_out, int out_size, void* d_ws, size_t ws_size,
                              hipStream_t stream) {
    const float* x_in       = (const float*)d_in[0];
    const float* workspace  = (const float*)d_in[1];
    const float* compete_w  = (const float*)d_in[2];
    const float* compete_b  = (const float*)d_in[3];
    const float* write_w    = (const float*)d_in[4];
    const float* write_b    = (const float*)d_in[5];
    const float* in_proj_w  = (const float*)d_in[6];
    const float* in_proj_b  = (const float*)d_in[7];
    const float* out_proj_w = (const float*)d_in[8];
    const float* out_proj_b = (const float*)d_in[9];
    const float* norm_pre_w  = (const float*)d_in[12];
    const float* norm_post_w = (const float*)d_in[13];
    float* xout = (float*)d_out;

    char* base = (char*)d_ws;
    size_t off = 0;
    auto alloc = [&](size_t bytes) {
        void* p = base + off;
        off += (bytes + 255) & ~(size_t)255;
        return p;
    };
    ushort* xb      = (ushort*)alloc((size_t)BL * D * 2);
    ushort* xbb     = (ushort*)alloc((size_t)BL * D * 2);     // x_b (bf16)
    float*  logits  = (float*) alloc((size_t)BATCH * NSLOT * LSEQ * 4);
    ushort* xbar    = (ushort*)alloc((size_t)BATCH * NSLOT * D * 2);
    float*  written = (float*) alloc((size_t)BATCH * NSLOT * D * 4);
    float*  wsbuf   = (float*) alloc((size_t)BATCH * NSLOT * D * 4);
    ushort* wsb     = (ushort*)alloc((size_t)BATCH * NSLOT * D * 2);
    ushort* ipb     = (ushort*)alloc((size_t)3 * D * D * 2);
    ushort* wob     = (ushort*)alloc((size_t)D * D * 2);
    ushort* wwb     = (ushort*)alloc((size_t)D * D * 2);
    ushort* wqt     = (ushort*)alloc((size_t)D * D * 2);      // Wq^T bf16
    ushort* kb16    = (ushort*)alloc((size_t)BATCH * NHEAD * NSLOT * HDIM * 2);
    ushort* vb16    = (ushort*)alloc((size_t)BATCH * NHEAD * NSLOT * HDIM * 2);
    ushort* ktil    = (ushort*)alloc((size_t)BATCH * 512 * D * 2);   // K~ rows b*512+hs
    ushort* wtilT   = (ushort*)alloc((size_t)D * BATCH * 512 * 2);   // W~^T rows j
    float*  qlog    = (float*) alloc((size_t)2 * BL * 512 * 4);      // 2 K-split planes
    ushort* aatt    = (ushort*)alloc((size_t)BL * 512 * 2);
    float*  cbias   = (float*) alloc((size_t)BATCH * 512 * 4);
    (void)ws_size; (void)in_sizes; (void)n_in; (void)out_size;

    conv_bf16_kernel<<<2048, 256, 0, stream>>>((const float4*)in_proj_w, ipb, 3 * D * D / 4);
    conv_bf16_kernel<<<2048, 256, 0, stream>>>((const float4*)out_proj_w, wob, D * D / 4);
    conv_bf16_kernel<<<2048, 256, 0, stream>>>((const float4*)write_w, wwb, D * D / 4);
    conv_bf16_kernel<<<2048, 256, 0, stream>>>((const float4*)x_in, xb, BL * D / 4);
    transpose_bf16_kernel<<<1024, 256, 0, stream>>>(ipb, wqt);   // Wq^T (q rows 0..D)

    for (int it = 0; it < 2; ++it) {
        const float* xs = it ? (const float*)xout : x_in;
        logits_kernel<<<BL / 4, 256, 0, stream>>>(xs, compete_w, compete_b, norm_pre_w,
                                                  logits);
        topk_xbar_kernel<<<BATCH * NSLOT, 256, 0, stream>>>(logits, xs, xbar);
        // written = xbar @ wwb^T + write_b   (64x2048, K=2048) — 512 waves
        gemm_tiny<0><<<128, 256, 0, stream>>>(xbar, wwb, write_b, written,
                                              BATCH * NSLOT, D, D,
                                              (ushort*)nullptr, (ushort*)nullptr);
        ws_update_kernel<<<BATCH * NSLOT, 256, 0, stream>>>(written, wsbuf, workspace,
                                                            it == 0 ? 1 : 0, norm_post_w,
                                                            wsbuf, wsb);
        // kv = wsb @ Wkv^T + bkv  (64x4096, K=2048) — 1024 waves, scatter to kb/vb
        gemm_tiny<1><<<256, 256, 0, stream>>>(wsb, ipb + (size_t)D * D, in_proj_b + D,
                                              (float*)nullptr, BATCH * NSLOT, 2 * D, D,
                                              kb16, vb16);
        cbias_kernel<<<8, 256, 0, stream>>>(kb16, in_proj_b, cbias);
        grouped16_kernel<0><<<1024, 256, 0, stream>>>(kb16, wqt, ktil);
        grouped16_kernel<1><<<1024, 256, 0, stream>>>(vb16, wob, wtilT);
        // qlog[z][l, hs] = xb[l, zK:zK+1024] . K~[b,hs, zK:zK+1024]  (split-K=2)
        gemm_bt<64, 0><<<dim3(512 / 128, BL / 64, 2), 256, 0, stream>>>(
            xb, ktil, (const float*)nullptr, qlog, BL, 512, D / 2,
            (size_t)512 * D, D, D, D / 2, D / 2, (size_t)BL * 512);
        attn_sm_kernel<<<BL / 8, 256, 0, stream>>>(qlog, cbias, aatt);
        // x_b[l, j] (bf16) = sum_hs aatt[l,hs] * W~T[j, b*512+hs] + out_proj_b[j]
        gemm_bt<64, 1><<<dim3(D / 128, BL / 64), 256, 0, stream>>>(
            aatt, wtilT, out_proj_b, (float*)xbb, BL, D, 512,
            (size_t)512, D, 512, 0, 0, 0);
        resid_rms_kernel<<<BL, 256, 0, stream>>>(xs, xbb, norm_post_w, xout, xb);
    }
}

// Round 17
// 534.660 us; speedup vs baseline: 1.0326x; 1.0010x over previous
//
#include <hip/hip_runtime.h>
#include <stdint.h>

#define D 2048
#define LSEQ 2048
#define BATCH 4
#define BL (BATCH * LSEQ)   // 8192 rows
#define NSLOT 16
#define NHEAD 32
#define HDIM 64
#define EPSV 1e-6f

typedef __attribute__((ext_vector_type(8))) short bf16x8;
typedef __attribute__((ext_vector_type(4))) float f32x4;

static __device__ __forceinline__ ushort f2bf(float f) {
    uint32_t u = __float_as_uint(f);
    u += 0x7fffu + ((u >> 16) & 1u);   // RNE
    return (ushort)(u >> 16);
}

static __device__ __forceinline__ float wave_sum(float v) {
#pragma unroll
    for (int off = 32; off > 0; off >>= 1) v += __shfl_xor(v, off, 64);
    return v;
}

static __device__ __forceinline__ void gl_lds16(const void* g, void* l) {
    __builtin_amdgcn_global_load_lds(
        (__attribute__((address_space(1))) uint32_t*)(uintptr_t)g,
        (__attribute__((address_space(3))) uint32_t*)(uint32_t)(uintptr_t)l,
        16, 0, 0);
}

// ---------------- weight convert f32 -> bf16 ----------------
__global__ __launch_bounds__(256) void conv_bf16_kernel(const float4* __restrict__ src,
                                                        ushort* __restrict__ dst, int n4) {
    int i = blockIdx.x * 256 + threadIdx.x;
    int stride = gridDim.x * 256;
    for (; i < n4; i += stride) {
        float4 v = src[i];
        uint2 o;
        o.x = (uint)f2bf(v.x) | ((uint)f2bf(v.y) << 16);
        o.y = (uint)f2bf(v.z) | ((uint)f2bf(v.w) << 16);
        *(uint2*)(dst + (size_t)i * 4) = o;
    }
}

// ---------------- 2048x2048 bf16 transpose (once, for Wq^T) ----------------
__global__ __launch_bounds__(256) void transpose_bf16_kernel(const ushort* __restrict__ src,
                                                             ushort* __restrict__ dst) {
    __shared__ ushort t[64][72];
    int bx = blockIdx.x & 31, by = blockIdx.x >> 5;
    int r0 = by * 64, c0 = bx * 64;
    int tid = threadIdx.x;
    int lr = tid >> 3;
    int lc = (tid & 7) * 8;
#pragma unroll
    for (int p = 0; p < 2; ++p) {
        int rr = p * 32 + lr;
        bf16x8 v = *(const bf16x8*)(src + (size_t)(r0 + rr) * 2048 + c0 + lc);
#pragma unroll
        for (int j = 0; j < 8; ++j) t[lc + j][rr] = (ushort)v[j];
    }
    __syncthreads();
#pragma unroll
    for (int p = 0; p < 2; ++p) {
        int rr = p * 32 + lr;
        *(bf16x8*)(dst + (size_t)(c0 + rr) * 2048 + r0 + lc) = *(const bf16x8*)&t[rr][lc];
    }
}

// ---------------- logits v7: v6 + __launch_bounds__(256,4) anti-spill ------------
// v6's compiler chose VGPR=32 (occupancy-greedy) and SPILLED xw[4][8] to scratch:
// every slot iteration re-read ~128B/thread of spill through L2 (the 50us, VALU
// 16%, HBM 9% signature). min-4-waves/EU caps VGPRs at 128 -> no spill, still up
// to 16 waves/CU. Arithmetic is UNCHANGED (bit-exact logits; R5 lesson: top-k is
// an order-statistic discontinuity - do not touch any FP op here).
__global__ __launch_bounds__(256, 4) void logits_kernel(
    const float* __restrict__ x, const float* __restrict__ cw,
    const float* __restrict__ cb, const float* __restrict__ wpre,
    float* __restrict__ logits_t) {
    int blk = blockIdx.x;              // 2048 blocks, 4 rows each
    int b = blk >> 9;                  // 512 blocks per batch
    int l0 = (blk & 511) << 2;
    int tid = threadIdx.x;
    int i0 = tid * 8;
    float4 w0 = *(const float4*)(wpre + i0);
    float4 w1 = *(const float4*)(wpre + i0 + 4);
    float wv[8] = {w0.x, w0.y, w0.z, w0.w, w1.x, w1.y, w1.z, w1.w};
    float xw[4][8];
    float ss[4];
#pragma unroll
    for (int r = 0; r < 4; ++r) {
        const float* xr = x + ((size_t)(b * LSEQ + l0 + r)) * D;
        float4 a0 = *(const float4*)(xr + i0);
        float4 a1 = *(const float4*)(xr + i0 + 4);
        float xv[8] = {a0.x, a0.y, a0.z, a0.w, a1.x, a1.y, a1.z, a1.w};
        float s0 = 0.f;
#pragma unroll
        for (int j = 0; j < 8; ++j) { s0 += xv[j] * xv[j]; xw[r][j] = xv[j] * wv[j]; }
        ss[r] = s0;
    }
#pragma unroll
    for (int r = 0; r < 4; ++r) ss[r] = wave_sum(ss[r]);
    __shared__ float red[4][NSLOT][4];
    __shared__ float redss[4][4];
    int lane = tid & 63, w = tid >> 6;
    if (lane == 0) {
#pragma unroll
        for (int r = 0; r < 4; ++r) redss[w][r] = ss[r];
    }
#pragma unroll 2
    for (int s = 0; s < NSLOT; ++s) {
        const float* cwr = cw + (size_t)s * D + i0;
        float4 c0 = *(const float4*)(cwr);
        float4 c1 = *(const float4*)(cwr + 4);
        float acc[4];
#pragma unroll
        for (int r = 0; r < 4; ++r)
            acc[r] = xw[r][0] * c0.x + xw[r][1] * c0.y + xw[r][2] * c0.z + xw[r][3] * c0.w +
                     xw[r][4] * c1.x + xw[r][5] * c1.y + xw[r][6] * c1.z + xw[r][7] * c1.w;
#pragma unroll
        for (int r = 0; r < 4; ++r) acc[r] = wave_sum(acc[r]);
        if (lane == 0) {
#pragma unroll
            for (int r = 0; r < 4; ++r) red[w][s][r] = acc[r];
        }
    }
    __syncthreads();
    if (tid < 64) {
        int s = tid >> 2, r = tid & 3;
        float tot = red[0][s][r] + red[1][s][r] + red[2][s][r] + red[3][s][r];
        float s2 = redss[0][r] + redss[1][r] + redss[2][r] + redss[3][r];
        float rsq = 1.0f / sqrtf(s2 * (1.0f / (float)D) + EPSV);
        logits_t[((size_t)(b * NSLOT + s)) * LSEQ + l0 + r] = tot * rsq + cb[s];
    }
}

// ---------------- top-4 + softmax + weighted row gather (xbar, bf16) ----------------
__global__ __launch_bounds__(256) void topk_xbar_kernel(
    const float* __restrict__ logits_t, const float* __restrict__ x,
    ushort* __restrict__ xbar_b) {
    int bs = blockIdx.x;
    int b = bs >> 4;
    const float* lr = logits_t + (size_t)bs * LSEQ;
    int tid = threadIdx.x, lane = tid & 63, w = tid >> 6;
    __shared__ float rv[4];
    __shared__ int ri[4];
    __shared__ float selv[4];
    __shared__ int seli[4];
    int i0 = tid * 8;
    float myv[8];
#pragma unroll
    for (int j = 0; j < 8; ++j) myv[j] = lr[i0 + j];
    int chosen[4];
    for (int p = 0; p < 4; ++p) {
        float bv = -3.4e38f;
        int bi = 0x7fffffff;
#pragma unroll
        for (int j = 0; j < 8; ++j) {
            int i = i0 + j;
            bool skip = false;
            for (int q = 0; q < p; ++q) skip = skip || (i == chosen[q]);
            float v = myv[j];
            if (!skip && (v > bv || (v == bv && i < bi))) { bv = v; bi = i; }
        }
#pragma unroll
        for (int off = 1; off < 64; off <<= 1) {
            float ov = __shfl_xor(bv, off, 64);
            int oi = __shfl_xor(bi, off, 64);
            if (ov > bv || (ov == bv && oi < bi)) { bv = ov; bi = oi; }
        }
        if (lane == 0) { rv[w] = bv; ri[w] = bi; }
        __syncthreads();
        if (tid == 0) {
            float fv = rv[0];
            int fi = ri[0];
            for (int q = 1; q < 4; ++q)
                if (rv[q] > fv || (rv[q] == fv && ri[q] < fi)) { fv = rv[q]; fi = ri[q]; }
            selv[p] = fv;
            seli[p] = fi;
        }
        __syncthreads();
        chosen[p] = seli[p];
    }
    float vals[4];
#pragma unroll
    for (int p = 0; p < 4; ++p) vals[p] = selv[p];
    float mx = vals[0];   // first pick is the max
    float e[4], den = 0.f;
#pragma unroll
    for (int p = 0; p < 4; ++p) { e[p] = expf(vals[p] - mx); den += e[p]; }
    float inv = 1.0f / den;
    const float* xr0 = x + ((size_t)b * LSEQ + chosen[0]) * D;
    const float* xr1 = x + ((size_t)b * LSEQ + chosen[1]) * D;
    const float* xr2 = x + ((size_t)b * LSEQ + chosen[2]) * D;
    const float* xr3 = x + ((size_t)b * LSEQ + chosen[3]) * D;
    float s[8];
#pragma unroll
    for (int j = 0; j < 8; ++j) {
        int i = i0 + j;
        s[j] = (e[0] * xr0[i] + e[1] * xr1[i] + e[2] * xr2[i] + e[3] * xr3[i]) * inv;
    }
    uint4 o;
    o.x = (uint)f2bf(s[0]) | ((uint)f2bf(s[1]) << 16);
    o.y = (uint)f2bf(s[2]) | ((uint)f2bf(s[3]) << 16);
    o.z = (uint)f2bf(s[4]) | ((uint)f2bf(s[5]) << 16);
    o.w = (uint)f2bf(s[6]) | ((uint)f2bf(s[7]) << 16);
    *(uint4*)(xbar_b + (size_t)bs * D + i0) = o;
}

// ---------------- ws = rms(ws_prev + written) (+bf16 copy) ----------------
__global__ __launch_bounds__(256) void ws_update_kernel(
    const float* __restrict__ written, const float* __restrict__ ws_prev,
    const float* __restrict__ workspace0, int first,
    const float* __restrict__ wpost, float* __restrict__ ws_out,
    ushort* __restrict__ ws_b) {
    int bs = blockIdx.x;
    int s = bs & (NSLOT - 1);
    int tid = threadIdx.x;
    int i0 = tid * 8;
    const float* prev = first ? (workspace0 + (size_t)s * D) : (ws_prev + (size_t)bs * D);
    const float* wr = written + (size_t)bs * D;
    float4 p0 = *(const float4*)(prev + i0);
    float4 p1 = *(const float4*)(prev + i0 + 4);
    float4 q0 = *(const float4*)(wr + i0);
    float4 q1 = *(const float4*)(wr + i0 + 4);
    float t[8] = {p0.x + q0.x, p0.y + q0.y, p0.z + q0.z, p0.w + q0.w,
                  p1.x + q1.x, p1.y + q1.y, p1.z + q1.z, p1.w + q1.w};
    float ss = 0.f;
#pragma unroll
    for (int j = 0; j < 8; ++j) ss += t[j] * t[j];
    ss = wave_sum(ss);
    __shared__ float sb[4];
    if ((tid & 63) == 0) sb[tid >> 6] = ss;
    __syncthreads();
    ss = sb[0] + sb[1] + sb[2] + sb[3];
    float rsq = 1.0f / sqrtf(ss * (1.0f / (float)D) + EPSV);
    float4 w0 = *(const float4*)(wpost + i0);
    float4 w1 = *(const float4*)(wpost + i0 + 4);
    float wv[8] = {w0.x, w0.y, w0.z, w0.w, w1.x, w1.y, w1.z, w1.w};
    float o[8];
#pragma unroll
    for (int j = 0; j < 8; ++j) o[j] = t[j] * rsq * wv[j];
    float4 r0 = {o[0], o[1], o[2], o[3]};
    float4 r1 = {o[4], o[5], o[6], o[7]};
    *(float4*)(ws_out + (size_t)bs * D + i0) = r0;
    *(float4*)(ws_out + (size_t)bs * D + i0 + 4) = r1;
    uint4 ob;
    ob.x = (uint)f2bf(o[0]) | ((uint)f2bf(o[1]) << 16);
    ob.y = (uint)f2bf(o[2]) | ((uint)f2bf(o[3]) << 16);
    ob.z = (uint)f2bf(o[4]) | ((uint)f2bf(o[5]) << 16);
    ob.w = (uint)f2bf(o[6]) | ((uint)f2bf(o[7]) << 16);
    *(uint4*)(ws_b + (size_t)bs * D + i0) = ob;
}

// ---------------- x = rms(x + attn_out[bf16]) (+bf16 copy) ----------------
__global__ __launch_bounds__(256) void resid_rms_kernel(
    const float* __restrict__ x_src, const ushort* __restrict__ ao,
    const float* __restrict__ wpost, float* __restrict__ x_dst,
    ushort* __restrict__ xb) {
    int row = blockIdx.x;
    int tid = threadIdx.x;
    int i0 = tid * 8;
    const float* xr = x_src + (size_t)row * D;
    uint4 av = *(const uint4*)(ao + (size_t)row * D + i0);
    float af[8];
    af[0] = __uint_as_float(av.x << 16);
    af[1] = __uint_as_float(av.x & 0xffff0000u);
    af[2] = __uint_as_float(av.y << 16);
    af[3] = __uint_as_float(av.y & 0xffff0000u);
    af[4] = __uint_as_float(av.z << 16);
    af[5] = __uint_as_float(av.z & 0xffff0000u);
    af[6] = __uint_as_float(av.w << 16);
    af[7] = __uint_as_float(av.w & 0xffff0000u);
    float4 p0 = *(const float4*)(xr + i0);
    float4 p1 = *(const float4*)(xr + i0 + 4);
    float t[8] = {p0.x + af[0], p0.y + af[1], p0.z + af[2], p0.w + af[3],
                  p1.x + af[4], p1.y + af[5], p1.z + af[6], p1.w + af[7]};
    float ss = 0.f;
#pragma unroll
    for (int j = 0; j < 8; ++j) ss += t[j] * t[j];
    ss = wave_sum(ss);
    __shared__ float sb[4];
    if ((tid & 63) == 0) sb[tid >> 6] = ss;
    __syncthreads();
    ss = sb[0] + sb[1] + sb[2] + sb[3];
    float rsq = 1.0f / sqrtf(ss * (1.0f / (float)D) + EPSV);
    float4 w0 = *(const float4*)(wpost + i0);
    float4 w1 = *(const float4*)(wpost + i0 + 4);
    float wv[8] = {w0.x, w0.y, w0.z, w0.w, w1.x, w1.y, w1.z, w1.w};
    float o[8];
#pragma unroll
    for (int j = 0; j < 8; ++j) o[j] = t[j] * rsq * wv[j];
    float4 r0 = {o[0], o[1], o[2], o[3]};
    float4 r1 = {o[4], o[5], o[6], o[7]};
    *(float4*)(x_dst + (size_t)row * D + i0) = r0;
    *(float4*)(x_dst + (size_t)row * D + i0 + 4) = r1;
    uint4 ob;
    ob.x = (uint)f2bf(o[0]) | ((uint)f2bf(o[1]) << 16);
    ob.y = (uint)f2bf(o[2]) | ((uint)f2bf(o[3]) << 16);
    ob.z = (uint)f2bf(o[4]) | ((uint)f2bf(o[5]) << 16);
    ob.w = (uint)f2bf(o[6]) | ((uint)f2bf(o[7]) << 16);
    *(uint4*)(xb + (size_t)row * D + i0) = ob;
}

// ---------------- cbias[b*512+hs] = sum_d K[b,h,s,d]*bq[h*64+d] ----------------
__global__ __launch_bounds__(256) void cbias_kernel(const ushort* __restrict__ kb16,
                                                    const float* __restrict__ bq,
                                                    float* __restrict__ cb) {
    int i = blockIdx.x * 256 + threadIdx.x;   // 0..2047
    int hs = i & 511;
    int h = hs >> 4;
    const ushort* kr = kb16 + (size_t)i * 64;
    const float* bb = bq + h * 64;
    float acc = 0.f;
#pragma unroll
    for (int d = 0; d < 64; ++d)
        acc += __uint_as_float(((uint)kr[d]) << 16) * bb[d];
    cb[i] = acc;
}

// ---------------- grouped 16x64 GEMM: per (b,h): C[16x2048] = A[16x64] @ Bslice^T --
template <int TRANS>
__global__ __launch_bounds__(256) void grouped16_kernel(
    const ushort* __restrict__ Abase, const ushort* __restrict__ Bmat,
    ushort* __restrict__ Cout) {
    int blk = blockIdx.x;           // g*8 + nt   (1024 blocks)
    int g = blk >> 3;               // 0..127 = b*32+h
    int nt = blk & 7;
    int h = g & 31;
    int hoff = h * 64;
    int tid = threadIdx.x, lane = tid & 63, wv = tid >> 6;
    int j0 = nt * 256 + wv * 64;
    int rr = lane & 15, ko = lane >> 4;
    const ushort* A = Abase + (size_t)g * 16 * 64;
    bf16x8 af0 = *(const bf16x8*)(A + rr * 64 + ko * 8);
    bf16x8 af1 = *(const bf16x8*)(A + rr * 64 + 32 + ko * 8);
    f32x4 acc[4];
    f32x4 zero = {0.f, 0.f, 0.f, 0.f};
#pragma unroll
    for (int nf = 0; nf < 4; ++nf) acc[nf] = zero;
#pragma unroll
    for (int nf = 0; nf < 4; ++nf) {
        int j = j0 + nf * 16 + rr;
        bf16x8 b0 = *(const bf16x8*)(Bmat + (size_t)j * 2048 + hoff + ko * 8);
        bf16x8 b1 = *(const bf16x8*)(Bmat + (size_t)j * 2048 + hoff + 32 + ko * 8);
        acc[nf] = __builtin_amdgcn_mfma_f32_16x16x32_bf16(af0, b0, acc[nf], 0, 0, 0);
        acc[nf] = __builtin_amdgcn_mfma_f32_16x16x32_bf16(af1, b1, acc[nf], 0, 0, 0);
    }
#pragma unroll
    for (int nf = 0; nf < 4; ++nf)
#pragma unroll
        for (int r = 0; r < 4; ++r) {
            int s = ko * 4 + r;
            int j = j0 + nf * 16 + rr;
            ushort v = f2bf(acc[nf][r]);
            if (TRANS) Cout[(size_t)j * 2048 + g * 16 + s] = v;
            else       Cout[(size_t)(g * 16 + s) * 2048 + j] = v;
        }
}

// ---------------- attn softmax: A_att = softmax_s((qlog0+qlog1+cbias)*0.125) ------
__global__ __launch_bounds__(256) void attn_sm_kernel(
    const float* __restrict__ qlog, const float* __restrict__ cb,
    ushort* __restrict__ aatt) {
    int blk = blockIdx.x;               // 1024 blocks x 8 rows
    int tid = threadIdx.x;
    int l = blk * 8 + (tid >> 5);
    int b = l >> 11;
    int h = tid & 31;
    const float* q0 = qlog + (size_t)l * 512 + h * 16;
    const float* q1 = q0 + (size_t)BL * 512;
    const float* c = cb + b * 512 + h * 16;
    float p[16];
#pragma unroll
    for (int i = 0; i < 16; i += 4) {
        float4 v0 = *(const float4*)(q0 + i);
        float4 v1 = *(const float4*)(q1 + i);
        float4 cc = *(const float4*)(c + i);
        p[i]     = v0.x + v1.x + cc.x;
        p[i + 1] = v0.y + v1.y + cc.y;
        p[i + 2] = v0.z + v1.z + cc.z;
        p[i + 3] = v0.w + v1.w + cc.w;
    }
    float mx = p[0];
#pragma unroll
    for (int s = 1; s < 16; ++s) mx = fmaxf(mx, p[s]);
    float den = 0.f;
#pragma unroll
    for (int s = 0; s < 16; ++s) { p[s] = __expf((p[s] - mx) * 0.125f); den += p[s]; }
    float inv = 1.0f / den;
    uint4 o[2];
    uint* ow = (uint*)o;
#pragma unroll
    for (int i = 0; i < 8; ++i)
        ow[i] = (uint)f2bf(p[2 * i] * inv) | ((uint)f2bf(p[2 * i + 1] * inv) << 16);
    ushort* dst = aatt + (size_t)l * 512 + h * 16;
    *(uint4*)dst = o[0];
    *(uint4*)(dst + 8) = o[1];
}

// ---------------- tiny-M GEMM: one wave per 16x16 output tile, no LDS/barriers ----
template <int KVMODE>
__global__ __launch_bounds__(256) void gemm_tiny(
    const ushort* __restrict__ A, const ushort* __restrict__ Bw,
    const float* __restrict__ bias, float* __restrict__ C,
    int M, int N, int K, ushort* __restrict__ kvk, ushort* __restrict__ kvv) {
    int gw = (blockIdx.x * 256 + threadIdx.x) >> 6;
    int lane = threadIdx.x & 63;
    int ntiles = N >> 4;
    int nt = gw % ntiles, mt = gw / ntiles;
    int rr = lane & 15, ko = lane >> 4;
    const ushort* Ar = A + (size_t)(mt * 16 + rr) * K;
    const ushort* Br = Bw + (size_t)(nt * 16 + rr) * K;
    f32x4 acc = {0.f, 0.f, 0.f, 0.f};
    int NT = K / 32;
#pragma unroll 8
    for (int t = 0; t < NT; ++t) {
        bf16x8 af = *(const bf16x8*)(Ar + t * 32 + ko * 8);
        bf16x8 bf = *(const bf16x8*)(Br + t * 32 + ko * 8);
        acc = __builtin_amdgcn_mfma_f32_16x16x32_bf16(af, bf, acc, 0, 0, 0);
    }
    int col = nt * 16 + rr;
    float bsv = bias ? bias[col] : 0.f;
#pragma unroll
    for (int r = 0; r < 4; ++r) {
        int rowi = mt * 16 + ko * 4 + r;
        float v = acc[r] + bsv;
        if (KVMODE) {
            int b = rowi >> 4, s = rowi & 15;
            int c2 = (col < 2048) ? col : col - 2048;
            int h = c2 >> 6, d = c2 & 63;
            size_t dst = (((size_t)(b * NHEAD + h)) * NSLOT + s) * HDIM + d;
            if (col < 2048) kvk[dst] = f2bf(v);
            else            kvv[dst] = f2bf(v);
        } else {
            C[(size_t)rowi * N + col] = v;
        }
    }
}

// ---------------- bf16 MFMA GEMM: C[m,n] = sum_k A[m,k]*Bw[n,k] + bias[n] ----------
// OBF=1: write bf16 to ((ushort*)C). bOff: per-batch B offset; strides/z as before.
template <int BM, int OBF>
__global__ __launch_bounds__(256) void gemm_bt(
    const ushort* __restrict__ A, const ushort* __restrict__ Bw,
    const float* __restrict__ bias, float* __restrict__ C,
    int M, int N, int K, size_t bOff, int bStride, int aStride,
    int zA, int zB, size_t zC) {
    constexpr int BN = 128, BK = 32;
    constexpr int MF = BM / 32;
    constexpr int APASS = (BM * BK / 8) / 256;
    __shared__ short lds[2][(BM + BN) * BK];
    int tid = threadIdx.x;
    int lane = tid & 63, w = tid >> 6;
    int wr = w >> 1, wc = w & 1;
    int tn = blockIdx.x * BN;
    int tm = blockIdx.y * BM;
    int ksl = blockIdx.z;
    A += (size_t)ksl * zA;
    Bw += (size_t)ksl * zB + (size_t)(tm >> 11) * bOff;
    C += (size_t)ksl * zC;
    f32x4 acc[MF][4];
    f32x4 zero = {0.f, 0.f, 0.f, 0.f};
#pragma unroll
    for (int m = 0; m < MF; ++m)
#pragma unroll
        for (int n = 0; n < 4; ++n) acc[m][n] = zero;
    int NT = K / BK;

    auto stage = [&](int buf, int t) {
        int kt = t * BK;
#pragma unroll
        for (int p = 0; p < APASS; ++p) {
            int cb = p * 256 + w * 64;
            int c = cb + lane;
            int r = c >> 2;
            int k8 = (c & 3) * 8;
            int gr = tm + r;
            if (gr >= M) gr = M - 1;
            gl_lds16(A + (size_t)gr * aStride + kt + k8, (void*)&lds[buf][cb * 8]);
        }
#pragma unroll
        for (int p = 0; p < 2; ++p) {
            int cb = p * 256 + w * 64;
            int c = cb + lane;
            int r = c >> 2;
            int k8 = (c & 3) * 8;
            gl_lds16(Bw + (size_t)(tn + r) * bStride + kt + k8,
                     (void*)&lds[buf][BM * BK + cb * 8]);
        }
    };
    stage(0, 0);
    for (int t = 0; t < NT; ++t) {
        __syncthreads();
        if (t + 1 < NT) stage((t + 1) & 1, t + 1);
        const short* Ab = &lds[t & 1][0];
        const short* Bb = &lds[t & 1][BM * BK];
        int ko = (lane >> 4) * 8;
        int rr = lane & 15;
        bf16x8 af[MF], bfr[4];
#pragma unroll
        for (int m = 0; m < MF; ++m)
            af[m] = *(const bf16x8*)&Ab[(wr * (MF * 16) + m * 16 + rr) * BK + ko];
#pragma unroll
        for (int n = 0; n < 4; ++n)
            bfr[n] = *(const bf16x8*)&Bb[(wc * 64 + n * 16 + rr) * BK + ko];
#pragma unroll
        for (int m = 0; m < MF; ++m)
#pragma unroll
            for (int n = 0; n < 4; ++n)
                acc[m][n] = __builtin_amdgcn_mfma_f32_16x16x32_bf16(af[m], bfr[n],
                                                                    acc[m][n], 0, 0, 0);
    }
#pragma unroll
    for (int m = 0; m < MF; ++m) {
#pragma unroll
        for (int n = 0; n < 4; ++n) {
            int col = tn + wc * 64 + n * 16 + (lane & 15);
            float bsv = bias ? bias[col] : 0.f;
#pragma unroll
            for (int r = 0; r < 4; ++r) {
                int rowi = tm + wr * (MF * 16) + m * 16 + (lane >> 4) * 4 + r;
                if (rowi >= M) continue;
                float v = acc[m][n][r] + bsv;
                if (OBF) ((ushort*)C)[(size_t)rowi * N + col] = f2bf(v);
                else     C[(size_t)rowi * N + col] = v;
            }
        }
    }
}

extern "C" void kernel_launch(void* const* d_in, const int* in_sizes, int n_in,
                              void* d_out, int out_size, void* d_ws, size_t ws_size,
                              hipStream_t stream) {
    const float* x_in       = (const float*)d_in[0];
    const float* workspace  = (const float*)d_in[1];
    const float* compete_w  = (const float*)d_in[2];
    const float* compete_b  = (const float*)d_in[3];
    const float* write_w    = (const float*)d_in[4];
    const float* write_b    = (const float*)d_in[5];
    const float* in_proj_w  = (const float*)d_in[6];
    const float* in_proj_b  = (const float*)d_in[7];
    const float* out_proj_w = (const float*)d_in[8];
    const float* out_proj_b = (const float*)d_in[9];
    const float* norm_pre_w  = (const float*)d_in[12];
    const float* norm_post_w = (const float*)d_in[13];
    float* xout = (float*)d_out;

    char* base = (char*)d_ws;
    size_t off = 0;
    auto alloc = [&](size_t bytes) {
        void* p = base + off;
        off += (bytes + 255) & ~(size_t)255;
        return p;
    };
    ushort* xb      = (ushort*)alloc((size_t)BL * D * 2);
    ushort* xbb     = (ushort*)alloc((size_t)BL * D * 2);     // x_b (bf16)
    float*  logits  = (float*) alloc((size_t)BATCH * NSLOT * LSEQ * 4);
    ushort* xbar    = (ushort*)alloc((size_t)BATCH * NSLOT * D * 2);
    float*  written = (float*) alloc((size_t)BATCH * NSLOT * D * 4);
    float*  wsbuf   = (float*) alloc((size_t)BATCH * NSLOT * D * 4);
    ushort* wsb     = (ushort*)alloc((size_t)BATCH * NSLOT * D * 2);
    ushort* ipb     = (ushort*)alloc((size_t)3 * D * D * 2);
    ushort* wob     = (ushort*)alloc((size_t)D * D * 2);
    ushort* wwb     = (ushort*)alloc((size_t)D * D * 2);
    ushort* wqt     = (ushort*)alloc((size_t)D * D * 2);      // Wq^T bf16
    ushort* kb16    = (ushort*)alloc((size_t)BATCH * NHEAD * NSLOT * HDIM * 2);
    ushort* vb16    = (ushort*)alloc((size_t)BATCH * NHEAD * NSLOT * HDIM * 2);
    ushort* ktil    = (ushort*)alloc((size_t)BATCH * 512 * D * 2);   // K~ rows b*512+hs
    ushort* wtilT   = (ushort*)alloc((size_t)D * BATCH * 512 * 2);   // W~^T rows j
    float*  qlog    = (float*) alloc((size_t)2 * BL * 512 * 4);      // 2 K-split planes
    ushort* aatt    = (ushort*)alloc((size_t)BL * 512 * 2);
    float*  cbias   = (float*) alloc((size_t)BATCH * 512 * 4);
    (void)ws_size; (void)in_sizes; (void)n_in; (void)out_size;

    conv_bf16_kernel<<<2048, 256, 0, stream>>>((const float4*)in_proj_w, ipb, 3 * D * D / 4);
    conv_bf16_kernel<<<2048, 256, 0, stream>>>((const float4*)out_proj_w, wob, D * D / 4);
    conv_bf16_kernel<<<2048, 256, 0, stream>>>((const float4*)write_w, wwb, D * D / 4);
    conv_bf16_kernel<<<2048, 256, 0, stream>>>((const float4*)x_in, xb, BL * D / 4);
    transpose_bf16_kernel<<<1024, 256, 0, stream>>>(ipb, wqt);   // Wq^T (q rows 0..D)

    for (int it = 0; it < 2; ++it) {
        const float* xs = it ? (const float*)xout : x_in;
        logits_kernel<<<BL / 4, 256, 0, stream>>>(xs, compete_w, compete_b, norm_pre_w,
                                                  logits);
        topk_xbar_kernel<<<BATCH * NSLOT, 256, 0, stream>>>(logits, xs, xbar);
        // written = xbar @ wwb^T + write_b   (64x2048, K=2048) — 512 waves
        gemm_tiny<0><<<128, 256, 0, stream>>>(xbar, wwb, write_b, written,
                                              BATCH * NSLOT, D, D,
                                              (ushort*)nullptr, (ushort*)nullptr);
        ws_update_kernel<<<BATCH * NSLOT, 256, 0, stream>>>(written, wsbuf, workspace,
                                                            it == 0 ? 1 : 0, norm_post_w,
                                                            wsbuf, wsb);
        // kv = wsb @ Wkv^T + bkv  (64x4096, K=2048) — 1024 waves, scatter to kb/vb
        gemm_tiny<1><<<256, 256, 0, stream>>>(wsb, ipb + (size_t)D * D, in_proj_b + D,
                                              (float*)nullptr, BATCH * NSLOT, 2 * D, D,
                                              kb16, vb16);
        cbias_kernel<<<8, 256, 0, stream>>>(kb16, in_proj_b, cbias);
        grouped16_kernel<0><<<1024, 256, 0, stream>>>(kb16, wqt, ktil);
        grouped16_kernel<1><<<1024, 256, 0, stream>>>(vb16, wob, wtilT);
        // qlog[z][l, hs] = xb[l, zK:zK+1024] . K~[b,hs, zK:zK+1024]  (split-K=2)
        gemm_bt<64, 0><<<dim3(512 / 128, BL / 64, 2), 256, 0, stream>>>(
            xb, ktil, (const float*)nullptr, qlog, BL, 512, D / 2,
            (size_t)512 * D, D, D, D / 2, D / 2, (size_t)BL * 512);
        attn_sm_kernel<<<BL / 8, 256, 0, stream>>>(qlog, cbias, aatt);
        // x_b[l, j] (bf16) = sum_hs aatt[l,hs] * W~T[j, b*512+hs] + out_proj_b[j]
        gemm_bt<64, 1><<<dim3(D / 128, BL / 64), 256, 0, stream>>>(
            aatt, wtilT, out_proj_b, (float*)xbb, BL, D, 512,
            (size_t)512, D, 512, 0, 0, 0);
        resid_rms_kernel<<<BL, 256, 0, stream>>>(xs, xbb, norm_post_w, xout, xb);
    }
}

// Round 19
// 496.439 us; speedup vs baseline: 1.1121x; 1.0770x over previous
//
#include <hip/hip_runtime.h>
#include <stdint.h>

#define D 2048
#define LSEQ 2048
#define BATCH 4
#define BL (BATCH * LSEQ)   // 8192 rows
#define NSLOT 16
#define NHEAD 32
#define HDIM 64
#define EPSV 1e-6f

typedef __attribute__((ext_vector_type(8))) short bf16x8;
typedef __attribute__((ext_vector_type(4))) float f32x4;

static __device__ __forceinline__ ushort f2bf(float f) {
    uint32_t u = __float_as_uint(f);
    u += 0x7fffu + ((u >> 16) & 1u);   // RNE
    return (ushort)(u >> 16);
}

// DPP-based xor-add level: lane i receives lane i^off's value via the VALU/DPP
// pipe instead of the LDS shuffle pipe. Values are IDENTICAL to __shfl_xor ->
// bit-exact sums. CTRL: 0x128=row_ror:8 (==xor8 within a 16-lane row),
// 0x4E=quad_perm[2,3,0,1] (==xor2), 0xB1=quad_perm[1,0,3,2] (==xor1).
// CTRL must be a compile-time constant (builtin requirement) -> template.
template <int CTRL>
static __device__ __forceinline__ float dpp_xadd(float v) {
    int t = __builtin_amdgcn_mov_dpp(__float_as_int(v), CTRL, 0xf, 0xf, true);
    return v + __int_as_float(t);
}

// Bit-exact butterfly sum, same order as the original (off = 32,16,8,4,2,1),
// with 3 of 6 levels moved off the shared per-CU LDS pipe onto VALU DPP.
static __device__ __forceinline__ float wave_sum(float v) {
    v += __shfl_xor(v, 32, 64);
    v += __shfl_xor(v, 16, 64);
    v = dpp_xadd<0x128>(v);   // xor 8
    v += __shfl_xor(v, 4, 64);
    v = dpp_xadd<0x4E>(v);    // xor 2
    v = dpp_xadd<0xB1>(v);    // xor 1
    return v;
}

static __device__ __forceinline__ void gl_lds16(const void* g, void* l) {
    __builtin_amdgcn_global_load_lds(
        (__attribute__((address_space(1))) uint32_t*)(uintptr_t)g,
        (__attribute__((address_space(3))) uint32_t*)(uint32_t)(uintptr_t)l,
        16, 0, 0);
}

// ---------------- weight convert f32 -> bf16 ----------------
__global__ __launch_bounds__(256) void conv_bf16_kernel(const float4* __restrict__ src,
                                                        ushort* __restrict__ dst, int n4) {
    int i = blockIdx.x * 256 + threadIdx.x;
    int stride = gridDim.x * 256;
    for (; i < n4; i += stride) {
        float4 v = src[i];
        uint2 o;
        o.x = (uint)f2bf(v.x) | ((uint)f2bf(v.y) << 16);
        o.y = (uint)f2bf(v.z) | ((uint)f2bf(v.w) << 16);
        *(uint2*)(dst + (size_t)i * 4) = o;
    }
}

// ---------------- 2048x2048 bf16 transpose (once, for Wq^T) ----------------
__global__ __launch_bounds__(256) void transpose_bf16_kernel(const ushort* __restrict__ src,
                                                             ushort* __restrict__ dst) {
    __shared__ ushort t[64][72];
    int bx = blockIdx.x & 31, by = blockIdx.x >> 5;
    int r0 = by * 64, c0 = bx * 64;
    int tid = threadIdx.x;
    int lr = tid >> 3;
    int lc = (tid & 7) * 8;
#pragma unroll
    for (int p = 0; p < 2; ++p) {
        int rr = p * 32 + lr;
        bf16x8 v = *(const bf16x8*)(src + (size_t)(r0 + rr) * 2048 + c0 + lc);
#pragma unroll
        for (int j = 0; j < 8; ++j) t[lc + j][rr] = (ushort)v[j];
    }
    __syncthreads();
#pragma unroll
    for (int p = 0; p < 2; ++p) {
        int rr = p * 32 + lr;
        *(bf16x8*)(dst + (size_t)(c0 + rr) * 2048 + r0 + lc) = *(const bf16x8*)&t[rr][lc];
    }
}

// ---------------- logits v8: v6 schedule + DPP wave_sum (bit-exact) --------------
// Arithmetic (values/order) is UNCHANGED vs the passing kernels — only the lane
// data-movement mechanism changed (LDS shuffle pipe -> VALU DPP for 3 levels).
// DO NOT change any FP op here: logits feed top-k (order-statistic discontinuity).
__global__ __launch_bounds__(256) void logits_kernel(
    const float* __restrict__ x, const float* __restrict__ cw,
    const float* __restrict__ cb, const float* __restrict__ wpre,
    float* __restrict__ logits_t) {
    int blk = blockIdx.x;              // 2048 blocks, 4 rows each
    int b = blk >> 9;                  // 512 blocks per batch
    int l0 = (blk & 511) << 2;
    int tid = threadIdx.x;
    int i0 = tid * 8;
    float4 w0 = *(const float4*)(wpre + i0);
    float4 w1 = *(const float4*)(wpre + i0 + 4);
    float wv[8] = {w0.x, w0.y, w0.z, w0.w, w1.x, w1.y, w1.z, w1.w};
    float xw[4][8];
    float ss[4];
#pragma unroll
    for (int r = 0; r < 4; ++r) {
        const float* xr = x + ((size_t)(b * LSEQ + l0 + r)) * D;
        float4 a0 = *(const float4*)(xr + i0);
        float4 a1 = *(const float4*)(xr + i0 + 4);
        float xv[8] = {a0.x, a0.y, a0.z, a0.w, a1.x, a1.y, a1.z, a1.w};
        float s0 = 0.f;
#pragma unroll
        for (int j = 0; j < 8; ++j) { s0 += xv[j] * xv[j]; xw[r][j] = xv[j] * wv[j]; }
        ss[r] = s0;
    }
#pragma unroll
    for (int r = 0; r < 4; ++r) ss[r] = wave_sum(ss[r]);
    __shared__ float red[4][NSLOT][4];
    __shared__ float redss[4][4];
    int lane = tid & 63, w = tid >> 6;
    if (lane == 0) {
#pragma unroll
        for (int r = 0; r < 4; ++r) redss[w][r] = ss[r];
    }
#pragma unroll 2
    for (int s = 0; s < NSLOT; ++s) {
        const float* cwr = cw + (size_t)s * D + i0;
        float4 c0 = *(const float4*)(cwr);
        float4 c1 = *(const float4*)(cwr + 4);
        float acc[4];
#pragma unroll
        for (int r = 0; r < 4; ++r)
            acc[r] = xw[r][0] * c0.x + xw[r][1] * c0.y + xw[r][2] * c0.z + xw[r][3] * c0.w +
                     xw[r][4] * c1.x + xw[r][5] * c1.y + xw[r][6] * c1.z + xw[r][7] * c1.w;
#pragma unroll
        for (int r = 0; r < 4; ++r) acc[r] = wave_sum(acc[r]);
        if (lane == 0) {
#pragma unroll
            for (int r = 0; r < 4; ++r) red[w][s][r] = acc[r];
        }
    }
    __syncthreads();
    if (tid < 64) {
        int s = tid >> 2, r = tid & 3;
        float tot = red[0][s][r] + red[1][s][r] + red[2][s][r] + red[3][s][r];
        float s2 = redss[0][r] + redss[1][r] + redss[2][r] + redss[3][r];
        float rsq = 1.0f / sqrtf(s2 * (1.0f / (float)D) + EPSV);
        logits_t[((size_t)(b * NSLOT + s)) * LSEQ + l0 + r] = tot * rsq + cb[s];
    }
}

// ---------------- top-4 + softmax + weighted row gather (xbar, bf16) ----------------
__global__ __launch_bounds__(256) void topk_xbar_kernel(
    const float* __restrict__ logits_t, const float* __restrict__ x,
    ushort* __restrict__ xbar_b) {
    int bs = blockIdx.x;
    int b = bs >> 4;
    const float* lr = logits_t + (size_t)bs * LSEQ;
    int tid = threadIdx.x, lane = tid & 63, w = tid >> 6;
    __shared__ float rv[4];
    __shared__ int ri[4];
    __shared__ float selv[4];
    __shared__ int seli[4];
    int i0 = tid * 8;
    float myv[8];
#pragma unroll
    for (int j = 0; j < 8; ++j) myv[j] = lr[i0 + j];
    int chosen[4];
    for (int p = 0; p < 4; ++p) {
        float bv = -3.4e38f;
        int bi = 0x7fffffff;
#pragma unroll
        for (int j = 0; j < 8; ++j) {
            int i = i0 + j;
            bool skip = false;
            for (int q = 0; q < p; ++q) skip = skip || (i == chosen[q]);
            float v = myv[j];
            if (!skip && (v > bv || (v == bv && i < bi))) { bv = v; bi = i; }
        }
#pragma unroll
        for (int off = 1; off < 64; off <<= 1) {
            float ov = __shfl_xor(bv, off, 64);
            int oi = __shfl_xor(bi, off, 64);
            if (ov > bv || (ov == bv && oi < bi)) { bv = ov; bi = oi; }
        }
        if (lane == 0) { rv[w] = bv; ri[w] = bi; }
        __syncthreads();
        if (tid == 0) {
            float fv = rv[0];
            int fi = ri[0];
            for (int q = 1; q < 4; ++q)
                if (rv[q] > fv || (rv[q] == fv && ri[q] < fi)) { fv = rv[q]; fi = ri[q]; }
            selv[p] = fv;
            seli[p] = fi;
        }
        __syncthreads();
        chosen[p] = seli[p];
    }
    float vals[4];
#pragma unroll
    for (int p = 0; p < 4; ++p) vals[p] = selv[p];
    float mx = vals[0];   // first pick is the max
    float e[4], den = 0.f;
#pragma unroll
    for (int p = 0; p < 4; ++p) { e[p] = expf(vals[p] - mx); den += e[p]; }
    float inv = 1.0f / den;
    const float* xr0 = x + ((size_t)b * LSEQ + chosen[0]) * D;
    const float* xr1 = x + ((size_t)b * LSEQ + chosen[1]) * D;
    const float* xr2 = x + ((size_t)b * LSEQ + chosen[2]) * D;
    const float* xr3 = x + ((size_t)b * LSEQ + chosen[3]) * D;
    float s[8];
#pragma unroll
    for (int j = 0; j < 8; ++j) {
        int i = i0 + j;
        s[j] = (e[0] * xr0[i] + e[1] * xr1[i] + e[2] * xr2[i] + e[3] * xr3[i]) * inv;
    }
    uint4 o;
    o.x = (uint)f2bf(s[0]) | ((uint)f2bf(s[1]) << 16);
    o.y = (uint)f2bf(s[2]) | ((uint)f2bf(s[3]) << 16);
    o.z = (uint)f2bf(s[4]) | ((uint)f2bf(s[5]) << 16);
    o.w = (uint)f2bf(s[6]) | ((uint)f2bf(s[7]) << 16);
    *(uint4*)(xbar_b + (size_t)bs * D + i0) = o;
}

// ---------------- ws = rms(ws_prev + written) (+bf16 copy) ----------------
__global__ __launch_bounds__(256) void ws_update_kernel(
    const float* __restrict__ written, const float* __restrict__ ws_prev,
    const float* __restrict__ workspace0, int first,
    const float* __restrict__ wpost, float* __restrict__ ws_out,
    ushort* __restrict__ ws_b) {
    int bs = blockIdx.x;
    int s = bs & (NSLOT - 1);
    int tid = threadIdx.x;
    int i0 = tid * 8;
    const float* prev = first ? (workspace0 + (size_t)s * D) : (ws_prev + (size_t)bs * D);
    const float* wr = written + (size_t)bs * D;
    float4 p0 = *(const float4*)(prev + i0);
    float4 p1 = *(const float4*)(prev + i0 + 4);
    float4 q0 = *(const float4*)(wr + i0);
    float4 q1 = *(const float4*)(wr + i0 + 4);
    float t[8] = {p0.x + q0.x, p0.y + q0.y, p0.z + q0.z, p0.w + q0.w,
                  p1.x + q1.x, p1.y + q1.y, p1.z + q1.z, p1.w + q1.w};
    float ss = 0.f;
#pragma unroll
    for (int j = 0; j < 8; ++j) ss += t[j] * t[j];
    ss = wave_sum(ss);
    __shared__ float sb[4];
    if ((tid & 63) == 0) sb[tid >> 6] = ss;
    __syncthreads();
    ss = sb[0] + sb[1] + sb[2] + sb[3];
    float rsq = 1.0f / sqrtf(ss * (1.0f / (float)D) + EPSV);
    float4 w0 = *(const float4*)(wpost + i0);
    float4 w1 = *(const float4*)(wpost + i0 + 4);
    float wv[8] = {w0.x, w0.y, w0.z, w0.w, w1.x, w1.y, w1.z, w1.w};
    float o[8];
#pragma unroll
    for (int j = 0; j < 8; ++j) o[j] = t[j] * rsq * wv[j];
    float4 r0 = {o[0], o[1], o[2], o[3]};
    float4 r1 = {o[4], o[5], o[6], o[7]};
    *(float4*)(ws_out + (size_t)bs * D + i0) = r0;
    *(float4*)(ws_out + (size_t)bs * D + i0 + 4) = r1;
    uint4 ob;
    ob.x = (uint)f2bf(o[0]) | ((uint)f2bf(o[1]) << 16);
    ob.y = (uint)f2bf(o[2]) | ((uint)f2bf(o[3]) << 16);
    ob.z = (uint)f2bf(o[4]) | ((uint)f2bf(o[5]) << 16);
    ob.w = (uint)f2bf(o[6]) | ((uint)f2bf(o[7]) << 16);
    *(uint4*)(ws_b + (size_t)bs * D + i0) = ob;
}

// ---------------- x = rms(x + attn_out[bf16]) (+bf16 copy) ----------------
__global__ __launch_bounds__(256) void resid_rms_kernel(
    const float* __restrict__ x_src, const ushort* __restrict__ ao,
    const float* __restrict__ wpost, float* __restrict__ x_dst,
    ushort* __restrict__ xb) {
    int row = blockIdx.x;
    int tid = threadIdx.x;
    int i0 = tid * 8;
    const float* xr = x_src + (size_t)row * D;
    uint4 av = *(const uint4*)(ao + (size_t)row * D + i0);
    float af[8];
    af[0] = __uint_as_float(av.x << 16);
    af[1] = __uint_as_float(av.x & 0xffff0000u);
    af[2] = __uint_as_float(av.y << 16);
    af[3] = __uint_as_float(av.y & 0xffff0000u);
    af[4] = __uint_as_float(av.z << 16);
    af[5] = __uint_as_float(av.z & 0xffff0000u);
    af[6] = __uint_as_float(av.w << 16);
    af[7] = __uint_as_float(av.w & 0xffff0000u);
    float4 p0 = *(const float4*)(xr + i0);
    float4 p1 = *(const float4*)(xr + i0 + 4);
    float t[8] = {p0.x + af[0], p0.y + af[1], p0.z + af[2], p0.w + af[3],
                  p1.x + af[4], p1.y + af[5], p1.z + af[6], p1.w + af[7]};
    float ss = 0.f;
#pragma unroll
    for (int j = 0; j < 8; ++j) ss += t[j] * t[j];
    ss = wave_sum(ss);
    __shared__ float sb[4];
    if ((tid & 63) == 0) sb[tid >> 6] = ss;
    __syncthreads();
    ss = sb[0] + sb[1] + sb[2] + sb[3];
    float rsq = 1.0f / sqrtf(ss * (1.0f / (float)D) + EPSV);
    float4 w0 = *(const float4*)(wpost + i0);
    float4 w1 = *(const float4*)(wpost + i0 + 4);
    float wv[8] = {w0.x, w0.y, w0.z, w0.w, w1.x, w1.y, w1.z, w1.w};
    float o[8];
#pragma unroll
    for (int j = 0; j < 8; ++j) o[j] = t[j] * rsq * wv[j];
    float4 r0 = {o[0], o[1], o[2], o[3]};
    float4 r1 = {o[4], o[5], o[6], o[7]};
    *(float4*)(x_dst + (size_t)row * D + i0) = r0;
    *(float4*)(x_dst + (size_t)row * D + i0 + 4) = r1;
    uint4 ob;
    ob.x = (uint)f2bf(o[0]) | ((uint)f2bf(o[1]) << 16);
    ob.y = (uint)f2bf(o[2]) | ((uint)f2bf(o[3]) << 16);
    ob.z = (uint)f2bf(o[4]) | ((uint)f2bf(o[5]) << 16);
    ob.w = (uint)f2bf(o[6]) | ((uint)f2bf(o[7]) << 16);
    *(uint4*)(xb + (size_t)row * D + i0) = ob;
}

// ---------------- grouped 16x64 GEMM body (device) ----------------
// per (b,h): C[16x2048] = A[16x64] @ Bslice^T; TRANS selects output layout.
template <int TRANS>
static __device__ __forceinline__ void grouped16_body(
    int blk, const ushort* __restrict__ Abase, const ushort* __restrict__ Bmat,
    ushort* __restrict__ Cout) {
    int g = blk >> 3;               // 0..127 = b*32+h
    int nt = blk & 7;
    int h = g & 31;
    int hoff = h * 64;
    int tid = threadIdx.x, lane = tid & 63, wv = tid >> 6;
    int j0 = nt * 256 + wv * 64;
    int rr = lane & 15, ko = lane >> 4;
    const ushort* A = Abase + (size_t)g * 16 * 64;
    bf16x8 af0 = *(const bf16x8*)(A + rr * 64 + ko * 8);
    bf16x8 af1 = *(const bf16x8*)(A + rr * 64 + 32 + ko * 8);
    f32x4 acc[4];
    f32x4 zero = {0.f, 0.f, 0.f, 0.f};
#pragma unroll
    for (int nf = 0; nf < 4; ++nf) acc[nf] = zero;
#pragma unroll
    for (int nf = 0; nf < 4; ++nf) {
        int j = j0 + nf * 16 + rr;
        bf16x8 b0 = *(const bf16x8*)(Bmat + (size_t)j * 2048 + hoff + ko * 8);
        bf16x8 b1 = *(const bf16x8*)(Bmat + (size_t)j * 2048 + hoff + 32 + ko * 8);
        acc[nf] = __builtin_amdgcn_mfma_f32_16x16x32_bf16(af0, b0, acc[nf], 0, 0, 0);
        acc[nf] = __builtin_amdgcn_mfma_f32_16x16x32_bf16(af1, b1, acc[nf], 0, 0, 0);
    }
#pragma unroll
    for (int nf = 0; nf < 4; ++nf)
#pragma unroll
        for (int r = 0; r < 4; ++r) {
            int s = ko * 4 + r;
            int j = j0 + nf * 16 + rr;
            ushort v = f2bf(acc[nf][r]);
            if (TRANS) Cout[(size_t)j * 2048 + g * 16 + s] = v;
            else       Cout[(size_t)(g * 16 + s) * 2048 + j] = v;
        }
}

// ---------------- fused: grouped16<0> (ktil) | grouped16<1> (wtilT) | cbias -------
// All three are mutually independent and depend only on kb16/vb16 — one dispatch
// replaces three (cuts 2 launch bubbles). Code paths byte-identical to before.
__global__ __launch_bounds__(256) void fused_prep_kernel(
    const ushort* __restrict__ kb16, const ushort* __restrict__ vb16,
    const float* __restrict__ bq, const ushort* __restrict__ wqt,
    const ushort* __restrict__ wob, ushort* __restrict__ ktil,
    ushort* __restrict__ wtilT, float* __restrict__ cbias) {
    int blk = blockIdx.x;
    if (blk < 1024) {
        grouped16_body<0>(blk, kb16, wqt, ktil);
    } else if (blk < 2048) {
        grouped16_body<1>(blk - 1024, vb16, wob, wtilT);
    } else {
        int i = (blk - 2048) * 256 + threadIdx.x;   // 0..2047
        int hs = i & 511;
        int h = hs >> 4;
        const ushort* kr = kb16 + (size_t)i * 64;
        const float* bb = bq + h * 64;
        float acc = 0.f;
#pragma unroll
        for (int d = 0; d < 64; ++d)
            acc += __uint_as_float(((uint)kr[d]) << 16) * bb[d];
        cbias[i] = acc;
    }
}

// ---------------- attn softmax: A_att = softmax_s((qlog0+qlog1+cbias)*0.125) ------
__global__ __launch_bounds__(256) void attn_sm_kernel(
    const float* __restrict__ qlog, const float* __restrict__ cb,
    ushort* __restrict__ aatt) {
    int blk = blockIdx.x;               // 1024 blocks x 8 rows
    int tid = threadIdx.x;
    int l = blk * 8 + (tid >> 5);
    int b = l >> 11;
    int h = tid & 31;
    const float* q0 = qlog + (size_t)l * 512 + h * 16;
    const float* q1 = q0 + (size_t)BL * 512;
    const float* c = cb + b * 512 + h * 16;
    float p[16];
#pragma unroll
    for (int i = 0; i < 16; i += 4) {
        float4 v0 = *(const float4*)(q0 + i);
        float4 v1 = *(const float4*)(q1 + i);
        float4 cc = *(const float4*)(c + i);
        p[i]     = v0.x + v1.x + cc.x;
        p[i + 1] = v0.y + v1.y + cc.y;
        p[i + 2] = v0.z + v1.z + cc.z;
        p[i + 3] = v0.w + v1.w + cc.w;
    }
    float mx = p[0];
#pragma unroll
    for (int s = 1; s < 16; ++s) mx = fmaxf(mx, p[s]);
    float den = 0.f;
#pragma unroll
    for (int s = 0; s < 16; ++s) { p[s] = __expf((p[s] - mx) * 0.125f); den += p[s]; }
    float inv = 1.0f / den;
    uint4 o[2];
    uint* ow = (uint*)o;
#pragma unroll
    for (int i = 0; i < 8; ++i)
        ow[i] = (uint)f2bf(p[2 * i] * inv) | ((uint)f2bf(p[2 * i + 1] * inv) << 16);
    ushort* dst = aatt + (size_t)l * 512 + h * 16;
    *(uint4*)dst = o[0];
    *(uint4*)(dst + 8) = o[1];
}

// ---------------- tiny-M GEMM: one wave per 16x16 output tile, no LDS/barriers ----
template <int KVMODE>
__global__ __launch_bounds__(256) void gemm_tiny(
    const ushort* __restrict__ A, const ushort* __restrict__ Bw,
    const float* __restrict__ bias, float* __restrict__ C,
    int M, int N, int K, ushort* __restrict__ kvk, ushort* __restrict__ kvv) {
    int gw = (blockIdx.x * 256 + threadIdx.x) >> 6;
    int lane = threadIdx.x & 63;
    int ntiles = N >> 4;
    int nt = gw % ntiles, mt = gw / ntiles;
    int rr = lane & 15, ko = lane >> 4;
    const ushort* Ar = A + (size_t)(mt * 16 + rr) * K;
    const ushort* Br = Bw + (size_t)(nt * 16 + rr) * K;
    f32x4 acc = {0.f, 0.f, 0.f, 0.f};
    int NT = K / 32;
#pragma unroll 8
    for (int t = 0; t < NT; ++t) {
        bf16x8 af = *(const bf16x8*)(Ar + t * 32 + ko * 8);
        bf16x8 bf = *(const bf16x8*)(Br + t * 32 + ko * 8);
        acc = __builtin_amdgcn_mfma_f32_16x16x32_bf16(af, bf, acc, 0, 0, 0);
    }
    int col = nt * 16 + rr;
    float bsv = bias ? bias[col] : 0.f;
#pragma unroll
    for (int r = 0; r < 4; ++r) {
        int rowi = mt * 16 + ko * 4 + r;
        float v = acc[r] + bsv;
        if (KVMODE) {
            int b = rowi >> 4, s = rowi & 15;
            int c2 = (col < 2048) ? col : col - 2048;
            int h = c2 >> 6, d = c2 & 63;
            size_t dst = (((size_t)(b * NHEAD + h)) * NSLOT + s) * HDIM + d;
            if (col < 2048) kvk[dst] = f2bf(v);
            else            kvv[dst] = f2bf(v);
        } else {
            C[(size_t)rowi * N + col] = v;
        }
    }
}

// ---------------- bf16 MFMA GEMM: C[m,n] = sum_k A[m,k]*Bw[n,k] + bias[n] ----------
// OBF=1: write bf16 to ((ushort*)C). bOff: per-batch B offset; strides/z as before.
template <int BM, int OBF>
__global__ __launch_bounds__(256) void gemm_bt(
    const ushort* __restrict__ A, const ushort* __restrict__ Bw,
    const float* __restrict__ bias, float* __restrict__ C,
    int M, int N, int K, size_t bOff, int bStride, int aStride,
    int zA, int zB, size_t zC) {
    constexpr int BN = 128, BK = 32;
    constexpr int MF = BM / 32;
    constexpr int APASS = (BM * BK / 8) / 256;
    __shared__ short lds[2][(BM + BN) * BK];
    int tid = threadIdx.x;
    int lane = tid & 63, w = tid >> 6;
    int wr = w >> 1, wc = w & 1;
    int tn = blockIdx.x * BN;
    int tm = blockIdx.y * BM;
    int ksl = blockIdx.z;
    A += (size_t)ksl * zA;
    Bw += (size_t)ksl * zB + (size_t)(tm >> 11) * bOff;
    C += (size_t)ksl * zC;
    f32x4 acc[MF][4];
    f32x4 zero = {0.f, 0.f, 0.f, 0.f};
#pragma unroll
    for (int m = 0; m < MF; ++m)
#pragma unroll
        for (int n = 0; n < 4; ++n) acc[m][n] = zero;
    int NT = K / BK;

    auto stage = [&](int buf, int t) {
        int kt = t * BK;
#pragma unroll
        for (int p = 0; p < APASS; ++p) {
            int cb = p * 256 + w * 64;
            int c = cb + lane;
            int r = c >> 2;
            int k8 = (c & 3) * 8;
            int gr = tm + r;
            if (gr >= M) gr = M - 1;
            gl_lds16(A + (size_t)gr * aStride + kt + k8, (void*)&lds[buf][cb * 8]);
        }
#pragma unroll
        for (int p = 0; p < 2; ++p) {
            int cb = p * 256 + w * 64;
            int c = cb + lane;
            int r = c >> 2;
            int k8 = (c & 3) * 8;
            gl_lds16(Bw + (size_t)(tn + r) * bStride + kt + k8,
                     (void*)&lds[buf][BM * BK + cb * 8]);
        }
    };
    stage(0, 0);
    for (int t = 0; t < NT; ++t) {
        __syncthreads();
        if (t + 1 < NT) stage((t + 1) & 1, t + 1);
        const short* Ab = &lds[t & 1][0];
        const short* Bb = &lds[t & 1][BM * BK];
        int ko = (lane >> 4) * 8;
        int rr = lane & 15;
        bf16x8 af[MF], bfr[4];
#pragma unroll
        for (int m = 0; m < MF; ++m)
            af[m] = *(const bf16x8*)&Ab[(wr * (MF * 16) + m * 16 + rr) * BK + ko];
#pragma unroll
        for (int n = 0; n < 4; ++n)
            bfr[n] = *(const bf16x8*)&Bb[(wc * 64 + n * 16 + rr) * BK + ko];
#pragma unroll
        for (int m = 0; m < MF; ++m)
#pragma unroll
            for (int n = 0; n < 4; ++n)
                acc[m][n] = __builtin_amdgcn_mfma_f32_16x16x32_bf16(af[m], bfr[n],
                                                                    acc[m][n], 0, 0, 0);
    }
#pragma unroll
    for (int m = 0; m < MF; ++m) {
#pragma unroll
        for (int n = 0; n < 4; ++n) {
            int col = tn + wc * 64 + n * 16 + (lane & 15);
            float bsv = bias ? bias[col] : 0.f;
#pragma unroll
            for (int r = 0; r < 4; ++r) {
                int rowi = tm + wr * (MF * 16) + m * 16 + (lane >> 4) * 4 + r;
                if (rowi >= M) continue;
                float v = acc[m][n][r] + bsv;
                if (OBF) ((ushort*)C)[(size_t)rowi * N + col] = f2bf(v);
                else     C[(size_t)rowi * N + col] = v;
            }
        }
    }
}

extern "C" void kernel_launch(void* const* d_in, const int* in_sizes, int n_in,
                              void* d_out, int out_size, void* d_ws, size_t ws_size,
                              hipStream_t stream) {
    const float* x_in       = (const float*)d_in[0];
    const float* workspace  = (const float*)d_in[1];
    const float* compete_w  = (const float*)d_in[2];
    const float* compete_b  = (const float*)d_in[3];
    const float* write_w    = (const float*)d_in[4];
    const float* write_b    = (const float*)d_in[5];
    const float* in_proj_w  = (const float*)d_in[6];
    const float* in_proj_b  = (const float*)d_in[7];
    const float* out_proj_w = (const float*)d_in[8];
    const float* out_proj_b = (const float*)d_in[9];
    const float* norm_pre_w  = (const float*)d_in[12];
    const float* norm_post_w = (const float*)d_in[13];
    float* xout = (float*)d_out;

    char* base = (char*)d_ws;
    size_t off = 0;
    auto alloc = [&](size_t bytes) {
        void* p = base + off;
        off += (bytes + 255) & ~(size_t)255;
        return p;
    };
    ushort* xb      = (ushort*)alloc((size_t)BL * D * 2);
    ushort* xbb     = (ushort*)alloc((size_t)BL * D * 2);     // x_b (bf16)
    float*  logits  = (float*) alloc((size_t)BATCH * NSLOT * LSEQ * 4);
    ushort* xbar    = (ushort*)alloc((size_t)BATCH * NSLOT * D * 2);
    float*  written = (float*) alloc((size_t)BATCH * NSLOT * D * 4);
    float*  wsbuf   = (float*) alloc((size_t)BATCH * NSLOT * D * 4);
    ushort* wsb     = (ushort*)alloc((size_t)BATCH * NSLOT * D * 2);
    ushort* ipb     = (ushort*)alloc((size_t)3 * D * D * 2);
    ushort* wob     = (ushort*)alloc((size_t)D * D * 2);
    ushort* wwb     = (ushort*)alloc((size_t)D * D * 2);
    ushort* wqt     = (ushort*)alloc((size_t)D * D * 2);      // Wq^T bf16
    ushort* kb16    = (ushort*)alloc((size_t)BATCH * NHEAD * NSLOT * HDIM * 2);
    ushort* vb16    = (ushort*)alloc((size_t)BATCH * NHEAD * NSLOT * HDIM * 2);
    ushort* ktil    = (ushort*)alloc((size_t)BATCH * 512 * D * 2);   // K~ rows b*512+hs
    ushort* wtilT   = (ushort*)alloc((size_t)D * BATCH * 512 * 2);   // W~^T rows j
    float*  qlog    = (float*) alloc((size_t)2 * BL * 512 * 4);      // 2 K-split planes
    ushort* aatt    = (ushort*)alloc((size_t)BL * 512 * 2);
    float*  cbias   = (float*) alloc((size_t)BATCH * 512 * 4);
    (void)ws_size; (void)in_sizes; (void)n_in; (void)out_size;

    conv_bf16_kernel<<<2048, 256, 0, stream>>>((const float4*)in_proj_w, ipb, 3 * D * D / 4);
    conv_bf16_kernel<<<2048, 256, 0, stream>>>((const float4*)out_proj_w, wob, D * D / 4);
    conv_bf16_kernel<<<2048, 256, 0, stream>>>((const float4*)write_w, wwb, D * D / 4);
    conv_bf16_kernel<<<2048, 256, 0, stream>>>((const float4*)x_in, xb, BL * D / 4);
    transpose_bf16_kernel<<<1024, 256, 0, stream>>>(ipb, wqt);   // Wq^T (q rows 0..D)

    for (int it = 0; it < 2; ++it) {
        const float* xs = it ? (const float*)xout : x_in;
        logits_kernel<<<BL / 4, 256, 0, stream>>>(xs, compete_w, compete_b, norm_pre_w,
                                                  logits);
        topk_xbar_kernel<<<BATCH * NSLOT, 256, 0, stream>>>(logits, xs, xbar);
        // written = xbar @ wwb^T + write_b   (64x2048, K=2048) — 512 waves
        gemm_tiny<0><<<128, 256, 0, stream>>>(xbar, wwb, write_b, written,
                                              BATCH * NSLOT, D, D,
                                              (ushort*)nullptr, (ushort*)nullptr);
        ws_update_kernel<<<BATCH * NSLOT, 256, 0, stream>>>(written, wsbuf, workspace,
                                                            it == 0 ? 1 : 0, norm_post_w,
                                                            wsbuf, wsb);
        // kv = wsb @ Wkv^T + bkv  (64x4096, K=2048) — 1024 waves, scatter to kb/vb
        gemm_tiny<1><<<256, 256, 0, stream>>>(wsb, ipb + (size_t)D * D, in_proj_b + D,
                                              (float*)nullptr, BATCH * NSLOT, 2 * D, D,
                                              kb16, vb16);
        // ktil | wtilT | cbias in one dispatch (independent, all need kb16/vb16)
        fused_prep_kernel<<<2056, 256, 0, stream>>>(kb16, vb16, in_proj_b, wqt, wob,
                                                    ktil, wtilT, cbias);
        // qlog[z][l, hs] = xb[l, zK:zK+1024] . K~[b,hs, zK:zK+1024]  (split-K=2)
        gemm_bt<64, 0><<<dim3(512 / 128, BL / 64, 2), 256, 0, stream>>>(
            xb, ktil, (const float*)nullptr, qlog, BL, 512, D / 2,
            (size_t)512 * D, D, D, D / 2, D / 2, (size_t)BL * 512);
        attn_sm_kernel<<<BL / 8, 256, 0, stream>>>(qlog, cbias, aatt);
        // x_b[l, j] (bf16) = sum_hs aatt[l,hs] * W~T[j, b*512+hs] + out_proj_b[j]
        gemm_bt<64, 1><<<dim3(D / 128, BL / 64), 256, 0, stream>>>(
            aatt, wtilT, out_proj_b, (float*)xbb, BL, D, 512,
            (size_t)512, D, 512, 0, 0, 0);
        resid_rms_kernel<<<BL, 256, 0, stream>>>(xs, xbb, norm_post_w, xout, xb);
    }
}

// Round 20
// 486.375 us; speedup vs baseline: 1.1351x; 1.0207x over previous
//
#include <hip/hip_runtime.h>
#include <stdint.h>

#define D 2048
#define LSEQ 2048
#define BATCH 4
#define BL (BATCH * LSEQ)   // 8192 rows
#define NSLOT 16
#define NHEAD 32
#define HDIM 64
#define EPSV 1e-6f

typedef __attribute__((ext_vector_type(8))) short bf16x8;
typedef __attribute__((ext_vector_type(4))) float f32x4;

static __device__ __forceinline__ ushort f2bf(float f) {
    uint32_t u = __float_as_uint(f);
    u += 0x7fffu + ((u >> 16) & 1u);   // RNE
    return (ushort)(u >> 16);
}

// DPP-based xor-add level (bit-exact vs __shfl_xor, runs on VALU not LDS pipe).
template <int CTRL>
static __device__ __forceinline__ float dpp_xadd(float v) {
    int t = __builtin_amdgcn_mov_dpp(__float_as_int(v), CTRL, 0xf, 0xf, true);
    return v + __int_as_float(t);
}

// Bit-exact butterfly sum, same order as original (off = 32,16,8,4,2,1),
// 3 of 6 levels on VALU DPP (proven R19: logits 50->~35us).
static __device__ __forceinline__ float wave_sum(float v) {
    v += __shfl_xor(v, 32, 64);
    v += __shfl_xor(v, 16, 64);
    v = dpp_xadd<0x128>(v);   // xor 8 (row_ror:8)
    v += __shfl_xor(v, 4, 64);
    v = dpp_xadd<0x4E>(v);    // xor 2 (quad_perm)
    v = dpp_xadd<0xB1>(v);    // xor 1 (quad_perm)
    return v;
}

static __device__ __forceinline__ void gl_lds16(const void* g, void* l) {
    __builtin_amdgcn_global_load_lds(
        (__attribute__((address_space(1))) uint32_t*)(uintptr_t)g,
        (__attribute__((address_space(3))) uint32_t*)(uint32_t)(uintptr_t)l,
        16, 0, 0);
}

// ---------------- weight convert f32 -> bf16 ----------------
__global__ __launch_bounds__(256) void conv_bf16_kernel(const float4* __restrict__ src,
                                                        ushort* __restrict__ dst, int n4) {
    int i = blockIdx.x * 256 + threadIdx.x;
    int stride = gridDim.x * 256;
    for (; i < n4; i += stride) {
        float4 v = src[i];
        uint2 o;
        o.x = (uint)f2bf(v.x) | ((uint)f2bf(v.y) << 16);
        o.y = (uint)f2bf(v.z) | ((uint)f2bf(v.w) << 16);
        *(uint2*)(dst + (size_t)i * 4) = o;
    }
}

// ---------------- 2048x2048 bf16 transpose (once, for Wq^T) ----------------
__global__ __launch_bounds__(256) void transpose_bf16_kernel(const ushort* __restrict__ src,
                                                             ushort* __restrict__ dst) {
    __shared__ ushort t[64][72];
    int bx = blockIdx.x & 31, by = blockIdx.x >> 5;
    int r0 = by * 64, c0 = bx * 64;
    int tid = threadIdx.x;
    int lr = tid >> 3;
    int lc = (tid & 7) * 8;
#pragma unroll
    for (int p = 0; p < 2; ++p) {
        int rr = p * 32 + lr;
        bf16x8 v = *(const bf16x8*)(src + (size_t)(r0 + rr) * 2048 + c0 + lc);
#pragma unroll
        for (int j = 0; j < 8; ++j) t[lc + j][rr] = (ushort)v[j];
    }
    __syncthreads();
#pragma unroll
    for (int p = 0; p < 2; ++p) {
        int rr = p * 32 + lr;
        *(bf16x8*)(dst + (size_t)(c0 + rr) * 2048 + r0 + lc) = *(const bf16x8*)&t[rr][lc];
    }
}

// ---------------- logits v8: DPP wave_sum, bit-exact (DO NOT touch FP ops) -------
__global__ __launch_bounds__(256) void logits_kernel(
    const float* __restrict__ x, const float* __restrict__ cw,
    const float* __restrict__ cb, const float* __restrict__ wpre,
    float* __restrict__ logits_t) {
    int blk = blockIdx.x;              // 2048 blocks, 4 rows each
    int b = blk >> 9;                  // 512 blocks per batch
    int l0 = (blk & 511) << 2;
    int tid = threadIdx.x;
    int i0 = tid * 8;
    float4 w0 = *(const float4*)(wpre + i0);
    float4 w1 = *(const float4*)(wpre + i0 + 4);
    float wv[8] = {w0.x, w0.y, w0.z, w0.w, w1.x, w1.y, w1.z, w1.w};
    float xw[4][8];
    float ss[4];
#pragma unroll
    for (int r = 0; r < 4; ++r) {
        const float* xr = x + ((size_t)(b * LSEQ + l0 + r)) * D;
        float4 a0 = *(const float4*)(xr + i0);
        float4 a1 = *(const float4*)(xr + i0 + 4);
        float xv[8] = {a0.x, a0.y, a0.z, a0.w, a1.x, a1.y, a1.z, a1.w};
        float s0 = 0.f;
#pragma unroll
        for (int j = 0; j < 8; ++j) { s0 += xv[j] * xv[j]; xw[r][j] = xv[j] * wv[j]; }
        ss[r] = s0;
    }
#pragma unroll
    for (int r = 0; r < 4; ++r) ss[r] = wave_sum(ss[r]);
    __shared__ float red[4][NSLOT][4];
    __shared__ float redss[4][4];
    int lane = tid & 63, w = tid >> 6;
    if (lane == 0) {
#pragma unroll
        for (int r = 0; r < 4; ++r) redss[w][r] = ss[r];
    }
#pragma unroll 2
    for (int s = 0; s < NSLOT; ++s) {
        const float* cwr = cw + (size_t)s * D + i0;
        float4 c0 = *(const float4*)(cwr);
        float4 c1 = *(const float4*)(cwr + 4);
        float acc[4];
#pragma unroll
        for (int r = 0; r < 4; ++r)
            acc[r] = xw[r][0] * c0.x + xw[r][1] * c0.y + xw[r][2] * c0.z + xw[r][3] * c0.w +
                     xw[r][4] * c1.x + xw[r][5] * c1.y + xw[r][6] * c1.z + xw[r][7] * c1.w;
#pragma unroll
        for (int r = 0; r < 4; ++r) acc[r] = wave_sum(acc[r]);
        if (lane == 0) {
#pragma unroll
            for (int r = 0; r < 4; ++r) red[w][s][r] = acc[r];
        }
    }
    __syncthreads();
    if (tid < 64) {
        int s = tid >> 2, r = tid & 3;
        float tot = red[0][s][r] + red[1][s][r] + red[2][s][r] + red[3][s][r];
        float s2 = redss[0][r] + redss[1][r] + redss[2][r] + redss[3][r];
        float rsq = 1.0f / sqrtf(s2 * (1.0f / (float)D) + EPSV);
        logits_t[((size_t)(b * NSLOT + s)) * LSEQ + l0 + r] = tot * rsq + cb[s];
    }
}

// ---------------- top-4 + softmax + weighted row gather (xbar, bf16) ----------------
__global__ __launch_bounds__(256) void topk_xbar_kernel(
    const float* __restrict__ logits_t, const float* __restrict__ x,
    ushort* __restrict__ xbar_b) {
    int bs = blockIdx.x;
    int b = bs >> 4;
    const float* lr = logits_t + (size_t)bs * LSEQ;
    int tid = threadIdx.x, lane = tid & 63, w = tid >> 6;
    __shared__ float rv[4];
    __shared__ int ri[4];
    __shared__ float selv[4];
    __shared__ int seli[4];
    int i0 = tid * 8;
    float myv[8];
#pragma unroll
    for (int j = 0; j < 8; ++j) myv[j] = lr[i0 + j];
    int chosen[4];
    for (int p = 0; p < 4; ++p) {
        float bv = -3.4e38f;
        int bi = 0x7fffffff;
#pragma unroll
        for (int j = 0; j < 8; ++j) {
            int i = i0 + j;
            bool skip = false;
            for (int q = 0; q < p; ++q) skip = skip || (i == chosen[q]);
            float v = myv[j];
            if (!skip && (v > bv || (v == bv && i < bi))) { bv = v; bi = i; }
        }
#pragma unroll
        for (int off = 1; off < 64; off <<= 1) {
            float ov = __shfl_xor(bv, off, 64);
            int oi = __shfl_xor(bi, off, 64);
            if (ov > bv || (ov == bv && oi < bi)) { bv = ov; bi = oi; }
        }
        if (lane == 0) { rv[w] = bv; ri[w] = bi; }
        __syncthreads();
        if (tid == 0) {
            float fv = rv[0];
            int fi = ri[0];
            for (int q = 1; q < 4; ++q)
                if (rv[q] > fv || (rv[q] == fv && ri[q] < fi)) { fv = rv[q]; fi = ri[q]; }
            selv[p] = fv;
            seli[p] = fi;
        }
        __syncthreads();
        chosen[p] = seli[p];
    }
    float vals[4];
#pragma unroll
    for (int p = 0; p < 4; ++p) vals[p] = selv[p];
    float mx = vals[0];   // first pick is the max
    float e[4], den = 0.f;
#pragma unroll
    for (int p = 0; p < 4; ++p) { e[p] = expf(vals[p] - mx); den += e[p]; }
    float inv = 1.0f / den;
    const float* xr0 = x + ((size_t)b * LSEQ + chosen[0]) * D;
    const float* xr1 = x + ((size_t)b * LSEQ + chosen[1]) * D;
    const float* xr2 = x + ((size_t)b * LSEQ + chosen[2]) * D;
    const float* xr3 = x + ((size_t)b * LSEQ + chosen[3]) * D;
    float s[8];
#pragma unroll
    for (int j = 0; j < 8; ++j) {
        int i = i0 + j;
        s[j] = (e[0] * xr0[i] + e[1] * xr1[i] + e[2] * xr2[i] + e[3] * xr3[i]) * inv;
    }
    uint4 o;
    o.x = (uint)f2bf(s[0]) | ((uint)f2bf(s[1]) << 16);
    o.y = (uint)f2bf(s[2]) | ((uint)f2bf(s[3]) << 16);
    o.z = (uint)f2bf(s[4]) | ((uint)f2bf(s[5]) << 16);
    o.w = (uint)f2bf(s[6]) | ((uint)f2bf(s[7]) << 16);
    *(uint4*)(xbar_b + (size_t)bs * D + i0) = o;
}

// ---------------- ws = rms(ws_prev + written) (+bf16 copy) ----------------
__global__ __launch_bounds__(256) void ws_update_kernel(
    const float* __restrict__ written, const float* __restrict__ ws_prev,
    const float* __restrict__ workspace0, int first,
    const float* __restrict__ wpost, float* __restrict__ ws_out,
    ushort* __restrict__ ws_b) {
    int bs = blockIdx.x;
    int s = bs & (NSLOT - 1);
    int tid = threadIdx.x;
    int i0 = tid * 8;
    const float* prev = first ? (workspace0 + (size_t)s * D) : (ws_prev + (size_t)bs * D);
    const float* wr = written + (size_t)bs * D;
    float4 p0 = *(const float4*)(prev + i0);
    float4 p1 = *(const float4*)(prev + i0 + 4);
    float4 q0 = *(const float4*)(wr + i0);
    float4 q1 = *(const float4*)(wr + i0 + 4);
    float t[8] = {p0.x + q0.x, p0.y + q0.y, p0.z + q0.z, p0.w + q0.w,
                  p1.x + q1.x, p1.y + q1.y, p1.z + q1.z, p1.w + q1.w};
    float ss = 0.f;
#pragma unroll
    for (int j = 0; j < 8; ++j) ss += t[j] * t[j];
    ss = wave_sum(ss);
    __shared__ float sb[4];
    if ((tid & 63) == 0) sb[tid >> 6] = ss;
    __syncthreads();
    ss = sb[0] + sb[1] + sb[2] + sb[3];
    float rsq = 1.0f / sqrtf(ss * (1.0f / (float)D) + EPSV);
    float4 w0 = *(const float4*)(wpost + i0);
    float4 w1 = *(const float4*)(wpost + i0 + 4);
    float wv[8] = {w0.x, w0.y, w0.z, w0.w, w1.x, w1.y, w1.z, w1.w};
    float o[8];
#pragma unroll
    for (int j = 0; j < 8; ++j) o[j] = t[j] * rsq * wv[j];
    float4 r0 = {o[0], o[1], o[2], o[3]};
    float4 r1 = {o[4], o[5], o[6], o[7]};
    *(float4*)(ws_out + (size_t)bs * D + i0) = r0;
    *(float4*)(ws_out + (size_t)bs * D + i0 + 4) = r1;
    uint4 ob;
    ob.x = (uint)f2bf(o[0]) | ((uint)f2bf(o[1]) << 16);
    ob.y = (uint)f2bf(o[2]) | ((uint)f2bf(o[3]) << 16);
    ob.z = (uint)f2bf(o[4]) | ((uint)f2bf(o[5]) << 16);
    ob.w = (uint)f2bf(o[6]) | ((uint)f2bf(o[7]) << 16);
    *(uint4*)(ws_b + (size_t)bs * D + i0) = ob;
}

// ---------------- x = rms(x + attn_out[bf16]) (+bf16 copy) ----------------
__global__ __launch_bounds__(256) void resid_rms_kernel(
    const float* __restrict__ x_src, const ushort* __restrict__ ao,
    const float* __restrict__ wpost, float* __restrict__ x_dst,
    ushort* __restrict__ xb) {
    int row = blockIdx.x;
    int tid = threadIdx.x;
    int i0 = tid * 8;
    const float* xr = x_src + (size_t)row * D;
    uint4 av = *(const uint4*)(ao + (size_t)row * D + i0);
    float af[8];
    af[0] = __uint_as_float(av.x << 16);
    af[1] = __uint_as_float(av.x & 0xffff0000u);
    af[2] = __uint_as_float(av.y << 16);
    af[3] = __uint_as_float(av.y & 0xffff0000u);
    af[4] = __uint_as_float(av.z << 16);
    af[5] = __uint_as_float(av.z & 0xffff0000u);
    af[6] = __uint_as_float(av.w << 16);
    af[7] = __uint_as_float(av.w & 0xffff0000u);
    float4 p0 = *(const float4*)(xr + i0);
    float4 p1 = *(const float4*)(xr + i0 + 4);
    float t[8] = {p0.x + af[0], p0.y + af[1], p0.z + af[2], p0.w + af[3],
                  p1.x + af[4], p1.y + af[5], p1.z + af[6], p1.w + af[7]};
    float ss = 0.f;
#pragma unroll
    for (int j = 0; j < 8; ++j) ss += t[j] * t[j];
    ss = wave_sum(ss);
    __shared__ float sb[4];
    if ((tid & 63) == 0) sb[tid >> 6] = ss;
    __syncthreads();
    ss = sb[0] + sb[1] + sb[2] + sb[3];
    float rsq = 1.0f / sqrtf(ss * (1.0f / (float)D) + EPSV);
    float4 w0 = *(const float4*)(wpost + i0);
    float4 w1 = *(const float4*)(wpost + i0 + 4);
    float wv[8] = {w0.x, w0.y, w0.z, w0.w, w1.x, w1.y, w1.z, w1.w};
    float o[8];
#pragma unroll
    for (int j = 0; j < 8; ++j) o[j] = t[j] * rsq * wv[j];
    float4 r0 = {o[0], o[1], o[2], o[3]};
    float4 r1 = {o[4], o[5], o[6], o[7]};
    *(float4*)(x_dst + (size_t)row * D + i0) = r0;
    *(float4*)(x_dst + (size_t)row * D + i0 + 4) = r1;
    uint4 ob;
    ob.x = (uint)f2bf(o[0]) | ((uint)f2bf(o[1]) << 16);
    ob.y = (uint)f2bf(o[2]) | ((uint)f2bf(o[3]) << 16);
    ob.z = (uint)f2bf(o[4]) | ((uint)f2bf(o[5]) << 16);
    ob.w = (uint)f2bf(o[6]) | ((uint)f2bf(o[7]) << 16);
    *(uint4*)(xb + (size_t)row * D + i0) = ob;
}

// ---------------- grouped 16x64 GEMM body (device) ----------------
template <int TRANS>
static __device__ __forceinline__ void grouped16_body(
    int blk, const ushort* __restrict__ Abase, const ushort* __restrict__ Bmat,
    ushort* __restrict__ Cout) {
    int g = blk >> 3;               // 0..127 = b*32+h
    int nt = blk & 7;
    int h = g & 31;
    int hoff = h * 64;
    int tid = threadIdx.x, lane = tid & 63, wv = tid >> 6;
    int j0 = nt * 256 + wv * 64;
    int rr = lane & 15, ko = lane >> 4;
    const ushort* A = Abase + (size_t)g * 16 * 64;
    bf16x8 af0 = *(const bf16x8*)(A + rr * 64 + ko * 8);
    bf16x8 af1 = *(const bf16x8*)(A + rr * 64 + 32 + ko * 8);
    f32x4 acc[4];
    f32x4 zero = {0.f, 0.f, 0.f, 0.f};
#pragma unroll
    for (int nf = 0; nf < 4; ++nf) acc[nf] = zero;
#pragma unroll
    for (int nf = 0; nf < 4; ++nf) {
        int j = j0 + nf * 16 + rr;
        bf16x8 b0 = *(const bf16x8*)(Bmat + (size_t)j * 2048 + hoff + ko * 8);
        bf16x8 b1 = *(const bf16x8*)(Bmat + (size_t)j * 2048 + hoff + 32 + ko * 8);
        acc[nf] = __builtin_amdgcn_mfma_f32_16x16x32_bf16(af0, b0, acc[nf], 0, 0, 0);
        acc[nf] = __builtin_amdgcn_mfma_f32_16x16x32_bf16(af1, b1, acc[nf], 0, 0, 0);
    }
#pragma unroll
    for (int nf = 0; nf < 4; ++nf)
#pragma unroll
        for (int r = 0; r < 4; ++r) {
            int s = ko * 4 + r;
            int j = j0 + nf * 16 + rr;
            ushort v = f2bf(acc[nf][r]);
            if (TRANS) Cout[(size_t)j * 2048 + g * 16 + s] = v;
            else       Cout[(size_t)(g * 16 + s) * 2048 + j] = v;
        }
}

// ---------------- fused: grouped16<0> (ktil) | grouped16<1> (wtilT) | cbias -------
__global__ __launch_bounds__(256) void fused_prep_kernel(
    const ushort* __restrict__ kb16, const ushort* __restrict__ vb16,
    const float* __restrict__ bq, const ushort* __restrict__ wqt,
    const ushort* __restrict__ wob, ushort* __restrict__ ktil,
    ushort* __restrict__ wtilT, float* __restrict__ cbias) {
    int blk = blockIdx.x;
    if (blk < 1024) {
        grouped16_body<0>(blk, kb16, wqt, ktil);
    } else if (blk < 2048) {
        grouped16_body<1>(blk - 1024, vb16, wob, wtilT);
    } else {
        int i = (blk - 2048) * 256 + threadIdx.x;   // 0..2047
        int hs = i & 511;
        int h = hs >> 4;
        const ushort* kr = kb16 + (size_t)i * 64;
        const float* bb = bq + h * 64;
        float acc = 0.f;
#pragma unroll
        for (int d = 0; d < 64; ++d)
            acc += __uint_as_float(((uint)kr[d]) << 16) * bb[d];
        cbias[i] = acc;
    }
}

// ---------------- attn softmax: A_att = softmax_s((qlog0+qlog1+cbias)*0.125) ------
// qlog planes are now bf16 (halved traffic); unpacked before the plane sum.
__global__ __launch_bounds__(256) void attn_sm_kernel(
    const ushort* __restrict__ qlog, const float* __restrict__ cb,
    ushort* __restrict__ aatt) {
    int blk = blockIdx.x;               // 1024 blocks x 8 rows
    int tid = threadIdx.x;
    int l = blk * 8 + (tid >> 5);
    int b = l >> 11;
    int h = tid & 31;
    const ushort* q0 = qlog + (size_t)l * 512 + h * 16;
    const ushort* q1 = q0 + (size_t)BL * 512;
    const float* c = cb + b * 512 + h * 16;
    uint4 u0a = *(const uint4*)q0;
    uint4 u0b = *(const uint4*)(q0 + 8);
    uint4 u1a = *(const uint4*)q1;
    uint4 u1b = *(const uint4*)(q1 + 8);
    uint ua[8] = {u0a.x, u0a.y, u0a.z, u0a.w, u0b.x, u0b.y, u0b.z, u0b.w};
    uint ub[8] = {u1a.x, u1a.y, u1a.z, u1a.w, u1b.x, u1b.y, u1b.z, u1b.w};
    float p[16];
#pragma unroll
    for (int i = 0; i < 8; ++i) {
        float a0 = __uint_as_float(ua[i] << 16);
        float a1 = __uint_as_float(ua[i] & 0xffff0000u);
        float b0 = __uint_as_float(ub[i] << 16);
        float b1 = __uint_as_float(ub[i] & 0xffff0000u);
        p[2 * i]     = a0 + b0 + c[2 * i];
        p[2 * i + 1] = a1 + b1 + c[2 * i + 1];
    }
    float mx = p[0];
#pragma unroll
    for (int s = 1; s < 16; ++s) mx = fmaxf(mx, p[s]);
    float den = 0.f;
#pragma unroll
    for (int s = 0; s < 16; ++s) { p[s] = __expf((p[s] - mx) * 0.125f); den += p[s]; }
    float inv = 1.0f / den;
    uint4 o[2];
    uint* ow = (uint*)o;
#pragma unroll
    for (int i = 0; i < 8; ++i)
        ow[i] = (uint)f2bf(p[2 * i] * inv) | ((uint)f2bf(p[2 * i + 1] * inv) << 16);
    ushort* dst = aatt + (size_t)l * 512 + h * 16;
    *(uint4*)dst = o[0];
    *(uint4*)(dst + 8) = o[1];
}

// ---------------- tiny-M GEMM: one wave per 16x16 output tile, no LDS/barriers ----
template <int KVMODE>
__global__ __launch_bounds__(256) void gemm_tiny(
    const ushort* __restrict__ A, const ushort* __restrict__ Bw,
    const float* __restrict__ bias, float* __restrict__ C,
    int M, int N, int K, ushort* __restrict__ kvk, ushort* __restrict__ kvv) {
    int gw = (blockIdx.x * 256 + threadIdx.x) >> 6;
    int lane = threadIdx.x & 63;
    int ntiles = N >> 4;
    int nt = gw % ntiles, mt = gw / ntiles;
    int rr = lane & 15, ko = lane >> 4;
    const ushort* Ar = A + (size_t)(mt * 16 + rr) * K;
    const ushort* Br = Bw + (size_t)(nt * 16 + rr) * K;
    f32x4 acc = {0.f, 0.f, 0.f, 0.f};
    int NT = K / 32;
#pragma unroll 8
    for (int t = 0; t < NT; ++t) {
        bf16x8 af = *(const bf16x8*)(Ar + t * 32 + ko * 8);
        bf16x8 bf = *(const bf16x8*)(Br + t * 32 + ko * 8);
        acc = __builtin_amdgcn_mfma_f32_16x16x32_bf16(af, bf, acc, 0, 0, 0);
    }
    int col = nt * 16 + rr;
    float bsv = bias ? bias[col] : 0.f;
#pragma unroll
    for (int r = 0; r < 4; ++r) {
        int rowi = mt * 16 + ko * 4 + r;
        float v = acc[r] + bsv;
        if (KVMODE) {
            int b = rowi >> 4, s = rowi & 15;
            int c2 = (col < 2048) ? col : col - 2048;
            int h = c2 >> 6, d = c2 & 63;
            size_t dst = (((size_t)(b * NHEAD + h)) * NSLOT + s) * HDIM + d;
            if (col < 2048) kvk[dst] = f2bf(v);
            else            kvv[dst] = f2bf(v);
        } else {
            C[(size_t)rowi * N + col] = v;
        }
    }
}

// ---------------- bf16 MFMA GEMM with paired-row XOR-swizzled LDS -----------------
// LDS is [pair L][8 slots of 16B] (128B line); logical (row r, 16B-chunk k):
// L=r>>1, lc=(r&1)*4+k, slot=lc^(L&7). Staging pre-swizzles the GLOBAL source
// (LDS dest stays linear — rule #21); reads apply the same involution. Breaks the
// 8-way ds_read_b128 conflict of 64B-pitch rows (SQ_LDS_BANK_CONFLICT 3.1M -> ~0).
// Pure layout change: every lane loads the same global data -> bit-identical.
// OBF=1: write bf16 to ((ushort*)C) (zC then counts FLOAT elems = bytes/4).
template <int BM, int OBF>
__global__ __launch_bounds__(256) void gemm_bt(
    const ushort* __restrict__ A, const ushort* __restrict__ Bw,
    const float* __restrict__ bias, float* __restrict__ C,
    int M, int N, int K, size_t bOff, int bStride, int aStride,
    int zA, int zB, size_t zC) {
    constexpr int BN = 128, BK = 32;
    constexpr int MF = BM / 32;
    constexpr int APASS = (BM * BK / 8) / 256;
    __shared__ short lds[2][(BM + BN) * BK];
    int tid = threadIdx.x;
    int lane = tid & 63, w = tid >> 6;
    int wr = w >> 1, wc = w & 1;
    int tn = blockIdx.x * BN;
    int tm = blockIdx.y * BM;
    int ksl = blockIdx.z;
    A += (size_t)ksl * zA;
    Bw += (size_t)ksl * zB + (size_t)(tm >> 11) * bOff;
    C += (size_t)ksl * zC;
    f32x4 acc[MF][4];
    f32x4 zero = {0.f, 0.f, 0.f, 0.f};
#pragma unroll
    for (int m = 0; m < MF; ++m)
#pragma unroll
        for (int n = 0; n < 4; ++n) acc[m][n] = zero;
    int NT = K / BK;

    auto stage = [&](int buf, int t) {
        int kt = t * BK;
#pragma unroll
        for (int p = 0; p < APASS; ++p) {
            int cb = p * 256 + w * 64;
            int c = cb + lane;
            int L = c >> 3, slot = c & 7;
            int lc = slot ^ (L & 7);            // pre-swizzled source
            int r = 2 * L + (lc >> 2);
            int k8 = (lc & 3) * 8;
            int gr = tm + r;
            if (gr >= M) gr = M - 1;
            gl_lds16(A + (size_t)gr * aStride + kt + k8, (void*)&lds[buf][cb * 8]);
        }
#pragma unroll
        for (int p = 0; p < 2; ++p) {
            int cb = p * 256 + w * 64;
            int c = cb + lane;
            int L = c >> 3, slot = c & 7;
            int lc = slot ^ (L & 7);
            int r = 2 * L + (lc >> 2);
            int k8 = (lc & 3) * 8;
            gl_lds16(Bw + (size_t)(tn + r) * bStride + kt + k8,
                     (void*)&lds[buf][BM * BK + cb * 8]);
        }
    };
    stage(0, 0);
    for (int t = 0; t < NT; ++t) {
        __syncthreads();
        if (t + 1 < NT) stage((t + 1) & 1, t + 1);
        const short* Ab = &lds[t & 1][0];
        const short* Bb = &lds[t & 1][BM * BK];
        int kc = lane >> 4;                    // 16B chunk 0..3
        int rr = lane & 15;
        bf16x8 af[MF], bfr[4];
#pragma unroll
        for (int m = 0; m < MF; ++m) {
            int row = wr * (MF * 16) + m * 16 + rr;
            int L = row >> 1;
            int sl = (((row & 1) * 4 + kc)) ^ (L & 7);
            af[m] = *(const bf16x8*)&Ab[L * 64 + sl * 8];
        }
#pragma unroll
        for (int n = 0; n < 4; ++n) {
            int row = wc * 64 + n * 16 + rr;
            int L = row >> 1;
            int sl = (((row & 1) * 4 + kc)) ^ (L & 7);
            bfr[n] = *(const bf16x8*)&Bb[L * 64 + sl * 8];
        }
#pragma unroll
        for (int m = 0; m < MF; ++m)
#pragma unroll
            for (int n = 0; n < 4; ++n)
                acc[m][n] = __builtin_amdgcn_mfma_f32_16x16x32_bf16(af[m], bfr[n],
                                                                    acc[m][n], 0, 0, 0);
    }
#pragma unroll
    for (int m = 0; m < MF; ++m) {
#pragma unroll
        for (int n = 0; n < 4; ++n) {
            int col = tn + wc * 64 + n * 16 + (lane & 15);
            float bsv = bias ? bias[col] : 0.f;
#pragma unroll
            for (int r = 0; r < 4; ++r) {
                int rowi = tm + wr * (MF * 16) + m * 16 + (lane >> 4) * 4 + r;
                if (rowi >= M) continue;
                float v = acc[m][n][r] + bsv;
                if (OBF) ((ushort*)C)[(size_t)rowi * N + col] = f2bf(v);
                else     C[(size_t)rowi * N + col] = v;
            }
        }
    }
}

extern "C" void kernel_launch(void* const* d_in, const int* in_sizes, int n_in,
                              void* d_out, int out_size, void* d_ws, size_t ws_size,
                              hipStream_t stream) {
    const float* x_in       = (const float*)d_in[0];
    const float* workspace  = (const float*)d_in[1];
    const float* compete_w  = (const float*)d_in[2];
    const float* compete_b  = (const float*)d_in[3];
    const float* write_w    = (const float*)d_in[4];
    const float* write_b    = (const float*)d_in[5];
    const float* in_proj_w  = (const float*)d_in[6];
    const float* in_proj_b  = (const float*)d_in[7];
    const float* out_proj_w = (const float*)d_in[8];
    const float* out_proj_b = (const float*)d_in[9];
    const float* norm_pre_w  = (const float*)d_in[12];
    const float* norm_post_w = (const float*)d_in[13];
    float* xout = (float*)d_out;

    char* base = (char*)d_ws;
    size_t off = 0;
    auto alloc = [&](size_t bytes) {
        void* p = base + off;
        off += (bytes + 255) & ~(size_t)255;
        return p;
    };
    ushort* xb      = (ushort*)alloc((size_t)BL * D * 2);
    ushort* xbb     = (ushort*)alloc((size_t)BL * D * 2);     // x_b (bf16)
    float*  logits  = (float*) alloc((size_t)BATCH * NSLOT * LSEQ * 4);
    ushort* xbar    = (ushort*)alloc((size_t)BATCH * NSLOT * D * 2);
    float*  written = (float*) alloc((size_t)BATCH * NSLOT * D * 4);
    float*  wsbuf   = (float*) alloc((size_t)BATCH * NSLOT * D * 4);
    ushort* wsb     = (ushort*)alloc((size_t)BATCH * NSLOT * D * 2);
    ushort* ipb     = (ushort*)alloc((size_t)3 * D * D * 2);
    ushort* wob     = (ushort*)alloc((size_t)D * D * 2);
    ushort* wwb     = (ushort*)alloc((size_t)D * D * 2);
    ushort* wqt     = (ushort*)alloc((size_t)D * D * 2);      // Wq^T bf16
    ushort* kb16    = (ushort*)alloc((size_t)BATCH * NHEAD * NSLOT * HDIM * 2);
    ushort* vb16    = (ushort*)alloc((size_t)BATCH * NHEAD * NSLOT * HDIM * 2);
    ushort* ktil    = (ushort*)alloc((size_t)BATCH * 512 * D * 2);   // K~ rows b*512+hs
    ushort* wtilT   = (ushort*)alloc((size_t)D * BATCH * 512 * 2);   // W~^T rows j
    ushort* qlogb   = (ushort*)alloc((size_t)2 * BL * 512 * 2);      // 2 bf16 planes
    ushort* aatt    = (ushort*)alloc((size_t)BL * 512 * 2);
    float*  cbias   = (float*) alloc((size_t)BATCH * 512 * 4);
    (void)ws_size; (void)in_sizes; (void)n_in; (void)out_size;

    conv_bf16_kernel<<<2048, 256, 0, stream>>>((const float4*)in_proj_w, ipb, 3 * D * D / 4);
    conv_bf16_kernel<<<2048, 256, 0, stream>>>((const float4*)out_proj_w, wob, D * D / 4);
    conv_bf16_kernel<<<2048, 256, 0, stream>>>((const float4*)write_w, wwb, D * D / 4);
    conv_bf16_kernel<<<2048, 256, 0, stream>>>((const float4*)x_in, xb, BL * D / 4);
    transpose_bf16_kernel<<<1024, 256, 0, stream>>>(ipb, wqt);   // Wq^T (q rows 0..D)

    for (int it = 0; it < 2; ++it) {
        const float* xs = it ? (const float*)xout : x_in;
        logits_kernel<<<BL / 4, 256, 0, stream>>>(xs, compete_w, compete_b, norm_pre_w,
                                                  logits);
        topk_xbar_kernel<<<BATCH * NSLOT, 256, 0, stream>>>(logits, xs, xbar);
        // written = xbar @ wwb^T + write_b   (64x2048, K=2048) — 512 waves
        gemm_tiny<0><<<128, 256, 0, stream>>>(xbar, wwb, write_b, written,
                                              BATCH * NSLOT, D, D,
                                              (ushort*)nullptr, (ushort*)nullptr);
        ws_update_kernel<<<BATCH * NSLOT, 256, 0, stream>>>(written, wsbuf, workspace,
                                                            it == 0 ? 1 : 0, norm_post_w,
                                                            wsbuf, wsb);
        // kv = wsb @ Wkv^T + bkv  (64x4096, K=2048) — 1024 waves, scatter to kb/vb
        gemm_tiny<1><<<256, 256, 0, stream>>>(wsb, ipb + (size_t)D * D, in_proj_b + D,
                                              (float*)nullptr, BATCH * NSLOT, 2 * D, D,
                                              kb16, vb16);
        // ktil | wtilT | cbias in one dispatch (independent, all need kb16/vb16)
        fused_prep_kernel<<<2056, 256, 0, stream>>>(kb16, vb16, in_proj_b, wqt, wob,
                                                    ktil, wtilT, cbias);
        // qlog[z][l, hs] (bf16) = xb[l, zK:] . K~[b,hs, zK:]  (split-K=2)
        // zC is in FLOAT elems: plane = BL*512 ushorts = BL*512/2 floats.
        gemm_bt<64, 1><<<dim3(512 / 128, BL / 64, 2), 256, 0, stream>>>(
            xb, ktil, (const float*)nullptr, (float*)qlogb, BL, 512, D / 2,
            (size_t)512 * D, D, D, D / 2, D / 2, (size_t)(BL * 512 / 2));
        attn_sm_kernel<<<BL / 8, 256, 0, stream>>>(qlogb, cbias, aatt);
        // x_b[l, j] (bf16) = sum_hs aatt[l,hs] * W~T[j, b*512+hs] + out_proj_b[j]
        gemm_bt<64, 1><<<dim3(D / 128, BL / 64), 256, 0, stream>>>(
            aatt, wtilT, out_proj_b, (float*)xbb, BL, D, 512,
            (size_t)512, D, 512, 0, 0, 0);
        resid_rms_kernel<<<BL, 256, 0, stream>>>(xs, xbb, norm_post_w, xout, xb);
    }
}

// Round 21
// 481.282 us; speedup vs baseline: 1.1471x; 1.0106x over previous
//
#include <hip/hip_runtime.h>
#include <stdint.h>

#define D 2048
#define LSEQ 2048
#define BATCH 4
#define BL (BATCH * LSEQ)   // 8192 rows
#define NSLOT 16
#define NHEAD 32
#define HDIM 64
#define EPSV 1e-6f

typedef __attribute__((ext_vector_type(8))) short bf16x8;
typedef __attribute__((ext_vector_type(4))) float f32x4;

static __device__ __forceinline__ ushort f2bf(float f) {
    uint32_t u = __float_as_uint(f);
    u += 0x7fffu + ((u >> 16) & 1u);   // RNE
    return (ushort)(u >> 16);
}

// DPP-based xor-add level (bit-exact vs __shfl_xor, runs on VALU not LDS pipe).
template <int CTRL>
static __device__ __forceinline__ float dpp_xadd(float v) {
    int t = __builtin_amdgcn_mov_dpp(__float_as_int(v), CTRL, 0xf, 0xf, true);
    return v + __int_as_float(t);
}

// Bit-exact butterfly sum, same order as original (off = 32,16,8,4,2,1),
// 3 of 6 levels on VALU DPP (proven R19: logits 50->~35us).
static __device__ __forceinline__ float wave_sum(float v) {
    v += __shfl_xor(v, 32, 64);
    v += __shfl_xor(v, 16, 64);
    v = dpp_xadd<0x128>(v);   // xor 8 (row_ror:8)
    v += __shfl_xor(v, 4, 64);
    v = dpp_xadd<0x4E>(v);    // xor 2 (quad_perm)
    v = dpp_xadd<0xB1>(v);    // xor 1 (quad_perm)
    return v;
}

static __device__ __forceinline__ void gl_lds16(const void* g, void* l) {
    __builtin_amdgcn_global_load_lds(
        (__attribute__((address_space(1))) uint32_t*)(uintptr_t)g,
        (__attribute__((address_space(3))) uint32_t*)(uint32_t)(uintptr_t)l,
        16, 0, 0);
}

// ---------------- weight convert f32 -> bf16 ----------------
__global__ __launch_bounds__(256) void conv_bf16_kernel(const float4* __restrict__ src,
                                                        ushort* __restrict__ dst, int n4) {
    int i = blockIdx.x * 256 + threadIdx.x;
    int stride = gridDim.x * 256;
    for (; i < n4; i += stride) {
        float4 v = src[i];
        uint2 o;
        o.x = (uint)f2bf(v.x) | ((uint)f2bf(v.y) << 16);
        o.y = (uint)f2bf(v.z) | ((uint)f2bf(v.w) << 16);
        *(uint2*)(dst + (size_t)i * 4) = o;
    }
}

// ---------------- 2048x2048 bf16 transpose (once, for Wq^T) ----------------
__global__ __launch_bounds__(256) void transpose_bf16_kernel(const ushort* __restrict__ src,
                                                             ushort* __restrict__ dst) {
    __shared__ ushort t[64][72];
    int bx = blockIdx.x & 31, by = blockIdx.x >> 5;
    int r0 = by * 64, c0 = bx * 64;
    int tid = threadIdx.x;
    int lr = tid >> 3;
    int lc = (tid & 7) * 8;
#pragma unroll
    for (int p = 0; p < 2; ++p) {
        int rr = p * 32 + lr;
        bf16x8 v = *(const bf16x8*)(src + (size_t)(r0 + rr) * 2048 + c0 + lc);
#pragma unroll
        for (int j = 0; j < 8; ++j) t[lc + j][rr] = (ushort)v[j];
    }
    __syncthreads();
#pragma unroll
    for (int p = 0; p < 2; ++p) {
        int rr = p * 32 + lr;
        *(bf16x8*)(dst + (size_t)(c0 + rr) * 2048 + r0 + lc) = *(const bf16x8*)&t[rr][lc];
    }
}

// ---------------- logits v8: DPP wave_sum, bit-exact (DO NOT touch FP ops) -------
__global__ __launch_bounds__(256) void logits_kernel(
    const float* __restrict__ x, const float* __restrict__ cw,
    const float* __restrict__ cb, const float* __restrict__ wpre,
    float* __restrict__ logits_t) {
    int blk = blockIdx.x;              // 2048 blocks, 4 rows each
    int b = blk >> 9;                  // 512 blocks per batch
    int l0 = (blk & 511) << 2;
    int tid = threadIdx.x;
    int i0 = tid * 8;
    float4 w0 = *(const float4*)(wpre + i0);
    float4 w1 = *(const float4*)(wpre + i0 + 4);
    float wv[8] = {w0.x, w0.y, w0.z, w0.w, w1.x, w1.y, w1.z, w1.w};
    float xw[4][8];
    float ss[4];
#pragma unroll
    for (int r = 0; r < 4; ++r) {
        const float* xr = x + ((size_t)(b * LSEQ + l0 + r)) * D;
        float4 a0 = *(const float4*)(xr + i0);
        float4 a1 = *(const float4*)(xr + i0 + 4);
        float xv[8] = {a0.x, a0.y, a0.z, a0.w, a1.x, a1.y, a1.z, a1.w};
        float s0 = 0.f;
#pragma unroll
        for (int j = 0; j < 8; ++j) { s0 += xv[j] * xv[j]; xw[r][j] = xv[j] * wv[j]; }
        ss[r] = s0;
    }
#pragma unroll
    for (int r = 0; r < 4; ++r) ss[r] = wave_sum(ss[r]);
    __shared__ float red[4][NSLOT][4];
    __shared__ float redss[4][4];
    int lane = tid & 63, w = tid >> 6;
    if (lane == 0) {
#pragma unroll
        for (int r = 0; r < 4; ++r) redss[w][r] = ss[r];
    }
#pragma unroll 2
    for (int s = 0; s < NSLOT; ++s) {
        const float* cwr = cw + (size_t)s * D + i0;
        float4 c0 = *(const float4*)(cwr);
        float4 c1 = *(const float4*)(cwr + 4);
        float acc[4];
#pragma unroll
        for (int r = 0; r < 4; ++r)
            acc[r] = xw[r][0] * c0.x + xw[r][1] * c0.y + xw[r][2] * c0.z + xw[r][3] * c0.w +
                     xw[r][4] * c1.x + xw[r][5] * c1.y + xw[r][6] * c1.z + xw[r][7] * c1.w;
#pragma unroll
        for (int r = 0; r < 4; ++r) acc[r] = wave_sum(acc[r]);
        if (lane == 0) {
#pragma unroll
            for (int r = 0; r < 4; ++r) red[w][s][r] = acc[r];
        }
    }
    __syncthreads();
    if (tid < 64) {
        int s = tid >> 2, r = tid & 3;
        float tot = red[0][s][r] + red[1][s][r] + red[2][s][r] + red[3][s][r];
        float s2 = redss[0][r] + redss[1][r] + redss[2][r] + redss[3][r];
        float rsq = 1.0f / sqrtf(s2 * (1.0f / (float)D) + EPSV);
        logits_t[((size_t)(b * NSLOT + s)) * LSEQ + l0 + r] = tot * rsq + cb[s];
    }
}

// ---------------- top-4 + softmax + weighted row gather (xbar, bf16) ----------------
__global__ __launch_bounds__(256) void topk_xbar_kernel(
    const float* __restrict__ logits_t, const float* __restrict__ x,
    ushort* __restrict__ xbar_b) {
    int bs = blockIdx.x;
    int b = bs >> 4;
    const float* lr = logits_t + (size_t)bs * LSEQ;
    int tid = threadIdx.x, lane = tid & 63, w = tid >> 6;
    __shared__ float rv[4];
    __shared__ int ri[4];
    __shared__ float selv[4];
    __shared__ int seli[4];
    int i0 = tid * 8;
    float myv[8];
#pragma unroll
    for (int j = 0; j < 8; ++j) myv[j] = lr[i0 + j];
    int chosen[4];
    for (int p = 0; p < 4; ++p) {
        float bv = -3.4e38f;
        int bi = 0x7fffffff;
#pragma unroll
        for (int j = 0; j < 8; ++j) {
            int i = i0 + j;
            bool skip = false;
            for (int q = 0; q < p; ++q) skip = skip || (i == chosen[q]);
            float v = myv[j];
            if (!skip && (v > bv || (v == bv && i < bi))) { bv = v; bi = i; }
        }
#pragma unroll
        for (int off = 1; off < 64; off <<= 1) {
            float ov = __shfl_xor(bv, off, 64);
            int oi = __shfl_xor(bi, off, 64);
            if (ov > bv || (ov == bv && oi < bi)) { bv = ov; bi = oi; }
        }
        if (lane == 0) { rv[w] = bv; ri[w] = bi; }
        __syncthreads();
        if (tid == 0) {
            float fv = rv[0];
            int fi = ri[0];
            for (int q = 1; q < 4; ++q)
                if (rv[q] > fv || (rv[q] == fv && ri[q] < fi)) { fv = rv[q]; fi = ri[q]; }
            selv[p] = fv;
            seli[p] = fi;
        }
        __syncthreads();
        chosen[p] = seli[p];
    }
    float vals[4];
#pragma unroll
    for (int p = 0; p < 4; ++p) vals[p] = selv[p];
    float mx = vals[0];   // first pick is the max
    float e[4], den = 0.f;
#pragma unroll
    for (int p = 0; p < 4; ++p) { e[p] = expf(vals[p] - mx); den += e[p]; }
    float inv = 1.0f / den;
    const float* xr0 = x + ((size_t)b * LSEQ + chosen[0]) * D;
    const float* xr1 = x + ((size_t)b * LSEQ + chosen[1]) * D;
    const float* xr2 = x + ((size_t)b * LSEQ + chosen[2]) * D;
    const float* xr3 = x + ((size_t)b * LSEQ + chosen[3]) * D;
    float s[8];
#pragma unroll
    for (int j = 0; j < 8; ++j) {
        int i = i0 + j;
        s[j] = (e[0] * xr0[i] + e[1] * xr1[i] + e[2] * xr2[i] + e[3] * xr3[i]) * inv;
    }
    uint4 o;
    o.x = (uint)f2bf(s[0]) | ((uint)f2bf(s[1]) << 16);
    o.y = (uint)f2bf(s[2]) | ((uint)f2bf(s[3]) << 16);
    o.z = (uint)f2bf(s[4]) | ((uint)f2bf(s[5]) << 16);
    o.w = (uint)f2bf(s[6]) | ((uint)f2bf(s[7]) << 16);
    *(uint4*)(xbar_b + (size_t)bs * D + i0) = o;
}

// ---------------- ws = rms(ws_prev + written) (+bf16 copy) ----------------
__global__ __launch_bounds__(256) void ws_update_kernel(
    const float* __restrict__ written, const float* __restrict__ ws_prev,
    const float* __restrict__ workspace0, int first,
    const float* __restrict__ wpost, float* __restrict__ ws_out,
    ushort* __restrict__ ws_b) {
    int bs = blockIdx.x;
    int s = bs & (NSLOT - 1);
    int tid = threadIdx.x;
    int i0 = tid * 8;
    const float* prev = first ? (workspace0 + (size_t)s * D) : (ws_prev + (size_t)bs * D);
    const float* wr = written + (size_t)bs * D;
    float4 p0 = *(const float4*)(prev + i0);
    float4 p1 = *(const float4*)(prev + i0 + 4);
    float4 q0 = *(const float4*)(wr + i0);
    float4 q1 = *(const float4*)(wr + i0 + 4);
    float t[8] = {p0.x + q0.x, p0.y + q0.y, p0.z + q0.z, p0.w + q0.w,
                  p1.x + q1.x, p1.y + q1.y, p1.z + q1.z, p1.w + q1.w};
    float ss = 0.f;
#pragma unroll
    for (int j = 0; j < 8; ++j) ss += t[j] * t[j];
    ss = wave_sum(ss);
    __shared__ float sb[4];
    if ((tid & 63) == 0) sb[tid >> 6] = ss;
    __syncthreads();
    ss = sb[0] + sb[1] + sb[2] + sb[3];
    float rsq = 1.0f / sqrtf(ss * (1.0f / (float)D) + EPSV);
    float4 w0 = *(const float4*)(wpost + i0);
    float4 w1 = *(const float4*)(wpost + i0 + 4);
    float wv[8] = {w0.x, w0.y, w0.z, w0.w, w1.x, w1.y, w1.z, w1.w};
    float o[8];
#pragma unroll
    for (int j = 0; j < 8; ++j) o[j] = t[j] * rsq * wv[j];
    float4 r0 = {o[0], o[1], o[2], o[3]};
    float4 r1 = {o[4], o[5], o[6], o[7]};
    *(float4*)(ws_out + (size_t)bs * D + i0) = r0;
    *(float4*)(ws_out + (size_t)bs * D + i0 + 4) = r1;
    uint4 ob;
    ob.x = (uint)f2bf(o[0]) | ((uint)f2bf(o[1]) << 16);
    ob.y = (uint)f2bf(o[2]) | ((uint)f2bf(o[3]) << 16);
    ob.z = (uint)f2bf(o[4]) | ((uint)f2bf(o[5]) << 16);
    ob.w = (uint)f2bf(o[6]) | ((uint)f2bf(o[7]) << 16);
    *(uint4*)(ws_b + (size_t)bs * D + i0) = ob;
}

// ---------------- x = rms(x + attn_out[bf16]) (+bf16 copy) ----------------
__global__ __launch_bounds__(256) void resid_rms_kernel(
    const float* __restrict__ x_src, const ushort* __restrict__ ao,
    const float* __restrict__ wpost, float* __restrict__ x_dst,
    ushort* __restrict__ xb) {
    int row = blockIdx.x;
    int tid = threadIdx.x;
    int i0 = tid * 8;
    const float* xr = x_src + (size_t)row * D;
    uint4 av = *(const uint4*)(ao + (size_t)row * D + i0);
    float af[8];
    af[0] = __uint_as_float(av.x << 16);
    af[1] = __uint_as_float(av.x & 0xffff0000u);
    af[2] = __uint_as_float(av.y << 16);
    af[3] = __uint_as_float(av.y & 0xffff0000u);
    af[4] = __uint_as_float(av.z << 16);
    af[5] = __uint_as_float(av.z & 0xffff0000u);
    af[6] = __uint_as_float(av.w << 16);
    af[7] = __uint_as_float(av.w & 0xffff0000u);
    float4 p0 = *(const float4*)(xr + i0);
    float4 p1 = *(const float4*)(xr + i0 + 4);
    float t[8] = {p0.x + af[0], p0.y + af[1], p0.z + af[2], p0.w + af[3],
                  p1.x + af[4], p1.y + af[5], p1.z + af[6], p1.w + af[7]};
    float ss = 0.f;
#pragma unroll
    for (int j = 0; j < 8; ++j) ss += t[j] * t[j];
    ss = wave_sum(ss);
    __shared__ float sb[4];
    if ((tid & 63) == 0) sb[tid >> 6] = ss;
    __syncthreads();
    ss = sb[0] + sb[1] + sb[2] + sb[3];
    float rsq = 1.0f / sqrtf(ss * (1.0f / (float)D) + EPSV);
    float4 w0 = *(const float4*)(wpost + i0);
    float4 w1 = *(const float4*)(wpost + i0 + 4);
    float wv[8] = {w0.x, w0.y, w0.z, w0.w, w1.x, w1.y, w1.z, w1.w};
    float o[8];
#pragma unroll
    for (int j = 0; j < 8; ++j) o[j] = t[j] * rsq * wv[j];
    float4 r0 = {o[0], o[1], o[2], o[3]};
    float4 r1 = {o[4], o[5], o[6], o[7]};
    *(float4*)(x_dst + (size_t)row * D + i0) = r0;
    *(float4*)(x_dst + (size_t)row * D + i0 + 4) = r1;
    uint4 ob;
    ob.x = (uint)f2bf(o[0]) | ((uint)f2bf(o[1]) << 16);
    ob.y = (uint)f2bf(o[2]) | ((uint)f2bf(o[3]) << 16);
    ob.z = (uint)f2bf(o[4]) | ((uint)f2bf(o[5]) << 16);
    ob.w = (uint)f2bf(o[6]) | ((uint)f2bf(o[7]) << 16);
    *(uint4*)(xb + (size_t)row * D + i0) = ob;
}

// ---------------- grouped 16x64 GEMM body (device) ----------------
template <int TRANS>
static __device__ __forceinline__ void grouped16_body(
    int blk, const ushort* __restrict__ Abase, const ushort* __restrict__ Bmat,
    ushort* __restrict__ Cout) {
    int g = blk >> 3;               // 0..127 = b*32+h
    int nt = blk & 7;
    int h = g & 31;
    int hoff = h * 64;
    int tid = threadIdx.x, lane = tid & 63, wv = tid >> 6;
    int j0 = nt * 256 + wv * 64;
    int rr = lane & 15, ko = lane >> 4;
    const ushort* A = Abase + (size_t)g * 16 * 64;
    bf16x8 af0 = *(const bf16x8*)(A + rr * 64 + ko * 8);
    bf16x8 af1 = *(const bf16x8*)(A + rr * 64 + 32 + ko * 8);
    f32x4 acc[4];
    f32x4 zero = {0.f, 0.f, 0.f, 0.f};
#pragma unroll
    for (int nf = 0; nf < 4; ++nf) acc[nf] = zero;
#pragma unroll
    for (int nf = 0; nf < 4; ++nf) {
        int j = j0 + nf * 16 + rr;
        bf16x8 b0 = *(const bf16x8*)(Bmat + (size_t)j * 2048 + hoff + ko * 8);
        bf16x8 b1 = *(const bf16x8*)(Bmat + (size_t)j * 2048 + hoff + 32 + ko * 8);
        acc[nf] = __builtin_amdgcn_mfma_f32_16x16x32_bf16(af0, b0, acc[nf], 0, 0, 0);
        acc[nf] = __builtin_amdgcn_mfma_f32_16x16x32_bf16(af1, b1, acc[nf], 0, 0, 0);
    }
#pragma unroll
    for (int nf = 0; nf < 4; ++nf)
#pragma unroll
        for (int r = 0; r < 4; ++r) {
            int s = ko * 4 + r;
            int j = j0 + nf * 16 + rr;
            ushort v = f2bf(acc[nf][r]);
            if (TRANS) Cout[(size_t)j * 2048 + g * 16 + s] = v;
            else       Cout[(size_t)(g * 16 + s) * 2048 + j] = v;
        }
}

// ---------------- fused: grouped16<0> (ktil) | grouped16<1> (wtilT) | cbias -------
__global__ __launch_bounds__(256) void fused_prep_kernel(
    const ushort* __restrict__ kb16, const ushort* __restrict__ vb16,
    const float* __restrict__ bq, const ushort* __restrict__ wqt,
    const ushort* __restrict__ wob, ushort* __restrict__ ktil,
    ushort* __restrict__ wtilT, float* __restrict__ cbias) {
    int blk = blockIdx.x;
    if (blk < 1024) {
        grouped16_body<0>(blk, kb16, wqt, ktil);
    } else if (blk < 2048) {
        grouped16_body<1>(blk - 1024, vb16, wob, wtilT);
    } else {
        int i = (blk - 2048) * 256 + threadIdx.x;   // 0..2047
        int hs = i & 511;
        int h = hs >> 4;
        const ushort* kr = kb16 + (size_t)i * 64;
        const float* bb = bq + h * 64;
        float acc = 0.f;
#pragma unroll
        for (int d = 0; d < 64; ++d)
            acc += __uint_as_float(((uint)kr[d]) << 16) * bb[d];
        cbias[i] = acc;
    }
}

// ---------------- attn softmax: A_att = softmax_s((qlog0+qlog1+cbias)*0.125) ------
__global__ __launch_bounds__(256) void attn_sm_kernel(
    const ushort* __restrict__ qlog, const float* __restrict__ cb,
    ushort* __restrict__ aatt) {
    int blk = blockIdx.x;               // 1024 blocks x 8 rows
    int tid = threadIdx.x;
    int l = blk * 8 + (tid >> 5);
    int b = l >> 11;
    int h = tid & 31;
    const ushort* q0 = qlog + (size_t)l * 512 + h * 16;
    const ushort* q1 = q0 + (size_t)BL * 512;
    const float* c = cb + b * 512 + h * 16;
    uint4 u0a = *(const uint4*)q0;
    uint4 u0b = *(const uint4*)(q0 + 8);
    uint4 u1a = *(const uint4*)q1;
    uint4 u1b = *(const uint4*)(q1 + 8);
    uint ua[8] = {u0a.x, u0a.y, u0a.z, u0a.w, u0b.x, u0b.y, u0b.z, u0b.w};
    uint ub[8] = {u1a.x, u1a.y, u1a.z, u1a.w, u1b.x, u1b.y, u1b.z, u1b.w};
    float p[16];
#pragma unroll
    for (int i = 0; i < 8; ++i) {
        float a0 = __uint_as_float(ua[i] << 16);
        float a1 = __uint_as_float(ua[i] & 0xffff0000u);
        float b0 = __uint_as_float(ub[i] << 16);
        float b1 = __uint_as_float(ub[i] & 0xffff0000u);
        p[2 * i]     = a0 + b0 + c[2 * i];
        p[2 * i + 1] = a1 + b1 + c[2 * i + 1];
    }
    float mx = p[0];
#pragma unroll
    for (int s = 1; s < 16; ++s) mx = fmaxf(mx, p[s]);
    float den = 0.f;
#pragma unroll
    for (int s = 0; s < 16; ++s) { p[s] = __expf((p[s] - mx) * 0.125f); den += p[s]; }
    float inv = 1.0f / den;
    uint4 o[2];
    uint* ow = (uint*)o;
#pragma unroll
    for (int i = 0; i < 8; ++i)
        ow[i] = (uint)f2bf(p[2 * i] * inv) | ((uint)f2bf(p[2 * i + 1] * inv) << 16);
    ushort* dst = aatt + (size_t)l * 512 + h * 16;
    *(uint4*)dst = o[0];
    *(uint4*)(dst + 8) = o[1];
}

// ---------------- tiny-M GEMM: one wave per 16x16 output tile, no LDS/barriers ----
template <int KVMODE>
__global__ __launch_bounds__(256) void gemm_tiny(
    const ushort* __restrict__ A, const ushort* __restrict__ Bw,
    const float* __restrict__ bias, float* __restrict__ C,
    int M, int N, int K, ushort* __restrict__ kvk, ushort* __restrict__ kvv) {
    int gw = (blockIdx.x * 256 + threadIdx.x) >> 6;
    int lane = threadIdx.x & 63;
    int ntiles = N >> 4;
    int nt = gw % ntiles, mt = gw / ntiles;
    int rr = lane & 15, ko = lane >> 4;
    const ushort* Ar = A + (size_t)(mt * 16 + rr) * K;
    const ushort* Br = Bw + (size_t)(nt * 16 + rr) * K;
    f32x4 acc = {0.f, 0.f, 0.f, 0.f};
    int NT = K / 32;
#pragma unroll 8
    for (int t = 0; t < NT; ++t) {
        bf16x8 af = *(const bf16x8*)(Ar + t * 32 + ko * 8);
        bf16x8 bf = *(const bf16x8*)(Br + t * 32 + ko * 8);
        acc = __builtin_amdgcn_mfma_f32_16x16x32_bf16(af, bf, acc, 0, 0, 0);
    }
    int col = nt * 16 + rr;
    float bsv = bias ? bias[col] : 0.f;
#pragma unroll
    for (int r = 0; r < 4; ++r) {
        int rowi = mt * 16 + ko * 4 + r;
        float v = acc[r] + bsv;
        if (KVMODE) {
            int b = rowi >> 4, s = rowi & 15;
            int c2 = (col < 2048) ? col : col - 2048;
            int h = c2 >> 6, d = c2 & 63;
            size_t dst = (((size_t)(b * NHEAD + h)) * NSLOT + s) * HDIM + d;
            if (col < 2048) kvk[dst] = f2bf(v);
            else            kvv[dst] = f2bf(v);
        } else {
            C[(size_t)rowi * N + col] = v;
        }
    }
}

// ---------------- bf16 MFMA GEMM, XOR-swizzled LDS, XCD-aware block remap ---------
// 1-D grid; (bx,by,z) derived so ALL n-tile blocks of one (row-tile,z) land on
// the SAME XCD (blockIdx%8 -> XCD round-robin heuristic): the A panel is then
// fetched once per XCD instead of ntx times across non-coherent L2s.
// Mapping is bijective for gridDim.x % 8 == 0 (both call sites: 1024, 2048).
// Pure block-id permutation -> bit-identical outputs.
template <int BM, int OBF>
__global__ __launch_bounds__(256) void gemm_bt(
    const ushort* __restrict__ A, const ushort* __restrict__ Bw,
    const float* __restrict__ bias, float* __restrict__ C,
    int M, int N, int K, size_t bOff, int bStride, int aStride,
    int zA, int zB, size_t zC, int ntz) {
    constexpr int BN = 128, BK = 32;
    constexpr int MF = BM / 32;
    constexpr int APASS = (BM * BK / 8) / 256;
    __shared__ short lds[2][(BM + BN) * BK];
    int tid = threadIdx.x;
    int lane = tid & 63, w = tid >> 6;
    int wr = w >> 1, wc = w & 1;
    // ---- XCD-aware remap ----
    int ntx = N / BN;
    int total = gridDim.x;
    int per = total >> 3;                 // blocks per XCD
    int xcd = blockIdx.x & 7;
    int j = blockIdx.x >> 3;
    int pairs_per = per / ntx;            // (by,z) pairs per XCD
    int pair = xcd * pairs_per + j / ntx;
    int bx = j % ntx;
    int by = pair / ntz;
    int ksl = pair % ntz;
    int tn = bx * BN;
    int tm = by * BM;
    A += (size_t)ksl * zA;
    Bw += (size_t)ksl * zB + (size_t)(tm >> 11) * bOff;
    C += (size_t)ksl * zC;
    f32x4 acc[MF][4];
    f32x4 zero = {0.f, 0.f, 0.f, 0.f};
#pragma unroll
    for (int m = 0; m < MF; ++m)
#pragma unroll
        for (int n = 0; n < 4; ++n) acc[m][n] = zero;
    int NT = K / BK;

    auto stage = [&](int buf, int t) {
        int kt = t * BK;
#pragma unroll
        for (int p = 0; p < APASS; ++p) {
            int cb = p * 256 + w * 64;
            int c = cb + lane;
            int L = c >> 3, slot = c & 7;
            int lc = slot ^ (L & 7);            // pre-swizzled source
            int r = 2 * L + (lc >> 2);
            int k8 = (lc & 3) * 8;
            int gr = tm + r;
            if (gr >= M) gr = M - 1;
            gl_lds16(A + (size_t)gr * aStride + kt + k8, (void*)&lds[buf][cb * 8]);
        }
#pragma unroll
        for (int p = 0; p < 2; ++p) {
            int cb = p * 256 + w * 64;
            int c = cb + lane;
            int L = c >> 3, slot = c & 7;
            int lc = slot ^ (L & 7);
            int r = 2 * L + (lc >> 2);
            int k8 = (lc & 3) * 8;
            gl_lds16(Bw + (size_t)(tn + r) * bStride + kt + k8,
                     (void*)&lds[buf][BM * BK + cb * 8]);
        }
    };
    stage(0, 0);
    for (int t = 0; t < NT; ++t) {
        __syncthreads();
        if (t + 1 < NT) stage((t + 1) & 1, t + 1);
        const short* Ab = &lds[t & 1][0];
        const short* Bb = &lds[t & 1][BM * BK];
        int kc = lane >> 4;                    // 16B chunk 0..3
        int rr = lane & 15;
        bf16x8 af[MF], bfr[4];
#pragma unroll
        for (int m = 0; m < MF; ++m) {
            int row = wr * (MF * 16) + m * 16 + rr;
            int L = row >> 1;
            int sl = (((row & 1) * 4 + kc)) ^ (L & 7);
            af[m] = *(const bf16x8*)&Ab[L * 64 + sl * 8];
        }
#pragma unroll
        for (int n = 0; n < 4; ++n) {
            int row = wc * 64 + n * 16 + rr;
            int L = row >> 1;
            int sl = (((row & 1) * 4 + kc)) ^ (L & 7);
            bfr[n] = *(const bf16x8*)&Bb[L * 64 + sl * 8];
        }
#pragma unroll
        for (int m = 0; m < MF; ++m)
#pragma unroll
            for (int n = 0; n < 4; ++n)
                acc[m][n] = __builtin_amdgcn_mfma_f32_16x16x32_bf16(af[m], bfr[n],
                                                                    acc[m][n], 0, 0, 0);
    }
#pragma unroll
    for (int m = 0; m < MF; ++m) {
#pragma unroll
        for (int n = 0; n < 4; ++n) {
            int col = tn + wc * 64 + n * 16 + (lane & 15);
            float bsv = bias ? bias[col] : 0.f;
#pragma unroll
            for (int r = 0; r < 4; ++r) {
                int rowi = tm + wr * (MF * 16) + m * 16 + (lane >> 4) * 4 + r;
                if (rowi >= M) continue;
                float v = acc[m][n][r] + bsv;
                if (OBF) ((ushort*)C)[(size_t)rowi * N + col] = f2bf(v);
                else     C[(size_t)rowi * N + col] = v;
            }
        }
    }
}

extern "C" void kernel_launch(void* const* d_in, const int* in_sizes, int n_in,
                              void* d_out, int out_size, void* d_ws, size_t ws_size,
                              hipStream_t stream) {
    const float* x_in       = (const float*)d_in[0];
    const float* workspace  = (const float*)d_in[1];
    const float* compete_w  = (const float*)d_in[2];
    const float* compete_b  = (const float*)d_in[3];
    const float* write_w    = (const float*)d_in[4];
    const float* write_b    = (const float*)d_in[5];
    const float* in_proj_w  = (const float*)d_in[6];
    const float* in_proj_b  = (const float*)d_in[7];
    const float* out_proj_w = (const float*)d_in[8];
    const float* out_proj_b = (const float*)d_in[9];
    const float* norm_pre_w  = (const float*)d_in[12];
    const float* norm_post_w = (const float*)d_in[13];
    float* xout = (float*)d_out;

    char* base = (char*)d_ws;
    size_t off = 0;
    auto alloc = [&](size_t bytes) {
        void* p = base + off;
        off += (bytes + 255) & ~(size_t)255;
        return p;
    };
    ushort* xb      = (ushort*)alloc((size_t)BL * D * 2);
    ushort* xbb     = (ushort*)alloc((size_t)BL * D * 2);     // x_b (bf16)
    float*  logits  = (float*) alloc((size_t)BATCH * NSLOT * LSEQ * 4);
    ushort* xbar    = (ushort*)alloc((size_t)BATCH * NSLOT * D * 2);
    float*  written = (float*) alloc((size_t)BATCH * NSLOT * D * 4);
    float*  wsbuf   = (float*) alloc((size_t)BATCH * NSLOT * D * 4);
    ushort* wsb     = (ushort*)alloc((size_t)BATCH * NSLOT * D * 2);
    ushort* ipb     = (ushort*)alloc((size_t)3 * D * D * 2);
    ushort* wob     = (ushort*)alloc((size_t)D * D * 2);
    ushort* wwb     = (ushort*)alloc((size_t)D * D * 2);
    ushort* wqt     = (ushort*)alloc((size_t)D * D * 2);      // Wq^T bf16
    ushort* kb16    = (ushort*)alloc((size_t)BATCH * NHEAD * NSLOT * HDIM * 2);
    ushort* vb16    = (ushort*)alloc((size_t)BATCH * NHEAD * NSLOT * HDIM * 2);
    ushort* ktil    = (ushort*)alloc((size_t)BATCH * 512 * D * 2);   // K~ rows b*512+hs
    ushort* wtilT   = (ushort*)alloc((size_t)D * BATCH * 512 * 2);   // W~^T rows j
    ushort* qlogb   = (ushort*)alloc((size_t)2 * BL * 512 * 2);      // 2 bf16 planes
    ushort* aatt    = (ushort*)alloc((size_t)BL * 512 * 2);
    float*  cbias   = (float*) alloc((size_t)BATCH * 512 * 4);
    (void)ws_size; (void)in_sizes; (void)n_in; (void)out_size;

    conv_bf16_kernel<<<2048, 256, 0, stream>>>((const float4*)in_proj_w, ipb, 3 * D * D / 4);
    conv_bf16_kernel<<<2048, 256, 0, stream>>>((const float4*)out_proj_w, wob, D * D / 4);
    conv_bf16_kernel<<<2048, 256, 0, stream>>>((const float4*)write_w, wwb, D * D / 4);
    conv_bf16_kernel<<<2048, 256, 0, stream>>>((const float4*)x_in, xb, BL * D / 4);
    transpose_bf16_kernel<<<1024, 256, 0, stream>>>(ipb, wqt);   // Wq^T (q rows 0..D)

    for (int it = 0; it < 2; ++it) {
        const float* xs = it ? (const float*)xout : x_in;
        logits_kernel<<<BL / 4, 256, 0, stream>>>(xs, compete_w, compete_b, norm_pre_w,
                                                  logits);
        topk_xbar_kernel<<<BATCH * NSLOT, 256, 0, stream>>>(logits, xs, xbar);
        // written = xbar @ wwb^T + write_b   (64x2048, K=2048) — 512 waves
        gemm_tiny<0><<<128, 256, 0, stream>>>(xbar, wwb, write_b, written,
                                              BATCH * NSLOT, D, D,
                                              (ushort*)nullptr, (ushort*)nullptr);
        ws_update_kernel<<<BATCH * NSLOT, 256, 0, stream>>>(written, wsbuf, workspace,
                                                            it == 0 ? 1 : 0, norm_post_w,
                                                            wsbuf, wsb);
        // kv = wsb @ Wkv^T + bkv  (64x4096, K=2048) — 1024 waves, scatter to kb/vb
        gemm_tiny<1><<<256, 256, 0, stream>>>(wsb, ipb + (size_t)D * D, in_proj_b + D,
                                              (float*)nullptr, BATCH * NSLOT, 2 * D, D,
                                              kb16, vb16);
        // ktil | wtilT | cbias in one dispatch (independent, all need kb16/vb16)
        fused_prep_kernel<<<2056, 256, 0, stream>>>(kb16, vb16, in_proj_b, wqt, wob,
                                                    ktil, wtilT, cbias);
        // qlog[z][l, hs] (bf16) = xb[l, zK:] . K~[b,hs, zK:]  (split-K=2)
        // 1-D grid 1024 = 4 ntx * 128 nty * 2 ntz, XCD-remapped in-kernel.
        gemm_bt<64, 1><<<1024, 256, 0, stream>>>(
            xb, ktil, (const float*)nullptr, (float*)qlogb, BL, 512, D / 2,
            (size_t)512 * D, D, D, D / 2, D / 2, (size_t)(BL * 512 / 2), 2);
        attn_sm_kernel<<<BL / 8, 256, 0, stream>>>(qlogb, cbias, aatt);
        // x_b[l, j] (bf16) = sum_hs aatt[l,hs] * W~T[j, b*512+hs] + out_proj_b[j]
        // 1-D grid 2048 = 16 ntx * 128 nty * 1 ntz, XCD-remapped in-kernel.
        gemm_bt<64, 1><<<2048, 256, 0, stream>>>(
            aatt, wtilT, out_proj_b, (float*)xbb, BL, D, 512,
            (size_t)512, D, 512, 0, 0, 0, 1);
        resid_rms_kernel<<<BL, 256, 0, stream>>>(xs, xbb, norm_post_w, xout, xb);
    }
}

// Round 22
// 453.592 us; speedup vs baseline: 1.2171x; 1.0610x over previous
//
#include <hip/hip_runtime.h>
#include <stdint.h>

#define D 2048
#define LSEQ 2048
#define BATCH 4
#define BL (BATCH * LSEQ)   // 8192 rows
#define NSLOT 16
#define NHEAD 32
#define HDIM 64
#define EPSV 1e-6f

typedef __attribute__((ext_vector_type(8))) short bf16x8;
typedef __attribute__((ext_vector_type(4))) float f32x4;

static __device__ __forceinline__ ushort f2bf(float f) {
    uint32_t u = __float_as_uint(f);
    u += 0x7fffu + ((u >> 16) & 1u);   // RNE
    return (ushort)(u >> 16);
}

// DPP-based xor-add level (bit-exact vs __shfl_xor, runs on VALU not LDS pipe).
template <int CTRL>
static __device__ __forceinline__ float dpp_xadd(float v) {
    int t = __builtin_amdgcn_mov_dpp(__float_as_int(v), CTRL, 0xf, 0xf, true);
    return v + __int_as_float(t);
}

// Bit-exact butterfly sum, same order as original (off = 32,16,8,4,2,1),
// 3 of 6 levels on VALU DPP (proven R19: logits 50->~35us).
static __device__ __forceinline__ float wave_sum(float v) {
    v += __shfl_xor(v, 32, 64);
    v += __shfl_xor(v, 16, 64);
    v = dpp_xadd<0x128>(v);   // xor 8 (row_ror:8)
    v += __shfl_xor(v, 4, 64);
    v = dpp_xadd<0x4E>(v);    // xor 2 (quad_perm)
    v = dpp_xadd<0xB1>(v);    // xor 1 (quad_perm)
    return v;
}

// max / sum over the 16-lane group sharing ko (lanes xor 1,2,4,8).
static __device__ __forceinline__ float grp16_max(float v) {
    v = fmaxf(v, __shfl_xor(v, 1, 64));
    v = fmaxf(v, __shfl_xor(v, 2, 64));
    v = fmaxf(v, __shfl_xor(v, 4, 64));
    v = fmaxf(v, __shfl_xor(v, 8, 64));
    return v;
}
static __device__ __forceinline__ float grp16_sum(float v) {
    v += __shfl_xor(v, 1, 64);
    v += __shfl_xor(v, 2, 64);
    v += __shfl_xor(v, 4, 64);
    v += __shfl_xor(v, 8, 64);
    return v;
}

static __device__ __forceinline__ void gl_lds16(const void* g, void* l) {
    __builtin_amdgcn_global_load_lds(
        (__attribute__((address_space(1))) uint32_t*)(uintptr_t)g,
        (__attribute__((address_space(3))) uint32_t*)(uint32_t)(uintptr_t)l,
        16, 0, 0);
}

// ---------------- weight convert f32 -> bf16 ----------------
__global__ __launch_bounds__(256) void conv_bf16_kernel(const float4* __restrict__ src,
                                                        ushort* __restrict__ dst, int n4) {
    int i = blockIdx.x * 256 + threadIdx.x;
    int stride = gridDim.x * 256;
    for (; i < n4; i += stride) {
        float4 v = src[i];
        uint2 o;
        o.x = (uint)f2bf(v.x) | ((uint)f2bf(v.y) << 16);
        o.y = (uint)f2bf(v.z) | ((uint)f2bf(v.w) << 16);
        *(uint2*)(dst + (size_t)i * 4) = o;
    }
}

// ---------------- 2048x2048 bf16 transpose (once, for Wq^T) ----------------
__global__ __launch_bounds__(256) void transpose_bf16_kernel(const ushort* __restrict__ src,
                                                             ushort* __restrict__ dst) {
    __shared__ ushort t[64][72];
    int bx = blockIdx.x & 31, by = blockIdx.x >> 5;
    int r0 = by * 64, c0 = bx * 64;
    int tid = threadIdx.x;
    int lr = tid >> 3;
    int lc = (tid & 7) * 8;
#pragma unroll
    for (int p = 0; p < 2; ++p) {
        int rr = p * 32 + lr;
        bf16x8 v = *(const bf16x8*)(src + (size_t)(r0 + rr) * 2048 + c0 + lc);
#pragma unroll
        for (int j = 0; j < 8; ++j) t[lc + j][rr] = (ushort)v[j];
    }
    __syncthreads();
#pragma unroll
    for (int p = 0; p < 2; ++p) {
        int rr = p * 32 + lr;
        *(bf16x8*)(dst + (size_t)(c0 + rr) * 2048 + r0 + lc) = *(const bf16x8*)&t[rr][lc];
    }
}

// ---------------- logits v8: DPP wave_sum, bit-exact (DO NOT touch FP ops) -------
__global__ __launch_bounds__(256) void logits_kernel(
    const float* __restrict__ x, const float* __restrict__ cw,
    const float* __restrict__ cb, const float* __restrict__ wpre,
    float* __restrict__ logits_t) {
    int blk = blockIdx.x;              // 2048 blocks, 4 rows each
    int b = blk >> 9;                  // 512 blocks per batch
    int l0 = (blk & 511) << 2;
    int tid = threadIdx.x;
    int i0 = tid * 8;
    float4 w0 = *(const float4*)(wpre + i0);
    float4 w1 = *(const float4*)(wpre + i0 + 4);
    float wv[8] = {w0.x, w0.y, w0.z, w0.w, w1.x, w1.y, w1.z, w1.w};
    float xw[4][8];
    float ss[4];
#pragma unroll
    for (int r = 0; r < 4; ++r) {
        const float* xr = x + ((size_t)(b * LSEQ + l0 + r)) * D;
        float4 a0 = *(const float4*)(xr + i0);
        float4 a1 = *(const float4*)(xr + i0 + 4);
        float xv[8] = {a0.x, a0.y, a0.z, a0.w, a1.x, a1.y, a1.z, a1.w};
        float s0 = 0.f;
#pragma unroll
        for (int j = 0; j < 8; ++j) { s0 += xv[j] * xv[j]; xw[r][j] = xv[j] * wv[j]; }
        ss[r] = s0;
    }
#pragma unroll
    for (int r = 0; r < 4; ++r) ss[r] = wave_sum(ss[r]);
    __shared__ float red[4][NSLOT][4];
    __shared__ float redss[4][4];
    int lane = tid & 63, w = tid >> 6;
    if (lane == 0) {
#pragma unroll
        for (int r = 0; r < 4; ++r) redss[w][r] = ss[r];
    }
#pragma unroll 2
    for (int s = 0; s < NSLOT; ++s) {
        const float* cwr = cw + (size_t)s * D + i0;
        float4 c0 = *(const float4*)(cwr);
        float4 c1 = *(const float4*)(cwr + 4);
        float acc[4];
#pragma unroll
        for (int r = 0; r < 4; ++r)
            acc[r] = xw[r][0] * c0.x + xw[r][1] * c0.y + xw[r][2] * c0.z + xw[r][3] * c0.w +
                     xw[r][4] * c1.x + xw[r][5] * c1.y + xw[r][6] * c1.z + xw[r][7] * c1.w;
#pragma unroll
        for (int r = 0; r < 4; ++r) acc[r] = wave_sum(acc[r]);
        if (lane == 0) {
#pragma unroll
            for (int r = 0; r < 4; ++r) red[w][s][r] = acc[r];
        }
    }
    __syncthreads();
    if (tid < 64) {
        int s = tid >> 2, r = tid & 3;
        float tot = red[0][s][r] + red[1][s][r] + red[2][s][r] + red[3][s][r];
        float s2 = redss[0][r] + redss[1][r] + redss[2][r] + redss[3][r];
        float rsq = 1.0f / sqrtf(s2 * (1.0f / (float)D) + EPSV);
        logits_t[((size_t)(b * NSLOT + s)) * LSEQ + l0 + r] = tot * rsq + cb[s];
    }
}

// ---------------- top-4 + softmax + weighted row gather (xbar, bf16) ----------------
__global__ __launch_bounds__(256) void topk_xbar_kernel(
    const float* __restrict__ logits_t, const float* __restrict__ x,
    ushort* __restrict__ xbar_b) {
    int bs = blockIdx.x;
    int b = bs >> 4;
    const float* lr = logits_t + (size_t)bs * LSEQ;
    int tid = threadIdx.x, lane = tid & 63, w = tid >> 6;
    __shared__ float rv[4];
    __shared__ int ri[4];
    __shared__ float selv[4];
    __shared__ int seli[4];
    int i0 = tid * 8;
    float myv[8];
#pragma unroll
    for (int j = 0; j < 8; ++j) myv[j] = lr[i0 + j];
    int chosen[4];
    for (int p = 0; p < 4; ++p) {
        float bv = -3.4e38f;
        int bi = 0x7fffffff;
#pragma unroll
        for (int j = 0; j < 8; ++j) {
            int i = i0 + j;
            bool skip = false;
            for (int q = 0; q < p; ++q) skip = skip || (i == chosen[q]);
            float v = myv[j];
            if (!skip && (v > bv || (v == bv && i < bi))) { bv = v; bi = i; }
        }
#pragma unroll
        for (int off = 1; off < 64; off <<= 1) {
            float ov = __shfl_xor(bv, off, 64);
            int oi = __shfl_xor(bi, off, 64);
            if (ov > bv || (ov == bv && oi < bi)) { bv = ov; bi = oi; }
        }
        if (lane == 0) { rv[w] = bv; ri[w] = bi; }
        __syncthreads();
        if (tid == 0) {
            float fv = rv[0];
            int fi = ri[0];
            for (int q = 1; q < 4; ++q)
                if (rv[q] > fv || (rv[q] == fv && ri[q] < fi)) { fv = rv[q]; fi = ri[q]; }
            selv[p] = fv;
            seli[p] = fi;
        }
        __syncthreads();
        chosen[p] = seli[p];
    }
    float vals[4];
#pragma unroll
    for (int p = 0; p < 4; ++p) vals[p] = selv[p];
    float mx = vals[0];   // first pick is the max
    float e[4], den = 0.f;
#pragma unroll
    for (int p = 0; p < 4; ++p) { e[p] = expf(vals[p] - mx); den += e[p]; }
    float inv = 1.0f / den;
    const float* xr0 = x + ((size_t)b * LSEQ + chosen[0]) * D;
    const float* xr1 = x + ((size_t)b * LSEQ + chosen[1]) * D;
    const float* xr2 = x + ((size_t)b * LSEQ + chosen[2]) * D;
    const float* xr3 = x + ((size_t)b * LSEQ + chosen[3]) * D;
    float s[8];
#pragma unroll
    for (int j = 0; j < 8; ++j) {
        int i = i0 + j;
        s[j] = (e[0] * xr0[i] + e[1] * xr1[i] + e[2] * xr2[i] + e[3] * xr3[i]) * inv;
    }
    uint4 o;
    o.x = (uint)f2bf(s[0]) | ((uint)f2bf(s[1]) << 16);
    o.y = (uint)f2bf(s[2]) | ((uint)f2bf(s[3]) << 16);
    o.z = (uint)f2bf(s[4]) | ((uint)f2bf(s[5]) << 16);
    o.w = (uint)f2bf(s[6]) | ((uint)f2bf(s[7]) << 16);
    *(uint4*)(xbar_b + (size_t)bs * D + i0) = o;
}

// ---------------- ws = rms(ws_prev + written) (+bf16 copy) ----------------
__global__ __launch_bounds__(256) void ws_update_kernel(
    const float* __restrict__ written, const float* __restrict__ ws_prev,
    const float* __restrict__ workspace0, int first,
    const float* __restrict__ wpost, float* __restrict__ ws_out,
    ushort* __restrict__ ws_b) {
    int bs = blockIdx.x;
    int s = bs & (NSLOT - 1);
    int tid = threadIdx.x;
    int i0 = tid * 8;
    const float* prev = first ? (workspace0 + (size_t)s * D) : (ws_prev + (size_t)bs * D);
    const float* wr = written + (size_t)bs * D;
    float4 p0 = *(const float4*)(prev + i0);
    float4 p1 = *(const float4*)(prev + i0 + 4);
    float4 q0 = *(const float4*)(wr + i0);
    float4 q1 = *(const float4*)(wr + i0 + 4);
    float t[8] = {p0.x + q0.x, p0.y + q0.y, p0.z + q0.z, p0.w + q0.w,
                  p1.x + q1.x, p1.y + q1.y, p1.z + q1.z, p1.w + q1.w};
    float ss = 0.f;
#pragma unroll
    for (int j = 0; j < 8; ++j) ss += t[j] * t[j];
    ss = wave_sum(ss);
    __shared__ float sb[4];
    if ((tid & 63) == 0) sb[tid >> 6] = ss;
    __syncthreads();
    ss = sb[0] + sb[1] + sb[2] + sb[3];
    float rsq = 1.0f / sqrtf(ss * (1.0f / (float)D) + EPSV);
    float4 w0 = *(const float4*)(wpost + i0);
    float4 w1 = *(const float4*)(wpost + i0 + 4);
    float wv[8] = {w0.x, w0.y, w0.z, w0.w, w1.x, w1.y, w1.z, w1.w};
    float o[8];
#pragma unroll
    for (int j = 0; j < 8; ++j) o[j] = t[j] * rsq * wv[j];
    float4 r0 = {o[0], o[1], o[2], o[3]};
    float4 r1 = {o[4], o[5], o[6], o[7]};
    *(float4*)(ws_out + (size_t)bs * D + i0) = r0;
    *(float4*)(ws_out + (size_t)bs * D + i0 + 4) = r1;
    uint4 ob;
    ob.x = (uint)f2bf(o[0]) | ((uint)f2bf(o[1]) << 16);
    ob.y = (uint)f2bf(o[2]) | ((uint)f2bf(o[3]) << 16);
    ob.z = (uint)f2bf(o[4]) | ((uint)f2bf(o[5]) << 16);
    ob.w = (uint)f2bf(o[6]) | ((uint)f2bf(o[7]) << 16);
    *(uint4*)(ws_b + (size_t)bs * D + i0) = ob;
}

// ---------------- x = rms(x + attn_out[bf16]) (+bf16 copy) ----------------
__global__ __launch_bounds__(256) void resid_rms_kernel(
    const float* __restrict__ x_src, const ushort* __restrict__ ao,
    const float* __restrict__ wpost, float* __restrict__ x_dst,
    ushort* __restrict__ xb) {
    int row = blockIdx.x;
    int tid = threadIdx.x;
    int i0 = tid * 8;
    const float* xr = x_src + (size_t)row * D;
    uint4 av = *(const uint4*)(ao + (size_t)row * D + i0);
    float af[8];
    af[0] = __uint_as_float(av.x << 16);
    af[1] = __uint_as_float(av.x & 0xffff0000u);
    af[2] = __uint_as_float(av.y << 16);
    af[3] = __uint_as_float(av.y & 0xffff0000u);
    af[4] = __uint_as_float(av.z << 16);
    af[5] = __uint_as_float(av.z & 0xffff0000u);
    af[6] = __uint_as_float(av.w << 16);
    af[7] = __uint_as_float(av.w & 0xffff0000u);
    float4 p0 = *(const float4*)(xr + i0);
    float4 p1 = *(const float4*)(xr + i0 + 4);
    float t[8] = {p0.x + af[0], p0.y + af[1], p0.z + af[2], p0.w + af[3],
                  p1.x + af[4], p1.y + af[5], p1.z + af[6], p1.w + af[7]};
    float ss = 0.f;
#pragma unroll
    for (int j = 0; j < 8; ++j) ss += t[j] * t[j];
    ss = wave_sum(ss);
    __shared__ float sb[4];
    if ((tid & 63) == 0) sb[tid >> 6] = ss;
    __syncthreads();
    ss = sb[0] + sb[1] + sb[2] + sb[3];
    float rsq = 1.0f / sqrtf(ss * (1.0f / (float)D) + EPSV);
    float4 w0 = *(const float4*)(wpost + i0);
    float4 w1 = *(const float4*)(wpost + i0 + 4);
    float wv[8] = {w0.x, w0.y, w0.z, w0.w, w1.x, w1.y, w1.z, w1.w};
    float o[8];
#pragma unroll
    for (int j = 0; j < 8; ++j) o[j] = t[j] * rsq * wv[j];
    float4 r0 = {o[0], o[1], o[2], o[3]};
    float4 r1 = {o[4], o[5], o[6], o[7]};
    *(float4*)(x_dst + (size_t)row * D + i0) = r0;
    *(float4*)(x_dst + (size_t)row * D + i0 + 4) = r1;
    uint4 ob;
    ob.x = (uint)f2bf(o[0]) | ((uint)f2bf(o[1]) << 16);
    ob.y = (uint)f2bf(o[2]) | ((uint)f2bf(o[3]) << 16);
    ob.z = (uint)f2bf(o[4]) | ((uint)f2bf(o[5]) << 16);
    ob.w = (uint)f2bf(o[6]) | ((uint)f2bf(o[7]) << 16);
    *(uint4*)(xb + (size_t)row * D + i0) = ob;
}

// ---------------- grouped 16x64 GEMM body (device) ----------------
template <int TRANS>
static __device__ __forceinline__ void grouped16_body(
    int blk, const ushort* __restrict__ Abase, const ushort* __restrict__ Bmat,
    ushort* __restrict__ Cout) {
    int g = blk >> 3;               // 0..127 = b*32+h
    int nt = blk & 7;
    int h = g & 31;
    int hoff = h * 64;
    int tid = threadIdx.x, lane = tid & 63, wv = tid >> 6;
    int j0 = nt * 256 + wv * 64;
    int rr = lane & 15, ko = lane >> 4;
    const ushort* A = Abase + (size_t)g * 16 * 64;
    bf16x8 af0 = *(const bf16x8*)(A + rr * 64 + ko * 8);
    bf16x8 af1 = *(const bf16x8*)(A + rr * 64 + 32 + ko * 8);
    f32x4 acc[4];
    f32x4 zero = {0.f, 0.f, 0.f, 0.f};
#pragma unroll
    for (int nf = 0; nf < 4; ++nf) acc[nf] = zero;
#pragma unroll
    for (int nf = 0; nf < 4; ++nf) {
        int j = j0 + nf * 16 + rr;
        bf16x8 b0 = *(const bf16x8*)(Bmat + (size_t)j * 2048 + hoff + ko * 8);
        bf16x8 b1 = *(const bf16x8*)(Bmat + (size_t)j * 2048 + hoff + 32 + ko * 8);
        acc[nf] = __builtin_amdgcn_mfma_f32_16x16x32_bf16(af0, b0, acc[nf], 0, 0, 0);
        acc[nf] = __builtin_amdgcn_mfma_f32_16x16x32_bf16(af1, b1, acc[nf], 0, 0, 0);
    }
#pragma unroll
    for (int nf = 0; nf < 4; ++nf)
#pragma unroll
        for (int r = 0; r < 4; ++r) {
            int s = ko * 4 + r;
            int j = j0 + nf * 16 + rr;
            ushort v = f2bf(acc[nf][r]);
            if (TRANS) Cout[(size_t)j * 2048 + g * 16 + s] = v;
            else       Cout[(size_t)(g * 16 + s) * 2048 + j] = v;
        }
}

// ---------------- fused: grouped16<0> (ktil) | grouped16<1> (wtilT) | cbias -------
__global__ __launch_bounds__(256) void fused_prep_kernel(
    const ushort* __restrict__ kb16, const ushort* __restrict__ vb16,
    const float* __restrict__ bq, const ushort* __restrict__ wqt,
    const ushort* __restrict__ wob, ushort* __restrict__ ktil,
    ushort* __restrict__ wtilT, float* __restrict__ cbias) {
    int blk = blockIdx.x;
    if (blk < 1024) {
        grouped16_body<0>(blk, kb16, wqt, ktil);
    } else if (blk < 2048) {
        grouped16_body<1>(blk - 1024, vb16, wob, wtilT);
    } else {
        int i = (blk - 2048) * 256 + threadIdx.x;   // 0..2047
        int hs = i & 511;
        int h = hs >> 4;
        const ushort* kr = kb16 + (size_t)i * 64;
        const float* bb = bq + h * 64;
        float acc = 0.f;
#pragma unroll
        for (int d = 0; d < 64; ++d)
            acc += __uint_as_float(((uint)kr[d]) << 16) * bb[d];
        cbias[i] = acc;
    }
}

// ---------------- tiny-M GEMM: one wave per 16x16 output tile, no LDS/barriers ----
template <int KVMODE>
__global__ __launch_bounds__(256) void gemm_tiny(
    const ushort* __restrict__ A, const ushort* __restrict__ Bw,
    const float* __restrict__ bias, float* __restrict__ C,
    int M, int N, int K, ushort* __restrict__ kvk, ushort* __restrict__ kvv) {
    int gw = (blockIdx.x * 256 + threadIdx.x) >> 6;
    int lane = threadIdx.x & 63;
    int ntiles = N >> 4;
    int nt = gw % ntiles, mt = gw / ntiles;
    int rr = lane & 15, ko = lane >> 4;
    const ushort* Ar = A + (size_t)(mt * 16 + rr) * K;
    const ushort* Br = Bw + (size_t)(nt * 16 + rr) * K;
    f32x4 acc = {0.f, 0.f, 0.f, 0.f};
    int NT = K / 32;
#pragma unroll 8
    for (int t = 0; t < NT; ++t) {
        bf16x8 af = *(const bf16x8*)(Ar + t * 32 + ko * 8);
        bf16x8 bf = *(const bf16x8*)(Br + t * 32 + ko * 8);
        acc = __builtin_amdgcn_mfma_f32_16x16x32_bf16(af, bf, acc, 0, 0, 0);
    }
    int col = nt * 16 + rr;
    float bsv = bias ? bias[col] : 0.f;
#pragma unroll
    for (int r = 0; r < 4; ++r) {
        int rowi = mt * 16 + ko * 4 + r;
        float v = acc[r] + bsv;
        if (KVMODE) {
            int b = rowi >> 4, s = rowi & 15;
            int c2 = (col < 2048) ? col : col - 2048;
            int h = c2 >> 6, d = c2 & 63;
            size_t dst = (((size_t)(b * NHEAD + h)) * NSLOT + s) * HDIM + d;
            if (col < 2048) kvk[dst] = f2bf(v);
            else            kvv[dst] = f2bf(v);
        } else {
            C[(size_t)rowi * N + col] = v;
        }
    }
}

// ---------------- fused qlog GEMM + head softmax -> aatt ----------------
// BM=64, BN=128, K=2048 (no split-K). Each block's 128 cols = 8 COMPLETE heads,
// so softmax over the 16 cols of each head happens in-register: the 16 values of
// a softmax row live across the 16 rr-lanes of one ko-group -> 4-level shfl max
// + exp + 4-level shfl sum. Softmax input is the f32 accumulator (MORE accurate
// than the old bf16 split-K planes; smooth path, frozen top-k chain untouched).
// Grid 512 (4 ntx x 128 nty), XCD-remapped; XOR-swizzled LDS as gemm_bt.
__global__ __launch_bounds__(256) void gemm_qsm_kernel(
    const ushort* __restrict__ A, const ushort* __restrict__ ktil,
    const float* __restrict__ cbias, ushort* __restrict__ aatt) {
    constexpr int BM = 64, BN = 128, BK = 32;
    constexpr int MF = 2;
    __shared__ short lds[2][(BM + BN) * BK];
    int tid = threadIdx.x;
    int lane = tid & 63, w = tid >> 6;
    int wr = w >> 1, wc = w & 1;
    // XCD remap: total=512, per=64, ntx=4 -> 16 (by) per XCD
    int xcd = blockIdx.x & 7;
    int j = blockIdx.x >> 3;
    int by = xcd * 16 + (j >> 2);
    int bx = j & 3;
    int tn = bx * BN;
    int tm = by * BM;
    int b = tm >> 11;                         // batch (64-row blocks never cross)
    const ushort* Bw = ktil + (size_t)b * 512 * D;
    f32x4 acc[MF][4];
    f32x4 zero = {0.f, 0.f, 0.f, 0.f};
#pragma unroll
    for (int m = 0; m < MF; ++m)
#pragma unroll
        for (int n = 0; n < 4; ++n) acc[m][n] = zero;
    int NT = D / BK;                          // 64

    auto stage = [&](int buf, int t) {
        int kt = t * BK;
        {
            int cb = w * 64;                  // APASS==1 for BM=64
            int c = cb + lane;
            int L = c >> 3, slot = c & 7;
            int lc = slot ^ (L & 7);
            int r = 2 * L + (lc >> 2);
            int k8 = (lc & 3) * 8;
            gl_lds16(A + (size_t)(tm + r) * D + kt + k8, (void*)&lds[buf][cb * 8]);
        }
#pragma unroll
        for (int p = 0; p < 2; ++p) {
            int cb = p * 256 + w * 64;
            int c = cb + lane;
            int L = c >> 3, slot = c & 7;
            int lc = slot ^ (L & 7);
            int r = 2 * L + (lc >> 2);
            int k8 = (lc & 3) * 8;
            gl_lds16(Bw + (size_t)(tn + r) * D + kt + k8,
                     (void*)&lds[buf][BM * BK + cb * 8]);
        }
    };
    stage(0, 0);
    for (int t = 0; t < NT; ++t) {
        __syncthreads();
        if (t + 1 < NT) stage((t + 1) & 1, t + 1);
        const short* Ab = &lds[t & 1][0];
        const short* Bb = &lds[t & 1][BM * BK];
        int kc = lane >> 4;
        int rr = lane & 15;
        bf16x8 af[MF], bfr[4];
#pragma unroll
        for (int m = 0; m < MF; ++m) {
            int row = wr * (MF * 16) + m * 16 + rr;
            int L = row >> 1;
            int sl = (((row & 1) * 4 + kc)) ^ (L & 7);
            af[m] = *(const bf16x8*)&Ab[L * 64 + sl * 8];
        }
#pragma unroll
        for (int n = 0; n < 4; ++n) {
            int row = wc * 64 + n * 16 + rr;
            int L = row >> 1;
            int sl = (((row & 1) * 4 + kc)) ^ (L & 7);
            bfr[n] = *(const bf16x8*)&Bb[L * 64 + sl * 8];
        }
#pragma unroll
        for (int m = 0; m < MF; ++m)
#pragma unroll
            for (int n = 0; n < 4; ++n)
                acc[m][n] = __builtin_amdgcn_mfma_f32_16x16x32_bf16(af[m], bfr[n],
                                                                    acc[m][n], 0, 0, 0);
    }
    // ---- fused softmax epilogue ----
    int rr = lane & 15, ko = lane >> 4;
#pragma unroll
    for (int n = 0; n < 4; ++n) {
        int col = tn + wc * 64 + n * 16 + rr;
        float cbv = cbias[b * 512 + col];
#pragma unroll
        for (int m = 0; m < MF; ++m) {
#pragma unroll
            for (int r = 0; r < 4; ++r) {
                float p = acc[m][n][r] + cbv;
                float mx = grp16_max(p);
                float e = __expf((p - mx) * 0.125f);
                float den = grp16_sum(e);
                int row = tm + wr * (MF * 16) + m * 16 + ko * 4 + r;
                aatt[(size_t)row * 512 + col] = f2bf(e / den);
            }
        }
    }
}

// ---------------- bf16 MFMA GEMM, XOR-swizzled LDS, XCD-aware block remap ---------
template <int BM, int OBF>
__global__ __launch_bounds__(256) void gemm_bt(
    const ushort* __restrict__ A, const ushort* __restrict__ Bw,
    const float* __restrict__ bias, float* __restrict__ C,
    int M, int N, int K, size_t bOff, int bStride, int aStride,
    int zA, int zB, size_t zC, int ntz) {
    constexpr int BN = 128, BK = 32;
    constexpr int MF = BM / 32;
    constexpr int APASS = (BM * BK / 8) / 256;
    __shared__ short lds[2][(BM + BN) * BK];
    int tid = threadIdx.x;
    int lane = tid & 63, w = tid >> 6;
    int wr = w >> 1, wc = w & 1;
    // ---- XCD-aware remap ----
    int ntx = N / BN;
    int total = gridDim.x;
    int per = total >> 3;                 // blocks per XCD
    int xcd = blockIdx.x & 7;
    int j = blockIdx.x >> 3;
    int pairs_per = per / ntx;            // (by,z) pairs per XCD
    int pair = xcd * pairs_per + j / ntx;
    int bx = j % ntx;
    int by = pair / ntz;
    int ksl = pair % ntz;
    int tn = bx * BN;
    int tm = by * BM;
    A += (size_t)ksl * zA;
    Bw += (size_t)ksl * zB + (size_t)(tm >> 11) * bOff;
    C += (size_t)ksl * zC;
    f32x4 acc[MF][4];
    f32x4 zero = {0.f, 0.f, 0.f, 0.f};
#pragma unroll
    for (int m = 0; m < MF; ++m)
#pragma unroll
        for (int n = 0; n < 4; ++n) acc[m][n] = zero;
    int NT = K / BK;

    auto stage = [&](int buf, int t) {
        int kt = t * BK;
#pragma unroll
        for (int p = 0; p < APASS; ++p) {
            int cb = p * 256 + w * 64;
            int c = cb + lane;
            int L = c >> 3, slot = c & 7;
            int lc = slot ^ (L & 7);            // pre-swizzled source
            int r = 2 * L + (lc >> 2);
            int k8 = (lc & 3) * 8;
            int gr = tm + r;
            if (gr >= M) gr = M - 1;
            gl_lds16(A + (size_t)gr * aStride + kt + k8, (void*)&lds[buf][cb * 8]);
        }
#pragma unroll
        for (int p = 0; p < 2; ++p) {
            int cb = p * 256 + w * 64;
            int c = cb + lane;
            int L = c >> 3, slot = c & 7;
            int lc = slot ^ (L & 7);
            int r = 2 * L + (lc >> 2);
            int k8 = (lc & 3) * 8;
            gl_lds16(Bw + (size_t)(tn + r) * bStride + kt + k8,
                     (void*)&lds[buf][BM * BK + cb * 8]);
        }
    };
    stage(0, 0);
    for (int t = 0; t < NT; ++t) {
        __syncthreads();
        if (t + 1 < NT) stage((t + 1) & 1, t + 1);
        const short* Ab = &lds[t & 1][0];
        const short* Bb = &lds[t & 1][BM * BK];
        int kc = lane >> 4;                    // 16B chunk 0..3
        int rr = lane & 15;
        bf16x8 af[MF], bfr[4];
#pragma unroll
        for (int m = 0; m < MF; ++m) {
            int row = wr * (MF * 16) + m * 16 + rr;
            int L = row >> 1;
            int sl = (((row & 1) * 4 + kc)) ^ (L & 7);
            af[m] = *(const bf16x8*)&Ab[L * 64 + sl * 8];
        }
#pragma unroll
        for (int n = 0; n < 4; ++n) {
            int row = wc * 64 + n * 16 + rr;
            int L = row >> 1;
            int sl = (((row & 1) * 4 + kc)) ^ (L & 7);
            bfr[n] = *(const bf16x8*)&Bb[L * 64 + sl * 8];
        }
#pragma unroll
        for (int m = 0; m < MF; ++m)
#pragma unroll
            for (int n = 0; n < 4; ++n)
                acc[m][n] = __builtin_amdgcn_mfma_f32_16x16x32_bf16(af[m], bfr[n],
                                                                    acc[m][n], 0, 0, 0);
    }
#pragma unroll
    for (int m = 0; m < MF; ++m) {
#pragma unroll
        for (int n = 0; n < 4; ++n) {
            int col = tn + wc * 64 + n * 16 + (lane & 15);
            float bsv = bias ? bias[col] : 0.f;
#pragma unroll
            for (int r = 0; r < 4; ++r) {
                int rowi = tm + wr * (MF * 16) + m * 16 + (lane >> 4) * 4 + r;
                if (rowi >= M) continue;
                float v = acc[m][n][r] + bsv;
                if (OBF) ((ushort*)C)[(size_t)rowi * N + col] = f2bf(v);
                else     C[(size_t)rowi * N + col] = v;
            }
        }
    }
}

extern "C" void kernel_launch(void* const* d_in, const int* in_sizes, int n_in,
                              void* d_out, int out_size, void* d_ws, size_t ws_size,
                              hipStream_t stream) {
    const float* x_in       = (const float*)d_in[0];
    const float* workspace  = (const float*)d_in[1];
    const float* compete_w  = (const float*)d_in[2];
    const float* compete_b  = (const float*)d_in[3];
    const float* write_w    = (const float*)d_in[4];
    const float* write_b    = (const float*)d_in[5];
    const float* in_proj_w  = (const float*)d_in[6];
    const float* in_proj_b  = (const float*)d_in[7];
    const float* out_proj_w = (const float*)d_in[8];
    const float* out_proj_b = (const float*)d_in[9];
    const float* norm_pre_w  = (const float*)d_in[12];
    const float* norm_post_w = (const float*)d_in[13];
    float* xout = (float*)d_out;

    char* base = (char*)d_ws;
    size_t off = 0;
    auto alloc = [&](size_t bytes) {
        void* p = base + off;
        off += (bytes + 255) & ~(size_t)255;
        return p;
    };
    ushort* xb      = (ushort*)alloc((size_t)BL * D * 2);
    ushort* xbb     = (ushort*)alloc((size_t)BL * D * 2);     // x_b (bf16)
    float*  logits  = (float*) alloc((size_t)BATCH * NSLOT * LSEQ * 4);
    ushort* xbar    = (ushort*)alloc((size_t)BATCH * NSLOT * D * 2);
    float*  written = (float*) alloc((size_t)BATCH * NSLOT * D * 4);
    float*  wsbuf   = (float*) alloc((size_t)BATCH * NSLOT * D * 4);
    ushort* wsb     = (ushort*)alloc((size_t)BATCH * NSLOT * D * 2);
    ushort* ipb     = (ushort*)alloc((size_t)3 * D * D * 2);
    ushort* wob     = (ushort*)alloc((size_t)D * D * 2);
    ushort* wwb     = (ushort*)alloc((size_t)D * D * 2);
    ushort* wqt     = (ushort*)alloc((size_t)D * D * 2);      // Wq^T bf16
    ushort* kb16    = (ushort*)alloc((size_t)BATCH * NHEAD * NSLOT * HDIM * 2);
    ushort* vb16    = (ushort*)alloc((size_t)BATCH * NHEAD * NSLOT * HDIM * 2);
    ushort* ktil    = (ushort*)alloc((size_t)BATCH * 512 * D * 2);   // K~ rows b*512+hs
    ushort* wtilT   = (ushort*)alloc((size_t)D * BATCH * 512 * 2);   // W~^T rows j
    ushort* aatt    = (ushort*)alloc((size_t)BL * 512 * 2);
    float*  cbias   = (float*) alloc((size_t)BATCH * 512 * 4);
    (void)ws_size; (void)in_sizes; (void)n_in; (void)out_size;

    conv_bf16_kernel<<<2048, 256, 0, stream>>>((const float4*)in_proj_w, ipb, 3 * D * D / 4);
    conv_bf16_kernel<<<2048, 256, 0, stream>>>((const float4*)out_proj_w, wob, D * D / 4);
    conv_bf16_kernel<<<2048, 256, 0, stream>>>((const float4*)write_w, wwb, D * D / 4);
    conv_bf16_kernel<<<2048, 256, 0, stream>>>((const float4*)x_in, xb, BL * D / 4);
    transpose_bf16_kernel<<<1024, 256, 0, stream>>>(ipb, wqt);   // Wq^T (q rows 0..D)

    for (int it = 0; it < 2; ++it) {
        const float* xs = it ? (const float*)xout : x_in;
        logits_kernel<<<BL / 4, 256, 0, stream>>>(xs, compete_w, compete_b, norm_pre_w,
                                                  logits);
        topk_xbar_kernel<<<BATCH * NSLOT, 256, 0, stream>>>(logits, xs, xbar);
        // written = xbar @ wwb^T + write_b   (64x2048, K=2048) — 512 waves
        gemm_tiny<0><<<128, 256, 0, stream>>>(xbar, wwb, write_b, written,
                                              BATCH * NSLOT, D, D,
                                              (ushort*)nullptr, (ushort*)nullptr);
        ws_update_kernel<<<BATCH * NSLOT, 256, 0, stream>>>(written, wsbuf, workspace,
                                                            it == 0 ? 1 : 0, norm_post_w,
                                                            wsbuf, wsb);
        // kv = wsb @ Wkv^T + bkv  (64x4096, K=2048) — 1024 waves, scatter to kb/vb
        gemm_tiny<1><<<256, 256, 0, stream>>>(wsb, ipb + (size_t)D * D, in_proj_b + D,
                                              (float*)nullptr, BATCH * NSLOT, 2 * D, D,
                                              kb16, vb16);
        // ktil | wtilT | cbias in one dispatch (independent, all need kb16/vb16)
        fused_prep_kernel<<<2056, 256, 0, stream>>>(kb16, vb16, in_proj_b, wqt, wob,
                                                    ktil, wtilT, cbias);
        // fused: qlog GEMM (K=2048) + per-head softmax -> aatt (bf16)
        gemm_qsm_kernel<<<512, 256, 0, stream>>>(xb, ktil, cbias, aatt);
        // x_b[l, j] (bf16) = sum_hs aatt[l,hs] * W~T[j, b*512+hs] + out_proj_b[j]
        gemm_bt<64, 1><<<2048, 256, 0, stream>>>(
            aatt, wtilT, out_proj_b, (float*)xbb, BL, D, 512,
            (size_t)512, D, 512, 0, 0, 0, 1);
        resid_rms_kernel<<<BL, 256, 0, stream>>>(xs, xbb, norm_post_w, xout, xb);
    }
}